// Round 10
// baseline (71576.184 us; speedup 1.0000x reference)
//
#include <hip/hip_runtime.h>
#include <hip/hip_bf16.h>

#define DEV static __device__ __forceinline__

typedef __hip_bfloat162 bf162;

constexpr int H_ = 187, MS_ = 20, MOB_ = 10, D_ = 128, NH_ = 4, NL_ = 4,
              CE_ = 16, NAT_ = 5, NCT_ = 256, HEXC_ = 29, B_ = 1024;
constexpr int S_ = H_ + 2;   // 189 tokens
constexpr int TP = D_ + 1;   // tok LDS stride in floats
constexpr int KVS = 33;      // kv row stride in bf162 units

constexpr int OFF_HEX = B_ * NAT_;          // 5120
constexpr int OFF_TGT = OFF_HEX + B_ * H_;  // 196608
constexpr int OFF_VAL = OFF_TGT + B_ * MS_; // 217088

struct Params {
  const float *scalars, *stacks, *obstacles, *reach;
  const int  *n_stacks;
  const float *cemb, *pos_emb, *tte;
  const float *hexW, *hexB, *hexG, *hexBe;
  const float *heroW, *heroB, *heroG, *heroBe;
  const float *gW, *gB;
  const float *ln1g, *ln1b, *qkvW, *qkvB, *oW, *oB;
  const float *ln2g, *ln2b, *f1W, *f1B, *f2W, *f2B;
  const float *plng, *plnb;
  const float *atW1, *atB1, *atW2, *atB2;
  const float *hxW1, *hxB1, *hxW2, *hxB2;
  const float *tgW1, *tgB1, *tgW2, *tgB2;
  const float *vlW1, *vlB1, *vlW2, *vlB2;
  float *out;   // FLOAT32 output buffer (218112 elements)
};

constexpr int SCR_FLOATS = 6400;

__global__ __launch_bounds__(192, 1) void battle_kernel(Params p) {
  __shared__ float tok[S_][TP];
  __shared__ float scr[SCR_FLOATS];
  __shared__ float gvec[D_];
  __shared__ float pooled[D_];
  __shared__ float hid1[D_];
  __shared__ float hid2[D_];
  __shared__ int   svalid[MS_];
  __shared__ int   sposc[MS_];

  const int b = blockIdx.x;
  const int tid = threadIdx.x;
  const bool hasrow = tid < S_;
  const float *sc = p.scalars + b * 19;

  float *hexcont = &scr[0];
  int   *cids    = (int *)&scr[5440];
  float *obsch   = &scr[5632];
  bf162 *kv2     = (bf162 *)scr;

  if (tid < D_) {
    float g0 = sc[1] * 0.02f, g1 = sc[4] * 0.1f, g2 = sc[5] * 0.1f;
    float g3 = sc[6], g4 = sc[3];
    const float *w = p.gW + tid * 5;
    gvec[tid] = p.gB[tid] + g0 * w[0] + g1 * w[1] + g2 * w[2] + g3 * w[3] + g4 * w[4];
  }
  for (int i = tid; i < H_ * HEXC_; i += 192) hexcont[i] = 0.f;
  for (int i = tid; i < H_; i += 192) { cids[i] = 0; obsch[i] = 0.f; }
  __syncthreads();

  if (tid < MS_) {
    const float *st = p.stacks + (b * MS_ + tid) * 35;
    int pos = (int)st[18];
    float alive = st[23];
    int ns = p.n_stacks[b];
    bool valid = (pos >= 0) && (pos < H_) && (alive >= 0.5f) && (tid < ns);
    svalid[tid] = valid ? 1 : 0;
    sposc[tid] = min(max(pos, 0), H_ - 1);
    if (valid) {
      float maxhp = fmaxf(st[4], 1.0f);
      float *hc = hexcont + pos * HEXC_;
      hc[0] = 1.0f;
      hc[1] = st[2] * 1e-3f;
      hc[2] = st[3] / maxhp;
      hc[3] = st[8] * 0.01f;  hc[4] = st[9] * 0.01f;
      hc[5] = st[10] * 0.01f; hc[6] = st[11] * 0.01f;
      hc[7] = st[12] * 0.01f; hc[8] = st[13] * 0.01f;
      hc[9] = st[14] * 0.01f; hc[10] = st[15] * 0.01f;
      hc[11] = st[16] * 0.05f; hc[12] = st[17] * 0.05f;
      float s20 = st[20];
      hc[13] = s20;
      hc[14] = (s20 == sc[3]) ? 1.f : 0.f;
      hc[15] = alive;
      hc[16] = st[24]; hc[17] = st[25]; hc[18] = st[26];
      hc[19] = st[27]; hc[20] = st[28]; hc[21] = st[29];
      hc[22] = st[30];
      hc[23] = st[31] * (1.f / 30.f);
      hc[24] = st[33] * 0.2f;
      hc[25] = st[34] * 0.1f;
      hc[26] = (st[0] == sc[2]) ? 1.f : 0.f;
      hc[27] = 0.f; hc[28] = 0.f;
      cids[pos] = min((int)st[1], NCT_ - 1);
    }
  }
  if (tid >= 64 && tid < 64 + MOB_) {
    const float *ob = p.obstacles + (b * MOB_ + (tid - 64)) * 3;
    int opos = (int)ob[2];
    if (ob[0] > 0.f && opos >= 0 && opos < H_) obsch[opos] = 1.0f;
  }
  __syncthreads();

  if (tid < H_) {
    const int r = tid;
    float f[HEXC_ + CE_];
#pragma unroll
    for (int c = 0; c < HEXC_; ++c) f[c] = hexcont[r * HEXC_ + c];
    f[27] = p.reach[b * H_ + r];
    f[28] = obsch[r];
    int cid = cids[r];
#pragma unroll
    for (int e = 0; e < CE_; ++e) f[HEXC_ + e] = p.cemb[cid * CE_ + e];
    float sum = 0.f;
#pragma unroll 2
    for (int d = 0; d < D_; ++d) {
      float acc = p.hexB[d];
#pragma unroll
      for (int k = 0; k < HEXC_ + CE_; ++k) acc = fmaf(f[k], p.hexW[d * 45 + k], acc);
      tok[r][d] = acc; sum += acc;
    }
    float m = sum * (1.f / 128.f);
    float var = 0.f;
#pragma unroll 4
    for (int d = 0; d < D_; ++d) { float t = tok[r][d] - m; var += t * t; }
    float rs = rsqrtf(var * (1.f / 128.f) + 1e-5f);
#pragma unroll 2
    for (int d = 0; d < D_; ++d) {
      float v = (tok[r][d] - m) * rs * p.hexG[d] + p.hexBe[d];
      tok[r][d] = v + p.pos_emb[r * D_ + d] + p.tte[d] + gvec[d];
    }
  } else if (tid < S_) {
    const int which = tid - H_;
    float f0, f1, f2, f3, f4;
    if (which == 0) {
      f0 = sc[8];  f1 = sc[11] * (1.f / 300.f);
      f2 = sc[10] * 0.1f; f3 = sc[12] * 0.1f; f4 = 0.f;
    } else {
      f0 = sc[14]; f1 = sc[17] * (1.f / 300.f);
      f2 = sc[16] * 0.1f; f3 = sc[18] * 0.1f; f4 = 1.f;
    }
    const int r = tid;
    float sum = 0.f;
#pragma unroll 2
    for (int d = 0; d < D_; ++d) {
      const float *w = p.heroW + d * 5;
      float acc = p.heroB[d] + f0 * w[0] + f1 * w[1] + f2 * w[2] + f3 * w[3] + f4 * w[4];
      tok[r][d] = acc; sum += acc;
    }
    float m = sum * (1.f / 128.f);
    float var = 0.f;
    for (int d = 0; d < D_; ++d) { float t = tok[r][d] - m; var += t * t; }
    float rs = rsqrtf(var * (1.f / 128.f) + 1e-5f);
#pragma unroll 2
    for (int d = 0; d < D_; ++d) {
      float v = (tok[r][d] - m) * rs * p.heroG[d] + p.heroBe[d];
      tok[r][d] = v + p.tte[(1 + which) * D_ + d] + gvec[d];
    }
  }

  for (int l = 0; l < NL_; ++l) {
    const float *ln1g = p.ln1g + l * D_, *ln1b = p.ln1b + l * D_;
    const float *qkvW = p.qkvW + l * 3 * D_ * D_, *qkvB = p.qkvB + l * 3 * D_;
    const float *oW = p.oW + l * D_ * D_, *oB = p.oB + l * D_;
    const float *ln2g = p.ln2g + l * D_, *ln2b = p.ln2b + l * D_;
    const float *f1W = p.f1W + l * 4 * D_ * D_, *f1B = p.f1B + l * 4 * D_;
    const float *f2W = p.f2W + l * 4 * D_ * D_, *f2B = p.f2B + l * D_;

    __syncthreads();

    float o_all[128];
    float m1 = 0.f, rs1 = 1.f;
    if (hasrow) {
      float s = 0.f;
#pragma unroll 4
      for (int d = 0; d < D_; ++d) s += tok[tid][d];
      m1 = s * (1.f / 128.f);
      float var = 0.f;
#pragma unroll 4
      for (int d = 0; d < D_; ++d) { float t = tok[tid][d] - m1; var += t * t; }
      rs1 = rsqrtf(var * (1.f / 128.f) + 1e-5f);
    }
    for (int h = 0; h < NH_; ++h) {
      float qa[32];
      if (hasrow) {
        float ka[32], va[32];
#pragma unroll
        for (int c = 0; c < 32; ++c) {
          qa[c] = qkvB[h * 32 + c];
          ka[c] = qkvB[128 + h * 32 + c];
          va[c] = qkvB[256 + h * 32 + c];
        }
#pragma unroll 2
        for (int d = 0; d < D_; ++d) {
          float x = (tok[tid][d] - m1) * rs1 * ln1g[d] + ln1b[d];
#pragma unroll
          for (int c = 0; c < 32; ++c) {
            qa[c] = fmaf(x, qkvW[(h * 32 + c) * D_ + d], qa[c]);
            ka[c] = fmaf(x, qkvW[(128 + h * 32 + c) * D_ + d], ka[c]);
            va[c] = fmaf(x, qkvW[(256 + h * 32 + c) * D_ + d], va[c]);
          }
        }
        bf162 *row = kv2 + tid * KVS;
#pragma unroll
        for (int c2 = 0; c2 < 16; ++c2) {
          bf162 kk, vv;
          kk.x = __float2bfloat16(ka[2 * c2]);
          kk.y = __float2bfloat16(ka[2 * c2 + 1]);
          vv.x = __float2bfloat16(va[2 * c2]);
          vv.y = __float2bfloat16(va[2 * c2 + 1]);
          row[c2] = kk;
          row[16 + c2] = vv;
        }
      }
      __syncthreads();
      if (hasrow) {
        float mx = -1e30f, lsum = 0.f;
        float oa[32];
#pragma unroll
        for (int c = 0; c < 32; ++c) oa[c] = 0.f;
        for (int j = 0; j < S_; ++j) {
          const bf162 *rj = kv2 + j * KVS;
          float s = 0.f;
#pragma unroll
          for (int c2 = 0; c2 < 16; ++c2) {
            bf162 kk = rj[c2];
            s = fmaf(qa[2 * c2], __bfloat162float(kk.x), s);
            s = fmaf(qa[2 * c2 + 1], __bfloat162float(kk.y), s);
          }
          s *= 0.17677669529663687f;
          float mxn = fmaxf(mx, s);
          float corr = __expf(mx - mxn);
          float pw = __expf(s - mxn);
          mx = mxn;
          lsum = lsum * corr + pw;
#pragma unroll
          for (int c2 = 0; c2 < 16; ++c2) {
            bf162 vv = rj[16 + c2];
            oa[2 * c2]     = fmaf(pw, __bfloat162float(vv.x), oa[2 * c2] * corr);
            oa[2 * c2 + 1] = fmaf(pw, __bfloat162float(vv.y), oa[2 * c2 + 1] * corr);
          }
        }
        float inv = 1.f / lsum;
#pragma unroll
        for (int c = 0; c < 32; ++c) o_all[h * 32 + c] = oa[c] * inv;
      }
      __syncthreads();
    }

    if (hasrow) {
      for (int d = 0; d < D_; ++d) {
        float acc = oB[d];
#pragma unroll
        for (int c = 0; c < 128; ++c) acc = fmaf(o_all[c], oW[d * D_ + c], acc);
        tok[tid][d] += acc;
      }
    }

    if (hasrow) {
      float s = 0.f;
#pragma unroll 4
      for (int d = 0; d < D_; ++d) s += tok[tid][d];
      float m2 = s * (1.f / 128.f);
      float var = 0.f;
#pragma unroll 4
      for (int d = 0; d < D_; ++d) { float t = tok[tid][d] - m2; var += t * t; }
      float rs2 = rsqrtf(var * (1.f / 128.f) + 1e-5f);

      float *hrow = &scr[tid * 33];
      float outv[128];
#pragma unroll
      for (int i = 0; i < 128; ++i) outv[i] = f2B[i];
      for (int jc = 0; jc < 16; ++jc) {
        float hh[32];
#pragma unroll
        for (int jj = 0; jj < 32; ++jj) hh[jj] = f1B[jc * 32 + jj];
#pragma unroll 2
        for (int d = 0; d < D_; ++d) {
          float x = (tok[tid][d] - m2) * rs2 * ln2g[d] + ln2b[d];
#pragma unroll
          for (int jj = 0; jj < 32; ++jj)
            hh[jj] = fmaf(x, f1W[(jc * 32 + jj) * D_ + d], hh[jj]);
        }
#pragma unroll
        for (int jj = 0; jj < 32; ++jj) hrow[jj] = fmaxf(hh[jj], 0.f);
        for (int j2 = 0; j2 < 32; ++j2) {
          float hv = hrow[j2];
          int col = jc * 32 + j2;
#pragma unroll
          for (int i = 0; i < 128; ++i)
            outv[i] = fmaf(hv, f2W[i * 512 + col], outv[i]);
        }
      }
#pragma unroll
      for (int d = 0; d < D_; ++d) tok[tid][d] += outv[d];
    }
  }

  if (hasrow) {
    float s = 0.f;
#pragma unroll 4
    for (int d = 0; d < D_; ++d) s += tok[tid][d];
    float m = s * (1.f / 128.f);
    float var = 0.f;
#pragma unroll 4
    for (int d = 0; d < D_; ++d) { float t = tok[tid][d] - m; var += t * t; }
    float rs = rsqrtf(var * (1.f / 128.f) + 1e-5f);
#pragma unroll 2
    for (int d = 0; d < D_; ++d)
      tok[tid][d] = (tok[tid][d] - m) * rs * p.plng[d] + p.plnb[d];
  }
  __syncthreads();

  if (tid < D_) {
    float s = 0.f;
    for (int r = 0; r < S_; ++r) s += tok[r][tid];
    pooled[tid] = s * (1.f / (float)S_);
  }
  __syncthreads();
  if (tid < D_) {
    float a1 = p.atB1[tid], v1 = p.vlB1[tid];
    for (int k = 0; k < D_; ++k) {
      float pk = pooled[k];
      a1 = fmaf(pk, p.atW1[tid * D_ + k], a1);
      v1 = fmaf(pk, p.vlW1[tid * D_ + k], v1);
    }
    hid1[tid] = fmaxf(a1, 0.f);
    hid2[tid] = fmaxf(v1, 0.f);
  }
  __syncthreads();

  // ---- heads: FLOAT32 stores ----
  if (tid < H_) {
    float hh[64];
#pragma unroll
    for (int j = 0; j < 64; ++j) hh[j] = p.hxB1[j];
#pragma unroll 2
    for (int k = 0; k < D_; ++k) {
      float x = tok[tid][k];
#pragma unroll
      for (int j = 0; j < 64; ++j) hh[j] = fmaf(x, p.hxW1[j * D_ + k], hh[j]);
    }
    float o = p.hxB2[0];
#pragma unroll
    for (int j = 0; j < 64; ++j) o = fmaf(fmaxf(hh[j], 0.f), p.hxW2[j], o);
    p.out[OFF_HEX + b * H_ + tid] = o;
  }
  if (tid < NAT_) {
    float o = p.atB2[tid];
    for (int k = 0; k < D_; ++k) o = fmaf(hid1[k], p.atW2[tid * D_ + k], o);
    p.out[b * NAT_ + tid] = o;
  }
  if (tid == 190) {
    float o = p.vlB2[0];
    for (int k = 0; k < D_; ++k) o = fmaf(hid2[k], p.vlW2[k], o);
    p.out[OFF_VAL + b] = o;
  }
  if (tid >= 32 && tid < 32 + MS_) {
    int si = tid - 32;
    float o;
    if (svalid[si]) {
      int r = sposc[si];
      float hh[64];
#pragma unroll
      for (int j = 0; j < 64; ++j) hh[j] = p.tgB1[j];
#pragma unroll 2
      for (int k = 0; k < D_; ++k) {
        float x = tok[r][k];
#pragma unroll
        for (int j = 0; j < 64; ++j) hh[j] = fmaf(x, p.tgW1[j * D_ + k], hh[j]);
      }
      o = p.tgB2[0];
#pragma unroll
      for (int j = 0; j < 64; ++j) o = fmaf(fmaxf(hh[j], 0.f), p.tgW2[j], o);
    } else {
      o = -1e9f;
    }
    p.out[OFF_TGT + b * MS_ + si] = o;
  }
}

extern "C" void kernel_launch(void* const* d_in, const int* in_sizes, int n_in,
                              void* d_out, int out_size, void* d_ws, size_t ws_size,
                              hipStream_t stream) {
  (void)in_sizes; (void)n_in; (void)out_size; (void)d_ws; (void)ws_size;
  Params p;
  p.scalars = (const float *)d_in[0];
  p.stacks = (const float *)d_in[1];
  p.obstacles = (const float *)d_in[2];
  p.reach = (const float *)d_in[3];
  p.n_stacks = (const int *)d_in[4];
  p.cemb = (const float *)d_in[5];
  p.pos_emb = (const float *)d_in[6];
  p.tte = (const float *)d_in[7];
  p.hexW = (const float *)d_in[8];  p.hexB = (const float *)d_in[9];
  p.hexG = (const float *)d_in[10]; p.hexBe = (const float *)d_in[11];
  p.heroW = (const float *)d_in[12]; p.heroB = (const float *)d_in[13];
  p.heroG = (const float *)d_in[14]; p.heroBe = (const float *)d_in[15];
  p.gW = (const float *)d_in[16]; p.gB = (const float *)d_in[17];
  p.ln1g = (const float *)d_in[18]; p.ln1b = (const float *)d_in[19];
  p.qkvW = (const float *)d_in[20]; p.qkvB = (const float *)d_in[21];
  p.oW = (const float *)d_in[22]; p.oB = (const float *)d_in[23];
  p.ln2g = (const float *)d_in[24]; p.ln2b = (const float *)d_in[25];
  p.f1W = (const float *)d_in[26]; p.f1B = (const float *)d_in[27];
  p.f2W = (const float *)d_in[28]; p.f2B = (const float *)d_in[29];
  p.plng = (const float *)d_in[30]; p.plnb = (const float *)d_in[31];
  p.atW1 = (const float *)d_in[32]; p.atB1 = (const float *)d_in[33];
  p.atW2 = (const float *)d_in[34]; p.atB2 = (const float *)d_in[35];
  p.hxW1 = (const float *)d_in[36]; p.hxB1 = (const float *)d_in[37];
  p.hxW2 = (const float *)d_in[38]; p.hxB2 = (const float *)d_in[39];
  p.tgW1 = (const float *)d_in[40]; p.tgB1 = (const float *)d_in[41];
  p.tgW2 = (const float *)d_in[42]; p.tgB2 = (const float *)d_in[43];
  p.vlW1 = (const float *)d_in[44]; p.vlB1 = (const float *)d_in[45];
  p.vlW2 = (const float *)d_in[46]; p.vlB2 = (const float *)d_in[47];
  p.out = (float *)d_out;
  battle_kernel<<<dim3(B_), dim3(192), 0, stream>>>(p);
}

// Round 11
// 34335.025 us; speedup vs baseline: 2.0846x; 2.0846x over previous
//
#include <hip/hip_runtime.h>
#include <hip/hip_bf16.h>

#define DEV static __device__ __forceinline__

DEV unsigned short f2bf_rn(float x) {
  unsigned u = __float_as_uint(x);
  u = u + 0x7fffu + ((u >> 16) & 1u);
  return (unsigned short)(u >> 16);
}
DEV unsigned pack2(float a, float b) {
  return (unsigned)f2bf_rn(a) | ((unsigned)f2bf_rn(b) << 16);
}
DEV float lo2f(unsigned w) { return __uint_as_float(w << 16); }
DEV float hi2f(unsigned w) { return __uint_as_float(w & 0xffff0000u); }

constexpr int H_ = 187, MS_ = 20, MOB_ = 10, D_ = 128, NH_ = 4, NL_ = 4,
              CE_ = 16, NAT_ = 5, NCT_ = 256, HEXC_ = 29, B_ = 1024;
constexpr int S_ = H_ + 2;   // 189 tokens
constexpr int TP = D_ + 1;   // tok LDS stride in floats
constexpr int KVS = 68;      // scr row stride in floats (272B, 16B-aligned)

constexpr int OFF_HEX = B_ * NAT_;          // 5120
constexpr int OFF_TGT = OFF_HEX + B_ * H_;  // 196608
constexpr int OFF_VAL = OFF_TGT + B_ * MS_; // 217088

struct Params {
  const float *scalars, *stacks, *obstacles, *reach;
  const int  *n_stacks;
  const float *cemb, *pos_emb, *tte;
  const float *hexW, *hexB, *hexG, *hexBe;
  const float *heroW, *heroB, *heroG, *heroBe;
  const float *gW, *gB;
  const float *ln1g, *ln1b, *qkvW, *qkvB, *oW, *oB;
  const float *ln2g, *ln2b, *f1W, *f1B, *f2W, *f2B;
  const float *plng, *plnb;
  const float *atW1, *atB1, *atW2, *atB2;
  const float *hxW1, *hxB1, *hxW2, *hxB2;
  const float *tgW1, *tgB1, *tgW2, *tgB2;
  const float *vlW1, *vlB1, *vlW2, *vlB2;
  float *out;   // FLOAT32 output buffer
};

constexpr int SCR_FLOATS = 192 * KVS;  // 13056 floats = 52224 B

__global__ __launch_bounds__(192, 1) void battle_kernel(Params p) {
  __shared__ float tok[S_][TP];          // 97524 B
  __shared__ float scr[SCR_FLOATS];      // 52224 B
  __shared__ float gvec[D_];
  __shared__ float pooled[D_];
  __shared__ float hid1[D_];
  __shared__ float hid2[D_];
  __shared__ int   svalid[MS_];
  __shared__ int   sposc[MS_];

  const int b = blockIdx.x;
  const int tid = threadIdx.x;
  const bool hasrow = tid < S_;
  const float *sc = p.scalars + b * 19;

  float *hexcont = &scr[0];               // 187*29 = 5423 floats
  int   *cids    = (int *)&scr[5440];     // 187 ints
  float *obsch   = &scr[5632];            // 187 floats

  // ---- E0: global token bias ----
  if (tid < D_) {
    float g0 = sc[1] * 0.02f, g1 = sc[4] * 0.1f, g2 = sc[5] * 0.1f;
    float g3 = sc[6], g4 = sc[3];
    const float *w = p.gW + tid * 5;
    gvec[tid] = p.gB[tid] + g0 * w[0] + g1 * w[1] + g2 * w[2] + g3 * w[3] + g4 * w[4];
  }
  for (int i = tid; i < H_ * HEXC_; i += 192) hexcont[i] = 0.f;
  for (int i = tid; i < H_; i += 192) { cids[i] = 0; obsch[i] = 0.f; }
  __syncthreads();

  // ---- E2: stack scatter ----
  if (tid < MS_) {
    const float *st = p.stacks + (b * MS_ + tid) * 35;
    int pos = (int)st[18];
    float alive = st[23];
    int ns = p.n_stacks[b];
    bool valid = (pos >= 0) && (pos < H_) && (alive >= 0.5f) && (tid < ns);
    svalid[tid] = valid ? 1 : 0;
    sposc[tid] = min(max(pos, 0), H_ - 1);
    if (valid) {
      float maxhp = fmaxf(st[4], 1.0f);
      float *hc = hexcont + pos * HEXC_;
      hc[0] = 1.0f;
      hc[1] = st[2] * 1e-3f;
      hc[2] = st[3] / maxhp;
      hc[3] = st[8] * 0.01f;  hc[4] = st[9] * 0.01f;
      hc[5] = st[10] * 0.01f; hc[6] = st[11] * 0.01f;
      hc[7] = st[12] * 0.01f; hc[8] = st[13] * 0.01f;
      hc[9] = st[14] * 0.01f; hc[10] = st[15] * 0.01f;
      hc[11] = st[16] * 0.05f; hc[12] = st[17] * 0.05f;
      float s20 = st[20];
      hc[13] = s20;
      hc[14] = (s20 == sc[3]) ? 1.f : 0.f;
      hc[15] = alive;
      hc[16] = st[24]; hc[17] = st[25]; hc[18] = st[26];
      hc[19] = st[27]; hc[20] = st[28]; hc[21] = st[29];
      hc[22] = st[30];
      hc[23] = st[31] * (1.f / 30.f);
      hc[24] = st[33] * 0.2f;
      hc[25] = st[34] * 0.1f;
      hc[26] = (st[0] == sc[2]) ? 1.f : 0.f;
      hc[27] = 0.f; hc[28] = 0.f;
      cids[pos] = min((int)st[1], NCT_ - 1);
    }
  }
  if (tid >= 64 && tid < 64 + MOB_) {
    const float *ob = p.obstacles + (b * MOB_ + (tid - 64)) * 3;
    int opos = (int)ob[2];
    if (ob[0] > 0.f && opos >= 0 && opos < H_) obsch[opos] = 1.0f;
  }
  __syncthreads();

  // ---- E4/E5: build tokens ----
  if (tid < H_) {
    const int r = tid;
    float f[HEXC_ + CE_];
#pragma unroll
    for (int c = 0; c < HEXC_; ++c) f[c] = hexcont[r * HEXC_ + c];
    f[27] = p.reach[b * H_ + r];
    f[28] = obsch[r];
    int cid = cids[r];
#pragma unroll
    for (int e = 0; e < CE_; ++e) f[HEXC_ + e] = p.cemb[cid * CE_ + e];
    float sum = 0.f;
    for (int d = 0; d < D_; ++d) {
      const float *w = p.hexW + d * 45;
      float p0 = p.hexB[d], p1 = 0.f, p2 = 0.f, p3 = 0.f;
#pragma unroll
      for (int k = 0; k < 44; k += 4) {
        p0 = fmaf(f[k], w[k], p0);     p1 = fmaf(f[k + 1], w[k + 1], p1);
        p2 = fmaf(f[k + 2], w[k + 2], p2); p3 = fmaf(f[k + 3], w[k + 3], p3);
      }
      p0 = fmaf(f[44], w[44], p0);
      float acc = (p0 + p1) + (p2 + p3);
      tok[r][d] = acc; sum += acc;
    }
    float m = sum * (1.f / 128.f);
    float var = 0.f;
#pragma unroll 4
    for (int d = 0; d < D_; ++d) { float t = tok[r][d] - m; var += t * t; }
    float rs = rsqrtf(var * (1.f / 128.f) + 1e-5f);
#pragma unroll 2
    for (int d = 0; d < D_; ++d) {
      float v = (tok[r][d] - m) * rs * p.hexG[d] + p.hexBe[d];
      tok[r][d] = v + p.pos_emb[r * D_ + d] + p.tte[d] + gvec[d];
    }
  } else if (tid < S_) {
    const int which = tid - H_;
    float f0, f1, f2, f3, f4;
    if (which == 0) {
      f0 = sc[8];  f1 = sc[11] * (1.f / 300.f);
      f2 = sc[10] * 0.1f; f3 = sc[12] * 0.1f; f4 = 0.f;
    } else {
      f0 = sc[14]; f1 = sc[17] * (1.f / 300.f);
      f2 = sc[16] * 0.1f; f3 = sc[18] * 0.1f; f4 = 1.f;
    }
    const int r = tid;
    float sum = 0.f;
#pragma unroll 2
    for (int d = 0; d < D_; ++d) {
      const float *w = p.heroW + d * 5;
      float acc = p.heroB[d] + f0 * w[0] + f1 * w[1] + f2 * w[2] + f3 * w[3] + f4 * w[4];
      tok[r][d] = acc; sum += acc;
    }
    float m = sum * (1.f / 128.f);
    float var = 0.f;
    for (int d = 0; d < D_; ++d) { float t = tok[r][d] - m; var += t * t; }
    float rs = rsqrtf(var * (1.f / 128.f) + 1e-5f);
#pragma unroll 2
    for (int d = 0; d < D_; ++d) {
      float v = (tok[r][d] - m) * rs * p.heroG[d] + p.heroBe[d];
      tok[r][d] = v + p.tte[(1 + which) * D_ + d] + gvec[d];
    }
  }

  float *kvrow = &scr[tid * KVS];

  // ---- transformer layers ----
  for (int l = 0; l < NL_; ++l) {
    const float *ln1g = p.ln1g + l * D_, *ln1b = p.ln1b + l * D_;
    const float *qkvW = p.qkvW + l * 3 * D_ * D_, *qkvB = p.qkvB + l * 3 * D_;
    const float *oW = p.oW + l * D_ * D_, *oB = p.oB + l * D_;
    const float *ln2g = p.ln2g + l * D_, *ln2b = p.ln2b + l * D_;
    const float *f1W = p.f1W + l * 4 * D_ * D_, *f1B = p.f1B + l * 4 * D_;
    const float *f2W = p.f2W + l * 4 * D_ * D_, *f2B = p.f2B + l * D_;

    __syncthreads();  // scr region reuse fence

    float m1 = 0.f, rs1 = 1.f;
    if (hasrow) {
      float s0 = 0.f, s1 = 0.f, s2 = 0.f, s3 = 0.f;
#pragma unroll 8
      for (int d = 0; d < D_; d += 4) {
        s0 += tok[tid][d]; s1 += tok[tid][d + 1];
        s2 += tok[tid][d + 2]; s3 += tok[tid][d + 3];
      }
      m1 = ((s0 + s1) + (s2 + s3)) * (1.f / 128.f);
      float v0 = 0.f, v1 = 0.f, v2 = 0.f, v3 = 0.f;
#pragma unroll 8
      for (int d = 0; d < D_; d += 4) {
        float t0 = tok[tid][d] - m1, t1 = tok[tid][d + 1] - m1;
        float t2 = tok[tid][d + 2] - m1, t3 = tok[tid][d + 3] - m1;
        v0 = fmaf(t0, t0, v0); v1 = fmaf(t1, t1, v1);
        v2 = fmaf(t2, t2, v2); v3 = fmaf(t3, t3, v3);
      }
      rs1 = rsqrtf(((v0 + v1) + (v2 + v3)) * (1.f / 128.f) + 1e-5f);
    }

    unsigned oall2[64];  // bf16-packed attention outputs, 4 heads x 16 u32

    for (int h = 0; h < NH_; ++h) {
      float acc[96];  // q[0:32), k[32:64), v[64:96)
      if (hasrow) {
#pragma unroll
        for (int c = 0; c < 32; ++c) {
          acc[c]      = qkvB[h * 32 + c];
          acc[32 + c] = qkvB[128 + h * 32 + c];
          acc[64 + c] = qkvB[256 + h * 32 + c];
        }
        for (int dblk = 0; dblk < 8; ++dblk) {
          float xr[16];
#pragma unroll
          for (int i = 0; i < 16; ++i) {
            int d = dblk * 16 + i;
            xr[i] = (tok[tid][d] - m1) * rs1 * ln1g[d] + ln1b[d];
          }
          const float *wq = qkvW + (h * 32) * D_ + dblk * 16;
          const float *wk = qkvW + (128 + h * 32) * D_ + dblk * 16;
          const float *wv = qkvW + (256 + h * 32) * D_ + dblk * 16;
#pragma unroll
          for (int c = 0; c < 32; ++c) {
#pragma unroll
            for (int i = 0; i < 16; ++i) {
              acc[c]      = fmaf(xr[i], wq[c * D_ + i], acc[c]);
              acc[32 + c] = fmaf(xr[i], wk[c * D_ + i], acc[32 + c]);
              acc[64 + c] = fmaf(xr[i], wv[c * D_ + i], acc[64 + c]);
            }
          }
        }
#pragma unroll
        for (int c = 0; c < 32; ++c) {
          kvrow[c]      = acc[32 + c];
          kvrow[32 + c] = acc[64 + c];
        }
      }
      __syncthreads();
      if (hasrow) {
        float mx = -1e30f, lsum = 0.f;
        float oa[32];
#pragma unroll
        for (int c = 0; c < 32; ++c) oa[c] = 0.f;
        for (int j = 0; j < S_; ++j) {
          const float *kr = &scr[j * KVS];
          float s0 = 0.f, s1 = 0.f, s2 = 0.f, s3 = 0.f;
#pragma unroll
          for (int c = 0; c < 32; c += 4) {
            s0 = fmaf(acc[c], kr[c], s0);
            s1 = fmaf(acc[c + 1], kr[c + 1], s1);
            s2 = fmaf(acc[c + 2], kr[c + 2], s2);
            s3 = fmaf(acc[c + 3], kr[c + 3], s3);
          }
          float s = ((s0 + s1) + (s2 + s3)) * 0.17677669529663687f;
          float mxn = fmaxf(mx, s);
          float corr = __expf(mx - mxn);
          float pw = __expf(s - mxn);
          mx = mxn;
          lsum = lsum * corr + pw;
#pragma unroll
          for (int c = 0; c < 32; ++c)
            oa[c] = fmaf(pw, kr[32 + c], oa[c] * corr);
        }
        float inv = 1.f / lsum;
#pragma unroll
        for (int c2 = 0; c2 < 16; ++c2)
          oall2[h * 16 + c2] = pack2(oa[2 * c2] * inv, oa[2 * c2 + 1] * inv);
      }
      __syncthreads();
    }

    // O-projection + residual (contiguous weights, 4 partials)
    if (hasrow) {
      for (int d = 0; d < D_; ++d) {
        const float *wo = oW + d * D_;
        float p0 = oB[d], p1 = 0.f, p2 = 0.f, p3 = 0.f;
#pragma unroll
        for (int c2 = 0; c2 < 64; c2 += 2) {
          unsigned w0 = oall2[c2], w1 = oall2[c2 + 1];
          p0 = fmaf(lo2f(w0), wo[2 * c2], p0);
          p1 = fmaf(hi2f(w0), wo[2 * c2 + 1], p1);
          p2 = fmaf(lo2f(w1), wo[2 * c2 + 2], p2);
          p3 = fmaf(hi2f(w1), wo[2 * c2 + 3], p3);
        }
        tok[tid][d] += (p0 + p1) + (p2 + p3);
      }
    }

    // FFN (jc chunks of 32 hidden; weights contiguous in inner loops)
    if (hasrow) {
      float s0 = 0.f, s1 = 0.f, s2 = 0.f, s3 = 0.f;
#pragma unroll 8
      for (int d = 0; d < D_; d += 4) {
        s0 += tok[tid][d]; s1 += tok[tid][d + 1];
        s2 += tok[tid][d + 2]; s3 += tok[tid][d + 3];
      }
      float m2 = ((s0 + s1) + (s2 + s3)) * (1.f / 128.f);
      float v0 = 0.f, v1 = 0.f, v2 = 0.f, v3 = 0.f;
#pragma unroll 8
      for (int d = 0; d < D_; d += 4) {
        float t0 = tok[tid][d] - m2, t1 = tok[tid][d + 1] - m2;
        float t2 = tok[tid][d + 2] - m2, t3 = tok[tid][d + 3] - m2;
        v0 = fmaf(t0, t0, v0); v1 = fmaf(t1, t1, v1);
        v2 = fmaf(t2, t2, v2); v3 = fmaf(t3, t3, v3);
      }
      float rs2 = rsqrtf(((v0 + v1) + (v2 + v3)) * (1.f / 128.f) + 1e-5f);

      float outv[128];
#pragma unroll
      for (int i = 0; i < 128; ++i) outv[i] = f2B[i];

      for (int jc = 0; jc < 16; ++jc) {
        float hacc[32];
#pragma unroll
        for (int jj = 0; jj < 32; ++jj) hacc[jj] = f1B[jc * 32 + jj];
        for (int dblk = 0; dblk < 8; ++dblk) {
          float xr[16];
#pragma unroll
          for (int i = 0; i < 16; ++i) {
            int d = dblk * 16 + i;
            xr[i] = (tok[tid][d] - m2) * rs2 * ln2g[d] + ln2b[d];
          }
          const float *w1 = f1W + (jc * 32) * D_ + dblk * 16;
#pragma unroll
          for (int jj = 0; jj < 32; ++jj) {
#pragma unroll
            for (int i = 0; i < 16; ++i)
              hacc[jj] = fmaf(xr[i], w1[jj * D_ + i], hacc[jj]);
          }
        }
#pragma unroll
        for (int jj = 0; jj < 32; ++jj) kvrow[jj] = fmaxf(hacc[jj], 0.f);
        for (int colq = 0; colq < 2; ++colq) {
          float hq[16];
#pragma unroll
          for (int cc = 0; cc < 16; ++cc) hq[cc] = kvrow[colq * 16 + cc];
          const float *w2 = f2W + jc * 32 + colq * 16;
#pragma unroll
          for (int ic = 0; ic < 8; ++ic) {
#pragma unroll
            for (int ii = 0; ii < 16; ++ii) {
              const float *w2r = w2 + (ic * 16 + ii) * 512;
              float q0 = 0.f, q1 = 0.f, q2 = 0.f, q3 = 0.f;
#pragma unroll
              for (int cc = 0; cc < 16; cc += 4) {
                q0 = fmaf(hq[cc], w2r[cc], q0);
                q1 = fmaf(hq[cc + 1], w2r[cc + 1], q1);
                q2 = fmaf(hq[cc + 2], w2r[cc + 2], q2);
                q3 = fmaf(hq[cc + 3], w2r[cc + 3], q3);
              }
              outv[ic * 16 + ii] += (q0 + q1) + (q2 + q3);
            }
          }
        }
      }
#pragma unroll
      for (int d = 0; d < D_; ++d) tok[tid][d] += outv[d];
    }
  }

  // ---- post-LN ----
  if (hasrow) {
    float s0 = 0.f, s1 = 0.f, s2 = 0.f, s3 = 0.f;
#pragma unroll 8
    for (int d = 0; d < D_; d += 4) {
      s0 += tok[tid][d]; s1 += tok[tid][d + 1];
      s2 += tok[tid][d + 2]; s3 += tok[tid][d + 3];
    }
    float m = ((s0 + s1) + (s2 + s3)) * (1.f / 128.f);
    float v0 = 0.f, v1 = 0.f, v2 = 0.f, v3 = 0.f;
#pragma unroll 8
    for (int d = 0; d < D_; d += 4) {
      float t0 = tok[tid][d] - m, t1 = tok[tid][d + 1] - m;
      float t2 = tok[tid][d + 2] - m, t3 = tok[tid][d + 3] - m;
      v0 = fmaf(t0, t0, v0); v1 = fmaf(t1, t1, v1);
      v2 = fmaf(t2, t2, v2); v3 = fmaf(t3, t3, v3);
    }
    float rs = rsqrtf(((v0 + v1) + (v2 + v3)) * (1.f / 128.f) + 1e-5f);
#pragma unroll 2
    for (int d = 0; d < D_; ++d)
      tok[tid][d] = (tok[tid][d] - m) * rs * p.plng[d] + p.plnb[d];
  }
  __syncthreads();

  // ---- pooled mean ----
  if (tid < D_) {
    float s0 = 0.f, s1 = 0.f, s2 = 0.f, s3 = 0.f;
    int r = 0;
    for (; r + 4 <= S_; r += 4) {
      s0 += tok[r][tid]; s1 += tok[r + 1][tid];
      s2 += tok[r + 2][tid]; s3 += tok[r + 3][tid];
    }
    for (; r < S_; ++r) s0 += tok[r][tid];
    pooled[tid] = ((s0 + s1) + (s2 + s3)) * (1.f / (float)S_);
  }
  __syncthreads();
  if (tid < D_) {
    const float *wa = p.atW1 + tid * D_;
    const float *wv = p.vlW1 + tid * D_;
    float a0 = p.atB1[tid], a1 = 0.f, vv0 = p.vlB1[tid], vv1 = 0.f;
#pragma unroll 4
    for (int k = 0; k < D_; k += 2) {
      float pk0 = pooled[k], pk1 = pooled[k + 1];
      a0 = fmaf(pk0, wa[k], a0);   a1 = fmaf(pk1, wa[k + 1], a1);
      vv0 = fmaf(pk0, wv[k], vv0); vv1 = fmaf(pk1, wv[k + 1], vv1);
    }
    hid1[tid] = fmaxf(a0 + a1, 0.f);
    hid2[tid] = fmaxf(vv0 + vv1, 0.f);
  }
  __syncthreads();

  // ---- hex head (dblk-structured, contiguous weights) ----
  if (tid < H_) {
    float hh[64];
#pragma unroll
    for (int j = 0; j < 64; ++j) hh[j] = p.hxB1[j];
    for (int kb = 0; kb < 8; ++kb) {
      float xr[16];
#pragma unroll
      for (int i = 0; i < 16; ++i) xr[i] = tok[tid][kb * 16 + i];
      const float *w = p.hxW1 + kb * 16;
#pragma unroll
      for (int j = 0; j < 64; ++j) {
#pragma unroll
        for (int i = 0; i < 16; ++i)
          hh[j] = fmaf(xr[i], w[j * D_ + i], hh[j]);
      }
    }
    float o = p.hxB2[0];
#pragma unroll
    for (int j = 0; j < 64; ++j) o = fmaf(fmaxf(hh[j], 0.f), p.hxW2[j], o);
    p.out[OFF_HEX + b * H_ + tid] = o;
  }
  // ---- action-type logits ----
  if (tid < NAT_) {
    const float *w = p.atW2 + tid * D_;
    float o0 = p.atB2[tid], o1 = 0.f, o2 = 0.f, o3 = 0.f;
#pragma unroll 4
    for (int k = 0; k < D_; k += 4) {
      o0 = fmaf(hid1[k], w[k], o0);     o1 = fmaf(hid1[k + 1], w[k + 1], o1);
      o2 = fmaf(hid1[k + 2], w[k + 2], o2); o3 = fmaf(hid1[k + 3], w[k + 3], o3);
    }
    p.out[b * NAT_ + tid] = (o0 + o1) + (o2 + o3);
  }
  // ---- value ----
  if (tid == 190) {
    float o0 = p.vlB2[0], o1 = 0.f, o2 = 0.f, o3 = 0.f;
#pragma unroll 4
    for (int k = 0; k < D_; k += 4) {
      o0 = fmaf(hid2[k], p.vlW2[k], o0);     o1 = fmaf(hid2[k + 1], p.vlW2[k + 1], o1);
      o2 = fmaf(hid2[k + 2], p.vlW2[k + 2], o2); o3 = fmaf(hid2[k + 3], p.vlW2[k + 3], o3);
    }
    p.out[OFF_VAL + b] = (o0 + o1) + (o2 + o3);
  }
  // ---- target logits ----
  if (tid >= 32 && tid < 32 + MS_) {
    int si = tid - 32;
    float o;
    if (svalid[si]) {
      int r = sposc[si];
      float hh[64];
#pragma unroll
      for (int j = 0; j < 64; ++j) hh[j] = p.tgB1[j];
      for (int kb = 0; kb < 8; ++kb) {
        float xr[16];
#pragma unroll
        for (int i = 0; i < 16; ++i) xr[i] = tok[r][kb * 16 + i];
        const float *w = p.tgW1 + kb * 16;
#pragma unroll
        for (int j = 0; j < 64; ++j) {
#pragma unroll
          for (int i = 0; i < 16; ++i)
            hh[j] = fmaf(xr[i], w[j * D_ + i], hh[j]);
        }
      }
      o = p.tgB2[0];
#pragma unroll
      for (int j = 0; j < 64; ++j) o = fmaf(fmaxf(hh[j], 0.f), p.tgW2[j], o);
    } else {
      o = -1e9f;
    }
    p.out[OFF_TGT + b * MS_ + si] = o;
  }
}

extern "C" void kernel_launch(void* const* d_in, const int* in_sizes, int n_in,
                              void* d_out, int out_size, void* d_ws, size_t ws_size,
                              hipStream_t stream) {
  (void)in_sizes; (void)n_in; (void)out_size; (void)d_ws; (void)ws_size;
  Params p;
  p.scalars = (const float *)d_in[0];
  p.stacks = (const float *)d_in[1];
  p.obstacles = (const float *)d_in[2];
  p.reach = (const float *)d_in[3];
  p.n_stacks = (const int *)d_in[4];
  p.cemb = (const float *)d_in[5];
  p.pos_emb = (const float *)d_in[6];
  p.tte = (const float *)d_in[7];
  p.hexW = (const float *)d_in[8];  p.hexB = (const float *)d_in[9];
  p.hexG = (const float *)d_in[10]; p.hexBe = (const float *)d_in[11];
  p.heroW = (const float *)d_in[12]; p.heroB = (const float *)d_in[13];
  p.heroG = (const float *)d_in[14]; p.heroBe = (const float *)d_in[15];
  p.gW = (const float *)d_in[16]; p.gB = (const float *)d_in[17];
  p.ln1g = (const float *)d_in[18]; p.ln1b = (const float *)d_in[19];
  p.qkvW = (const float *)d_in[20]; p.qkvB = (const float *)d_in[21];
  p.oW = (const float *)d_in[22]; p.oB = (const float *)d_in[23];
  p.ln2g = (const float *)d_in[24]; p.ln2b = (const float *)d_in[25];
  p.f1W = (const float *)d_in[26]; p.f1B = (const float *)d_in[27];
  p.f2W = (const float *)d_in[28]; p.f2B = (const float *)d_in[29];
  p.plng = (const float *)d_in[30]; p.plnb = (const float *)d_in[31];
  p.atW1 = (const float *)d_in[32]; p.atB1 = (const float *)d_in[33];
  p.atW2 = (const float *)d_in[34]; p.atB2 = (const float *)d_in[35];
  p.hxW1 = (const float *)d_in[36]; p.hxB1 = (const float *)d_in[37];
  p.hxW2 = (const float *)d_in[38]; p.hxB2 = (const float *)d_in[39];
  p.tgW1 = (const float *)d_in[40]; p.tgB1 = (const float *)d_in[41];
  p.tgW2 = (const float *)d_in[42]; p.tgB2 = (const float *)d_in[43];
  p.vlW1 = (const float *)d_in[44]; p.vlB1 = (const float *)d_in[45];
  p.vlW2 = (const float *)d_in[46]; p.vlB2 = (const float *)d_in[47];
  p.out = (float *)d_out;
  battle_kernel<<<dim3(B_), dim3(192), 0, stream>>>(p);
}

// Round 12
// 34155.219 us; speedup vs baseline: 2.0956x; 1.0053x over previous
//
#include <hip/hip_runtime.h>
#include <hip/hip_bf16.h>

#define DEV static __device__ __forceinline__

DEV unsigned short f2bf_rn(float x) {
  unsigned u = __float_as_uint(x);
  u = u + 0x7fffu + ((u >> 16) & 1u);
  return (unsigned short)(u >> 16);
}
DEV unsigned pack2(float a, float b) {
  return (unsigned)f2bf_rn(a) | ((unsigned)f2bf_rn(b) << 16);
}
DEV float lo2f(unsigned w) { return __uint_as_float(w << 16); }
DEV float hi2f(unsigned w) { return __uint_as_float(w & 0xffff0000u); }

constexpr int H_ = 187, MS_ = 20, MOB_ = 10, D_ = 128, NH_ = 4, NL_ = 4,
              CE_ = 16, NAT_ = 5, NCT_ = 256, HEXC_ = 29, B_ = 1024;
constexpr int S_ = H_ + 2;   // 189 tokens
constexpr int TOKU = 65;     // tok row stride in u32 (64 bf16-pairs + pad)
constexpr int KVU = 33;      // kv row stride in u32 (16 K-pairs, 16 V-pairs, pad)

constexpr int OFF_HEX = B_ * NAT_;          // 5120
constexpr int OFF_TGT = OFF_HEX + B_ * H_;  // 196608
constexpr int OFF_VAL = OFF_TGT + B_ * MS_; // 217088

struct Params {
  const float *scalars, *stacks, *obstacles, *reach;
  const int  *n_stacks;
  const float *cemb, *pos_emb, *tte;
  const float *hexW, *hexB, *hexG, *hexBe;
  const float *heroW, *heroB, *heroG, *heroBe;
  const float *gW, *gB;
  const float *ln1g, *ln1b, *qkvW, *qkvB, *oW, *oB;
  const float *ln2g, *ln2b, *f1W, *f1B, *f2W, *f2B;
  const float *plng, *plnb;
  const float *atW1, *atB1, *atW2, *atB2;
  const float *hxW1, *hxB1, *hxW2, *hxB2;
  const float *tgW1, *tgB1, *tgW2, *tgB2;
  const float *vlW1, *vlB1, *vlW2, *vlB2;
  float *out;   // FLOAT32 output buffer
};

// LDS budget: tokp 49,140 + kvb 25,344 + 2,048 + 160 = ~76.7 KB -> 2 blocks/CU
__global__ __launch_bounds__(192, 2) void battle_kernel(Params p) {
  __shared__ unsigned tokp[S_][TOKU];   // tokens, bf16-packed pairs
  __shared__ unsigned kvb[192][KVU];    // K/V per row (also embed scratch)
  __shared__ float gvec[D_];
  __shared__ float pooled[D_];
  __shared__ float hid1[D_];
  __shared__ float hid2[D_];
  __shared__ int   svalid[MS_];
  __shared__ int   sposc[MS_];

  const int b = blockIdx.x;
  const int tid = threadIdx.x;
  const bool hasrow = tid < S_;
  const float *sc = p.scalars + b * 19;

  float *hexcont = (float *)&kvb[0][0];     // [0, 5423) floats
  int   *cids    = (int *)&kvb[0][0] + 5440; // 187 ints
  float *obsch   = (float *)&kvb[0][0] + 5632; // 187 floats  (5819 < 192*33=6336)

  // ---- E0: global token bias ----
  if (tid < D_) {
    float g0 = sc[1] * 0.02f, g1 = sc[4] * 0.1f, g2 = sc[5] * 0.1f;
    float g3 = sc[6], g4 = sc[3];
    const float *w = p.gW + tid * 5;
    gvec[tid] = p.gB[tid] + g0 * w[0] + g1 * w[1] + g2 * w[2] + g3 * w[3] + g4 * w[4];
  }
  for (int i = tid; i < H_ * HEXC_; i += 192) hexcont[i] = 0.f;
  for (int i = tid; i < H_; i += 192) { cids[i] = 0; obsch[i] = 0.f; }
  __syncthreads();

  // ---- E2: stack scatter ----
  if (tid < MS_) {
    const float *st = p.stacks + (b * MS_ + tid) * 35;
    int pos = (int)st[18];
    float alive = st[23];
    int ns = p.n_stacks[b];
    bool valid = (pos >= 0) && (pos < H_) && (alive >= 0.5f) && (tid < ns);
    svalid[tid] = valid ? 1 : 0;
    sposc[tid] = min(max(pos, 0), H_ - 1);
    if (valid) {
      float maxhp = fmaxf(st[4], 1.0f);
      float *hc = hexcont + pos * HEXC_;
      hc[0] = 1.0f;
      hc[1] = st[2] * 1e-3f;
      hc[2] = st[3] / maxhp;
      hc[3] = st[8] * 0.01f;  hc[4] = st[9] * 0.01f;
      hc[5] = st[10] * 0.01f; hc[6] = st[11] * 0.01f;
      hc[7] = st[12] * 0.01f; hc[8] = st[13] * 0.01f;
      hc[9] = st[14] * 0.01f; hc[10] = st[15] * 0.01f;
      hc[11] = st[16] * 0.05f; hc[12] = st[17] * 0.05f;
      float s20 = st[20];
      hc[13] = s20;
      hc[14] = (s20 == sc[3]) ? 1.f : 0.f;
      hc[15] = alive;
      hc[16] = st[24]; hc[17] = st[25]; hc[18] = st[26];
      hc[19] = st[27]; hc[20] = st[28]; hc[21] = st[29];
      hc[22] = st[30];
      hc[23] = st[31] * (1.f / 30.f);
      hc[24] = st[33] * 0.2f;
      hc[25] = st[34] * 0.1f;
      hc[26] = (st[0] == sc[2]) ? 1.f : 0.f;
      hc[27] = 0.f; hc[28] = 0.f;
      cids[pos] = min((int)st[1], NCT_ - 1);
    }
  }
  if (tid >= 64 && tid < 64 + MOB_) {
    const float *ob = p.obstacles + (b * MOB_ + (tid - 64)) * 3;
    int opos = (int)ob[2];
    if (ob[0] > 0.f && opos >= 0 && opos < H_) obsch[opos] = 1.0f;
  }
  __syncthreads();

  // ---- E4/E5: build tokens (bf16-packed into tokp) ----
  if (tid < H_) {
    const int r = tid;
    float f[HEXC_ + CE_];
#pragma unroll
    for (int c = 0; c < HEXC_; ++c) f[c] = hexcont[r * HEXC_ + c];
    f[27] = p.reach[b * H_ + r];
    f[28] = obsch[r];
    int cid = cids[r];
#pragma unroll
    for (int e = 0; e < CE_; ++e) f[HEXC_ + e] = p.cemb[cid * CE_ + e];
    float sum = 0.f;
    float rowv[2];
    // barrier below must be hit by all; stage into registers then write after sync
    __syncthreads();  // hexcont reads done block-wide before kvb reuse later
    (void)rowv;
    for (int d2 = 0; d2 < 64; ++d2) {
      const float *w0 = p.hexW + (2 * d2) * 45;
      const float *w1 = w0 + 45;
      float a0 = p.hexB[2 * d2], a1 = 0.f, a2 = 0.f, a3 = 0.f;
      float b0 = p.hexB[2 * d2 + 1], b1 = 0.f, b2 = 0.f, b3 = 0.f;
#pragma unroll
      for (int k = 0; k < 44; k += 4) {
        a0 = fmaf(f[k], w0[k], a0);       a1 = fmaf(f[k + 1], w0[k + 1], a1);
        a2 = fmaf(f[k + 2], w0[k + 2], a2); a3 = fmaf(f[k + 3], w0[k + 3], a3);
        b0 = fmaf(f[k], w1[k], b0);       b1 = fmaf(f[k + 1], w1[k + 1], b1);
        b2 = fmaf(f[k + 2], w1[k + 2], b2); b3 = fmaf(f[k + 3], w1[k + 3], b3);
      }
      a0 = fmaf(f[44], w0[44], a0);
      b0 = fmaf(f[44], w1[44], b0);
      float va = (a0 + a1) + (a2 + a3), vb = (b0 + b1) + (b2 + b3);
      tokp[r][d2] = pack2(va, vb);
      sum += va + vb;
    }
    float m = sum * (1.f / 128.f);
    float var = 0.f;
#pragma unroll 4
    for (int d2 = 0; d2 < 64; ++d2) {
      unsigned w = tokp[r][d2];
      float t0 = lo2f(w) - m, t1 = hi2f(w) - m;
      var = fmaf(t0, t0, var); var = fmaf(t1, t1, var);
    }
    float rs = rsqrtf(var * (1.f / 128.f) + 1e-5f);
#pragma unroll 2
    for (int d2 = 0; d2 < 64; ++d2) {
      unsigned w = tokp[r][d2];
      int d = 2 * d2;
      float v0 = (lo2f(w) - m) * rs * p.hexG[d] + p.hexBe[d] +
                 p.pos_emb[r * D_ + d] + p.tte[d] + gvec[d];
      float v1 = (hi2f(w) - m) * rs * p.hexG[d + 1] + p.hexBe[d + 1] +
                 p.pos_emb[r * D_ + d + 1] + p.tte[d + 1] + gvec[d + 1];
      tokp[r][d2] = pack2(v0, v1);
    }
  } else {
    __syncthreads();  // matching barrier for non-hex threads
    if (tid < S_) {
      const int which = tid - H_;
      float f0, f1, f2, f3, f4;
      if (which == 0) {
        f0 = sc[8];  f1 = sc[11] * (1.f / 300.f);
        f2 = sc[10] * 0.1f; f3 = sc[12] * 0.1f; f4 = 0.f;
      } else {
        f0 = sc[14]; f1 = sc[17] * (1.f / 300.f);
        f2 = sc[16] * 0.1f; f3 = sc[18] * 0.1f; f4 = 1.f;
      }
      const int r = tid;
      float sum = 0.f;
      for (int d2 = 0; d2 < 64; ++d2) {
        const float *w0 = p.heroW + (2 * d2) * 5;
        const float *w1 = w0 + 5;
        float va = p.heroB[2 * d2] + f0 * w0[0] + f1 * w0[1] + f2 * w0[2] + f3 * w0[3] + f4 * w0[4];
        float vb = p.heroB[2 * d2 + 1] + f0 * w1[0] + f1 * w1[1] + f2 * w1[2] + f3 * w1[3] + f4 * w1[4];
        tokp[r][d2] = pack2(va, vb);
        sum += va + vb;
      }
      float m = sum * (1.f / 128.f);
      float var = 0.f;
      for (int d2 = 0; d2 < 64; ++d2) {
        unsigned w = tokp[r][d2];
        float t0 = lo2f(w) - m, t1 = hi2f(w) - m;
        var = fmaf(t0, t0, var); var = fmaf(t1, t1, var);
      }
      float rs = rsqrtf(var * (1.f / 128.f) + 1e-5f);
      for (int d2 = 0; d2 < 64; ++d2) {
        unsigned w = tokp[r][d2];
        int d = 2 * d2;
        float v0 = (lo2f(w) - m) * rs * p.heroG[d] + p.heroBe[d] +
                   p.tte[(1 + which) * D_ + d] + gvec[d];
        float v1 = (hi2f(w) - m) * rs * p.heroG[d + 1] + p.heroBe[d + 1] +
                   p.tte[(1 + which) * D_ + d + 1] + gvec[d + 1];
        tokp[r][d2] = pack2(v0, v1);
      }
    }
  }

  unsigned *kvrow = &kvb[tid][0];

  // ---- transformer layers ----
  for (int l = 0; l < NL_; ++l) {
    const float *ln1g = p.ln1g + l * D_, *ln1b = p.ln1b + l * D_;
    const float *qkvW = p.qkvW + l * 3 * D_ * D_, *qkvB = p.qkvB + l * 3 * D_;
    const float *oW = p.oW + l * D_ * D_, *oB = p.oB + l * D_;
    const float *ln2g = p.ln2g + l * D_, *ln2b = p.ln2b + l * D_;
    const float *f1W = p.f1W + l * 4 * D_ * D_, *f1B = p.f1B + l * 4 * D_;
    const float *f2W = p.f2W + l * 4 * D_ * D_, *f2B = p.f2B + l * D_;

    __syncthreads();  // kvb reuse fence

    float m1 = 0.f, rs1 = 1.f;
    if (hasrow) {
      float s0 = 0.f, s1 = 0.f;
#pragma unroll 8
      for (int d2 = 0; d2 < 64; ++d2) {
        unsigned w = tokp[tid][d2];
        s0 += lo2f(w); s1 += hi2f(w);
      }
      m1 = (s0 + s1) * (1.f / 128.f);
      float v0 = 0.f, v1 = 0.f;
#pragma unroll 8
      for (int d2 = 0; d2 < 64; ++d2) {
        unsigned w = tokp[tid][d2];
        float t0 = lo2f(w) - m1, t1 = hi2f(w) - m1;
        v0 = fmaf(t0, t0, v0); v1 = fmaf(t1, t1, v1);
      }
      rs1 = rsqrtf((v0 + v1) * (1.f / 128.f) + 1e-5f);
    }

    unsigned oall2[64];  // bf16-packed attention outputs

    for (int h = 0; h < NH_; ++h) {
      float acc[96];  // q[0:32), k[32:64), v[64:96)
      if (hasrow) {
#pragma unroll
        for (int c = 0; c < 32; ++c) {
          acc[c]      = qkvB[h * 32 + c];
          acc[32 + c] = qkvB[128 + h * 32 + c];
          acc[64 + c] = qkvB[256 + h * 32 + c];
        }
        for (int dblk = 0; dblk < 8; ++dblk) {
          float xr[16];
#pragma unroll
          for (int i2 = 0; i2 < 8; ++i2) {
            unsigned w = tokp[tid][dblk * 8 + i2];
            int d = dblk * 16 + 2 * i2;
            xr[2 * i2]     = (lo2f(w) - m1) * rs1 * ln1g[d] + ln1b[d];
            xr[2 * i2 + 1] = (hi2f(w) - m1) * rs1 * ln1g[d + 1] + ln1b[d + 1];
          }
          const float *wq = qkvW + (h * 32) * D_ + dblk * 16;
          const float *wk = qkvW + (128 + h * 32) * D_ + dblk * 16;
          const float *wv = qkvW + (256 + h * 32) * D_ + dblk * 16;
#pragma unroll
          for (int c = 0; c < 32; ++c) {
#pragma unroll
            for (int i = 0; i < 16; ++i) {
              acc[c]      = fmaf(xr[i], wq[c * D_ + i], acc[c]);
              acc[32 + c] = fmaf(xr[i], wk[c * D_ + i], acc[32 + c]);
              acc[64 + c] = fmaf(xr[i], wv[c * D_ + i], acc[64 + c]);
            }
          }
        }
#pragma unroll
        for (int c2 = 0; c2 < 16; ++c2) {
          kvrow[c2]      = pack2(acc[32 + 2 * c2], acc[32 + 2 * c2 + 1]);
          kvrow[16 + c2] = pack2(acc[64 + 2 * c2], acc[64 + 2 * c2 + 1]);
        }
      }
      __syncthreads();
      if (hasrow) {
        float mx = -1e30f, lsum = 0.f;
        float oa[32];
#pragma unroll
        for (int c = 0; c < 32; ++c) oa[c] = 0.f;
        for (int j = 0; j < S_; ++j) {
          const unsigned *kr = &kvb[j][0];
          float s0 = 0.f, s1 = 0.f, s2 = 0.f, s3 = 0.f;
#pragma unroll
          for (int c2 = 0; c2 < 16; c2 += 2) {
            unsigned w0 = kr[c2], w1 = kr[c2 + 1];
            s0 = fmaf(acc[2 * c2], lo2f(w0), s0);
            s1 = fmaf(acc[2 * c2 + 1], hi2f(w0), s1);
            s2 = fmaf(acc[2 * c2 + 2], lo2f(w1), s2);
            s3 = fmaf(acc[2 * c2 + 3], hi2f(w1), s3);
          }
          float s = ((s0 + s1) + (s2 + s3)) * 0.17677669529663687f;
          float mxn = fmaxf(mx, s);
          float corr = __expf(mx - mxn);
          float pw = __expf(s - mxn);
          mx = mxn;
          lsum = lsum * corr + pw;
#pragma unroll
          for (int c2 = 0; c2 < 16; ++c2) {
            unsigned w = kr[16 + c2];
            oa[2 * c2]     = fmaf(pw, lo2f(w), oa[2 * c2] * corr);
            oa[2 * c2 + 1] = fmaf(pw, hi2f(w), oa[2 * c2 + 1] * corr);
          }
        }
        float inv = 1.f / lsum;
#pragma unroll
        for (int c2 = 0; c2 < 16; ++c2)
          oall2[h * 16 + c2] = pack2(oa[2 * c2] * inv, oa[2 * c2 + 1] * inv);
      }
      __syncthreads();
    }

    // O-projection + residual (paired d, shared unpacks)
    if (hasrow) {
      for (int d2 = 0; d2 < 64; ++d2) {
        const float *wo0 = oW + (2 * d2) * D_;
        const float *wo1 = wo0 + D_;
        float p0 = oB[2 * d2], p1 = 0.f, p2 = 0.f, p3 = 0.f;
        float q0 = oB[2 * d2 + 1], q1 = 0.f, q2 = 0.f, q3 = 0.f;
#pragma unroll
        for (int c2 = 0; c2 < 64; c2 += 2) {
          unsigned w0 = oall2[c2], w1 = oall2[c2 + 1];
          float x0 = lo2f(w0), x1 = hi2f(w0), x2 = lo2f(w1), x3 = hi2f(w1);
          p0 = fmaf(x0, wo0[2 * c2], p0);     p1 = fmaf(x1, wo0[2 * c2 + 1], p1);
          p2 = fmaf(x2, wo0[2 * c2 + 2], p2); p3 = fmaf(x3, wo0[2 * c2 + 3], p3);
          q0 = fmaf(x0, wo1[2 * c2], q0);     q1 = fmaf(x1, wo1[2 * c2 + 1], q1);
          q2 = fmaf(x2, wo1[2 * c2 + 2], q2); q3 = fmaf(x3, wo1[2 * c2 + 3], q3);
        }
        unsigned tw = tokp[tid][d2];
        tokp[tid][d2] = pack2(lo2f(tw) + ((p0 + p1) + (p2 + p3)),
                              hi2f(tw) + ((q0 + q1) + (q2 + q3)));
      }
    }

    // FFN
    if (hasrow) {
      float s0 = 0.f, s1 = 0.f;
#pragma unroll 8
      for (int d2 = 0; d2 < 64; ++d2) {
        unsigned w = tokp[tid][d2];
        s0 += lo2f(w); s1 += hi2f(w);
      }
      float m2 = (s0 + s1) * (1.f / 128.f);
      float v0 = 0.f, v1 = 0.f;
#pragma unroll 8
      for (int d2 = 0; d2 < 64; ++d2) {
        unsigned w = tokp[tid][d2];
        float t0 = lo2f(w) - m2, t1 = hi2f(w) - m2;
        v0 = fmaf(t0, t0, v0); v1 = fmaf(t1, t1, v1);
      }
      float rs2 = rsqrtf((v0 + v1) * (1.f / 128.f) + 1e-5f);

      float outv[128];
#pragma unroll
      for (int i = 0; i < 128; ++i) outv[i] = f2B[i];

      for (int jc = 0; jc < 16; ++jc) {
        float hacc[32];
#pragma unroll
        for (int jj = 0; jj < 32; ++jj) hacc[jj] = f1B[jc * 32 + jj];
        for (int dblk = 0; dblk < 8; ++dblk) {
          float xr[16];
#pragma unroll
          for (int i2 = 0; i2 < 8; ++i2) {
            unsigned w = tokp[tid][dblk * 8 + i2];
            int d = dblk * 16 + 2 * i2;
            xr[2 * i2]     = (lo2f(w) - m2) * rs2 * ln2g[d] + ln2b[d];
            xr[2 * i2 + 1] = (hi2f(w) - m2) * rs2 * ln2g[d + 1] + ln2b[d + 1];
          }
          const float *w1 = f1W + (jc * 32) * D_ + dblk * 16;
#pragma unroll
          for (int jj = 0; jj < 32; ++jj) {
#pragma unroll
            for (int i = 0; i < 16; ++i)
              hacc[jj] = fmaf(xr[i], w1[jj * D_ + i], hacc[jj]);
          }
        }
#pragma unroll
        for (int j2 = 0; j2 < 16; ++j2)
          kvrow[j2] = pack2(fmaxf(hacc[2 * j2], 0.f), fmaxf(hacc[2 * j2 + 1], 0.f));
        for (int colq = 0; colq < 2; ++colq) {
          float hq[16];
#pragma unroll
          for (int cc2 = 0; cc2 < 8; ++cc2) {
            unsigned w = kvrow[colq * 8 + cc2];
            hq[2 * cc2] = lo2f(w); hq[2 * cc2 + 1] = hi2f(w);
          }
          const float *w2 = f2W + jc * 32 + colq * 16;
#pragma unroll
          for (int ic = 0; ic < 8; ++ic) {
#pragma unroll
            for (int ii = 0; ii < 16; ++ii) {
              const float *w2r = w2 + (ic * 16 + ii) * 512;
              float q0 = 0.f, q1 = 0.f, q2 = 0.f, q3 = 0.f;
#pragma unroll
              for (int cc = 0; cc < 16; cc += 4) {
                q0 = fmaf(hq[cc], w2r[cc], q0);
                q1 = fmaf(hq[cc + 1], w2r[cc + 1], q1);
                q2 = fmaf(hq[cc + 2], w2r[cc + 2], q2);
                q3 = fmaf(hq[cc + 3], w2r[cc + 3], q3);
              }
              outv[ic * 16 + ii] += (q0 + q1) + (q2 + q3);
            }
          }
        }
      }
#pragma unroll
      for (int d2 = 0; d2 < 64; ++d2) {
        unsigned tw = tokp[tid][d2];
        tokp[tid][d2] = pack2(lo2f(tw) + outv[2 * d2], hi2f(tw) + outv[2 * d2 + 1]);
      }
    }
  }

  // ---- post-LN ----
  if (hasrow) {
    float s0 = 0.f, s1 = 0.f;
#pragma unroll 8
    for (int d2 = 0; d2 < 64; ++d2) {
      unsigned w = tokp[tid][d2];
      s0 += lo2f(w); s1 += hi2f(w);
    }
    float m = (s0 + s1) * (1.f / 128.f);
    float v0 = 0.f, v1 = 0.f;
#pragma unroll 8
    for (int d2 = 0; d2 < 64; ++d2) {
      unsigned w = tokp[tid][d2];
      float t0 = lo2f(w) - m, t1 = hi2f(w) - m;
      v0 = fmaf(t0, t0, v0); v1 = fmaf(t1, t1, v1);
    }
    float rs = rsqrtf((v0 + v1) * (1.f / 128.f) + 1e-5f);
#pragma unroll 2
    for (int d2 = 0; d2 < 64; ++d2) {
      unsigned w = tokp[tid][d2];
      int d = 2 * d2;
      tokp[tid][d2] = pack2((lo2f(w) - m) * rs * p.plng[d] + p.plnb[d],
                            (hi2f(w) - m) * rs * p.plng[d + 1] + p.plnb[d + 1]);
    }
  }
  __syncthreads();

  // ---- pooled mean (column access) ----
  if (tid < D_) {
    const int d2 = tid >> 1;
    const bool hi = tid & 1;
    float s0 = 0.f, s1 = 0.f;
    int r = 0;
    for (; r + 2 <= S_; r += 2) {
      unsigned w0 = tokp[r][d2], w1 = tokp[r + 1][d2];
      s0 += hi ? hi2f(w0) : lo2f(w0);
      s1 += hi ? hi2f(w1) : lo2f(w1);
    }
    unsigned wl = tokp[S_ - 1][d2];
    s0 += hi ? hi2f(wl) : lo2f(wl);
    pooled[tid] = (s0 + s1) * (1.f / (float)S_);
  }
  __syncthreads();
  if (tid < D_) {
    const float *wa = p.atW1 + tid * D_;
    const float *wv = p.vlW1 + tid * D_;
    float a0 = p.atB1[tid], a1 = 0.f, vv0 = p.vlB1[tid], vv1 = 0.f;
#pragma unroll 4
    for (int k = 0; k < D_; k += 2) {
      float pk0 = pooled[k], pk1 = pooled[k + 1];
      a0 = fmaf(pk0, wa[k], a0);   a1 = fmaf(pk1, wa[k + 1], a1);
      vv0 = fmaf(pk0, wv[k], vv0); vv1 = fmaf(pk1, wv[k + 1], vv1);
    }
    hid1[tid] = fmaxf(a0 + a1, 0.f);
    hid2[tid] = fmaxf(vv0 + vv1, 0.f);
  }
  __syncthreads();

  // ---- hex head ----
  if (tid < H_) {
    float hh[64];
#pragma unroll
    for (int j = 0; j < 64; ++j) hh[j] = p.hxB1[j];
    for (int kb = 0; kb < 8; ++kb) {
      float xr[16];
#pragma unroll
      for (int i2 = 0; i2 < 8; ++i2) {
        unsigned w = tokp[tid][kb * 8 + i2];
        xr[2 * i2] = lo2f(w); xr[2 * i2 + 1] = hi2f(w);
      }
      const float *w = p.hxW1 + kb * 16;
#pragma unroll
      for (int j = 0; j < 64; ++j) {
#pragma unroll
        for (int i = 0; i < 16; ++i)
          hh[j] = fmaf(xr[i], w[j * D_ + i], hh[j]);
      }
    }
    float o = p.hxB2[0];
#pragma unroll
    for (int j = 0; j < 64; ++j) o = fmaf(fmaxf(hh[j], 0.f), p.hxW2[j], o);
    p.out[OFF_HEX + b * H_ + tid] = o;
  }
  // ---- action-type logits ----
  if (tid < NAT_) {
    const float *w = p.atW2 + tid * D_;
    float o0 = p.atB2[tid], o1 = 0.f, o2 = 0.f, o3 = 0.f;
#pragma unroll 4
    for (int k = 0; k < D_; k += 4) {
      o0 = fmaf(hid1[k], w[k], o0);     o1 = fmaf(hid1[k + 1], w[k + 1], o1);
      o2 = fmaf(hid1[k + 2], w[k + 2], o2); o3 = fmaf(hid1[k + 3], w[k + 3], o3);
    }
    p.out[b * NAT_ + tid] = (o0 + o1) + (o2 + o3);
  }
  // ---- value ----
  if (tid == 190) {
    float o0 = p.vlB2[0], o1 = 0.f, o2 = 0.f, o3 = 0.f;
#pragma unroll 4
    for (int k = 0; k < D_; k += 4) {
      o0 = fmaf(hid2[k], p.vlW2[k], o0);     o1 = fmaf(hid2[k + 1], p.vlW2[k + 1], o1);
      o2 = fmaf(hid2[k + 2], p.vlW2[k + 2], o2); o3 = fmaf(hid2[k + 3], p.vlW2[k + 3], o3);
    }
    p.out[OFF_VAL + b] = (o0 + o1) + (o2 + o3);
  }
  // ---- target logits ----
  if (tid >= 32 && tid < 32 + MS_) {
    int si = tid - 32;
    float o;
    if (svalid[si]) {
      int r = sposc[si];
      float hh[64];
#pragma unroll
      for (int j = 0; j < 64; ++j) hh[j] = p.tgB1[j];
      for (int kb = 0; kb < 8; ++kb) {
        float xr[16];
#pragma unroll
        for (int i2 = 0; i2 < 8; ++i2) {
          unsigned w = tokp[r][kb * 8 + i2];
          xr[2 * i2] = lo2f(w); xr[2 * i2 + 1] = hi2f(w);
        }
        const float *w = p.tgW1 + kb * 16;
#pragma unroll
        for (int j = 0; j < 64; ++j) {
#pragma unroll
          for (int i = 0; i < 16; ++i)
            hh[j] = fmaf(xr[i], w[j * D_ + i], hh[j]);
        }
      }
      o = p.tgB2[0];
#pragma unroll
      for (int j = 0; j < 64; ++j) o = fmaf(fmaxf(hh[j], 0.f), p.tgW2[j], o);
    } else {
      o = -1e9f;
    }
    p.out[OFF_TGT + b * MS_ + si] = o;
  }
}

extern "C" void kernel_launch(void* const* d_in, const int* in_sizes, int n_in,
                              void* d_out, int out_size, void* d_ws, size_t ws_size,
                              hipStream_t stream) {
  (void)in_sizes; (void)n_in; (void)out_size; (void)d_ws; (void)ws_size;
  Params p;
  p.scalars = (const float *)d_in[0];
  p.stacks = (const float *)d_in[1];
  p.obstacles = (const float *)d_in[2];
  p.reach = (const float *)d_in[3];
  p.n_stacks = (const int *)d_in[4];
  p.cemb = (const float *)d_in[5];
  p.pos_emb = (const float *)d_in[6];
  p.tte = (const float *)d_in[7];
  p.hexW = (const float *)d_in[8];  p.hexB = (const float *)d_in[9];
  p.hexG = (const float *)d_in[10]; p.hexBe = (const float *)d_in[11];
  p.heroW = (const float *)d_in[12]; p.heroB = (const float *)d_in[13];
  p.heroG = (const float *)d_in[14]; p.heroBe = (const float *)d_in[15];
  p.gW = (const float *)d_in[16]; p.gB = (const float *)d_in[17];
  p.ln1g = (const float *)d_in[18]; p.ln1b = (const float *)d_in[19];
  p.qkvW = (const float *)d_in[20]; p.qkvB = (const float *)d_in[21];
  p.oW = (const float *)d_in[22]; p.oB = (const float *)d_in[23];
  p.ln2g = (const float *)d_in[24]; p.ln2b = (const float *)d_in[25];
  p.f1W = (const float *)d_in[26]; p.f1B = (const float *)d_in[27];
  p.f2W = (const float *)d_in[28]; p.f2B = (const float *)d_in[29];
  p.plng = (const float *)d_in[30]; p.plnb = (const float *)d_in[31];
  p.atW1 = (const float *)d_in[32]; p.atB1 = (const float *)d_in[33];
  p.atW2 = (const float *)d_in[34]; p.atB2 = (const float *)d_in[35];
  p.hxW1 = (const float *)d_in[36]; p.hxB1 = (const float *)d_in[37];
  p.hxW2 = (const float *)d_in[38]; p.hxB2 = (const float *)d_in[39];
  p.tgW1 = (const float *)d_in[40]; p.tgB1 = (const float *)d_in[41];
  p.tgW2 = (const float *)d_in[42]; p.tgB2 = (const float *)d_in[43];
  p.vlW1 = (const float *)d_in[44]; p.vlB1 = (const float *)d_in[45];
  p.vlW2 = (const float *)d_in[46]; p.vlB2 = (const float *)d_in[47];
  p.out = (float *)d_out;
  battle_kernel<<<dim3(B_), dim3(192), 0, stream>>>(p);
}

// Round 13
// 7652.746 us; speedup vs baseline: 9.3530x; 4.4631x over previous
//
#include <hip/hip_runtime.h>
#include <hip/hip_bf16.h>

#define DEV static __device__ __forceinline__

typedef __attribute__((ext_vector_type(8))) short bf16x8;
typedef __attribute__((ext_vector_type(4))) float f32x4;
#define MFMA16 __builtin_amdgcn_mfma_f32_16x16x32_bf16

DEV unsigned short f2bf_rn(float x) {
  unsigned u = __float_as_uint(x);
  u = u + 0x7fffu + ((u >> 16) & 1u);
  return (unsigned short)(u >> 16);
}
DEV unsigned pack2(float a, float b) {
  return (unsigned)f2bf_rn(a) | ((unsigned)f2bf_rn(b) << 16);
}
DEV float lo2f(unsigned w) { return __uint_as_float(w << 16); }
DEV float hi2f(unsigned w) { return __uint_as_float(w & 0xffff0000u); }

constexpr int H_ = 187, MS_ = 20, MOB_ = 10, D_ = 128, NH_ = 4, NL_ = 4,
              CE_ = 16, NAT_ = 5, NCT_ = 256, HEXC_ = 29, B_ = 1024;
constexpr int S_ = H_ + 2;   // 189 tokens
constexpr int ST = 68;       // LDS row stride in u32 (272B: 16B-aligned, 68%32=4)

constexpr int OFF_HEX = B_ * NAT_;          // 5120
constexpr int OFF_TGT = OFF_HEX + B_ * H_;  // 196608
constexpr int OFF_VAL = OFF_TGT + B_ * MS_; // 217088

struct Params {
  const float *scalars, *stacks, *obstacles, *reach;
  const int  *n_stacks;
  const float *cemb, *pos_emb, *tte;
  const float *hexW, *hexB, *hexG, *hexBe;
  const float *heroW, *heroB, *heroG, *heroBe;
  const float *gW, *gB;
  const float *ln1g, *ln1b, *qkvW, *qkvB, *oW, *oB;
  const float *ln2g, *ln2b, *f1W, *f1B, *f2W, *f2B;
  const float *plng, *plnb;
  const float *atW1, *atB1, *atW2, *atB2;
  const float *hxW1, *hxB1, *hxW2, *hxB2;
  const float *tgW1, *tgB1, *tgW2, *tgB2;
  const float *vlW1, *vlB1, *vlW2, *vlB2;
  float *out;
};

// A-fragment: lane holds A[row = mbase+(l&15)][k = kt*32 + (l>>4)*8 + j]
// stored bf16-packed: u32 col = k/2 -> cols kt*16 + (l>>4)*4 .. +3 (16B aligned)
DEV bf16x8 ldA(const unsigned* buf, int mbase, int kt, int lane) {
  int row = mbase + (lane & 15);
  int c = kt * 16 + ((lane >> 4) << 2);
  return *(const bf16x8*)(buf + row * ST + c);
}
// B-fragment from global f32 weight row-major [N][ldw]:
// lane: row n (free idx) = caller's base + (l&15); k = koff + j (8 consecutive)
DEV bf16x8 ldBw(const float* wrow, int koff) {
  const float* q = wrow + koff;
  bf16x8 r;
#pragma unroll
  for (int j = 0; j < 8; ++j) r[j] = (short)f2bf_rn(q[j]);
  return r;
}

// One N-tile (16 cols) of C[192 x N] = A(Abuf bf16) @ W^T + bias.
// mode 0: write f32 into outU at u32 col cbase+(l&15)
// mode 1: write bf16 (ushort) at col cbase+(l&15); mode 2: same with relu
DEV void mfma_ntile(const unsigned* Abuf, const float* W, int ldw, int nrow0,
                    const float* bias, unsigned* outU, int mode, int cbase,
                    int lane) {
  const float* wrow = W + (nrow0 + (lane & 15)) * ldw;
  int koff = (lane >> 4) << 3;
  bf16x8 b0 = ldBw(wrow, koff);
  bf16x8 b1 = ldBw(wrow, 32 + koff);
  bf16x8 b2 = ldBw(wrow, 64 + koff);
  bf16x8 b3 = ldBw(wrow, 96 + koff);
  float bv = bias[lane & 15];
  int col = cbase + (lane & 15);
  unsigned short* o16 = (unsigned short*)outU;
#pragma unroll 1
  for (int mt = 0; mt < 12; ++mt) {
    f32x4 acc = {bv, bv, bv, bv};
    acc = MFMA16(ldA(Abuf, mt * 16, 0, lane), b0, acc, 0, 0, 0);
    acc = MFMA16(ldA(Abuf, mt * 16, 1, lane), b1, acc, 0, 0, 0);
    acc = MFMA16(ldA(Abuf, mt * 16, 2, lane), b2, acc, 0, 0, 0);
    acc = MFMA16(ldA(Abuf, mt * 16, 3, lane), b3, acc, 0, 0, 0);
    int rb = mt * 16 + ((lane >> 4) << 2);
    if (mode == 0) {
#pragma unroll
      for (int g = 0; g < 4; ++g)
        outU[(rb + g) * ST + col] = __float_as_uint(acc[g]);
    } else if (mode == 1) {
#pragma unroll
      for (int g = 0; g < 4; ++g)
        o16[(rb + g) * (ST * 2) + col] = f2bf_rn(acc[g]);
    } else {
#pragma unroll
      for (int g = 0; g < 4; ++g)
        o16[(rb + g) * (ST * 2) + col] = f2bf_rn(fmaxf(acc[g], 0.f));
    }
  }
}

__global__ __launch_bounds__(192, 1) void battle_kernel(Params p) {
  __shared__ __align__(16) unsigned tokp[192 * ST];  // residual, bf16 pairs
  __shared__ __align__(16) unsigned xln[192 * ST];   // LN'd X / attn-out, bf16
  __shared__ __align__(16) unsigned aux[192 * ST];   // QKV f32 / hidden bf16
  __shared__ float gvec[D_], pooled[D_], hid1[D_], hid2[D_];
  __shared__ int svalid[MS_], sposc[MS_];

  const int b = blockIdx.x;
  const int tid = threadIdx.x;
  const int lane = tid & 63;
  const int wave = tid >> 6;
  const bool hasrow = tid < S_;
  const float *sc = p.scalars + b * 19;

  float *hexcont = (float *)aux;             // 5423 floats
  int   *cids    = (int *)aux + 5440;        // 187
  float *obsch   = (float *)aux + 5632;      // 187

  // ---- E0 ----
  if (tid < D_) {
    float g0 = sc[1] * 0.02f, g1 = sc[4] * 0.1f, g2 = sc[5] * 0.1f;
    float g3 = sc[6], g4 = sc[3];
    const float *w = p.gW + tid * 5;
    gvec[tid] = p.gB[tid] + g0 * w[0] + g1 * w[1] + g2 * w[2] + g3 * w[3] + g4 * w[4];
  }
  for (int i = tid; i < H_ * HEXC_; i += 192) hexcont[i] = 0.f;
  for (int i = tid; i < H_; i += 192) { cids[i] = 0; obsch[i] = 0.f; }
  __syncthreads();

  // ---- E2: stack scatter ----
  if (tid < MS_) {
    const float *st = p.stacks + (b * MS_ + tid) * 35;
    int pos = (int)st[18];
    float alive = st[23];
    int ns = p.n_stacks[b];
    bool valid = (pos >= 0) && (pos < H_) && (alive >= 0.5f) && (tid < ns);
    svalid[tid] = valid ? 1 : 0;
    sposc[tid] = min(max(pos, 0), H_ - 1);
    if (valid) {
      float maxhp = fmaxf(st[4], 1.0f);
      float *hc = hexcont + pos * HEXC_;
      hc[0] = 1.0f;
      hc[1] = st[2] * 1e-3f;
      hc[2] = st[3] / maxhp;
      hc[3] = st[8] * 0.01f;  hc[4] = st[9] * 0.01f;
      hc[5] = st[10] * 0.01f; hc[6] = st[11] * 0.01f;
      hc[7] = st[12] * 0.01f; hc[8] = st[13] * 0.01f;
      hc[9] = st[14] * 0.01f; hc[10] = st[15] * 0.01f;
      hc[11] = st[16] * 0.05f; hc[12] = st[17] * 0.05f;
      float s20 = st[20];
      hc[13] = s20;
      hc[14] = (s20 == sc[3]) ? 1.f : 0.f;
      hc[15] = alive;
      hc[16] = st[24]; hc[17] = st[25]; hc[18] = st[26];
      hc[19] = st[27]; hc[20] = st[28]; hc[21] = st[29];
      hc[22] = st[30];
      hc[23] = st[31] * (1.f / 30.f);
      hc[24] = st[33] * 0.2f;
      hc[25] = st[34] * 0.1f;
      hc[26] = (st[0] == sc[2]) ? 1.f : 0.f;
      hc[27] = 0.f; hc[28] = 0.f;
      cids[pos] = min((int)st[1], NCT_ - 1);
    }
  }
  if (tid >= 64 && tid < 64 + MOB_) {
    const float *ob = p.obstacles + (b * MOB_ + (tid - 64)) * 3;
    int opos = (int)ob[2];
    if (ob[0] > 0.f && opos >= 0 && opos < H_) obsch[opos] = 1.0f;
  }
  __syncthreads();

  // ---- E4/E5: tokens -> tokp ----
  if (tid < H_) {
    const int r = tid;
    float f[HEXC_ + CE_];
#pragma unroll
    for (int c = 0; c < HEXC_; ++c) f[c] = hexcont[r * HEXC_ + c];
    f[27] = p.reach[b * H_ + r];
    f[28] = obsch[r];
    int cid = cids[r];
#pragma unroll
    for (int e = 0; e < CE_; ++e) f[HEXC_ + e] = p.cemb[cid * CE_ + e];
    float sum = 0.f;
    for (int d2 = 0; d2 < 64; ++d2) {
      const float *w0 = p.hexW + (2 * d2) * 45;
      const float *w1 = w0 + 45;
      float a0 = p.hexB[2 * d2], a1 = 0.f, a2 = 0.f, a3 = 0.f;
      float b0 = p.hexB[2 * d2 + 1], b1 = 0.f, b2 = 0.f, b3 = 0.f;
#pragma unroll
      for (int k = 0; k < 44; k += 4) {
        a0 = fmaf(f[k], w0[k], a0);       a1 = fmaf(f[k + 1], w0[k + 1], a1);
        a2 = fmaf(f[k + 2], w0[k + 2], a2); a3 = fmaf(f[k + 3], w0[k + 3], a3);
        b0 = fmaf(f[k], w1[k], b0);       b1 = fmaf(f[k + 1], w1[k + 1], b1);
        b2 = fmaf(f[k + 2], w1[k + 2], b2); b3 = fmaf(f[k + 3], w1[k + 3], b3);
      }
      a0 = fmaf(f[44], w0[44], a0);
      b0 = fmaf(f[44], w1[44], b0);
      float va = (a0 + a1) + (a2 + a3), vb = (b0 + b1) + (b2 + b3);
      tokp[r * ST + d2] = pack2(va, vb);
      sum += va + vb;
    }
    float m = sum * (1.f / 128.f);
    float var = 0.f;
#pragma unroll 4
    for (int d2 = 0; d2 < 64; ++d2) {
      unsigned w = tokp[r * ST + d2];
      float t0 = lo2f(w) - m, t1 = hi2f(w) - m;
      var = fmaf(t0, t0, var); var = fmaf(t1, t1, var);
    }
    float rs = rsqrtf(var * (1.f / 128.f) + 1e-5f);
#pragma unroll 2
    for (int d2 = 0; d2 < 64; ++d2) {
      unsigned w = tokp[r * ST + d2];
      int d = 2 * d2;
      float v0 = (lo2f(w) - m) * rs * p.hexG[d] + p.hexBe[d] +
                 p.pos_emb[r * D_ + d] + p.tte[d] + gvec[d];
      float v1 = (hi2f(w) - m) * rs * p.hexG[d + 1] + p.hexBe[d + 1] +
                 p.pos_emb[r * D_ + d + 1] + p.tte[d + 1] + gvec[d + 1];
      tokp[r * ST + d2] = pack2(v0, v1);
    }
  } else if (tid < S_) {
    const int which = tid - H_;
    float f0, f1, f2, f3, f4;
    if (which == 0) {
      f0 = sc[8];  f1 = sc[11] * (1.f / 300.f);
      f2 = sc[10] * 0.1f; f3 = sc[12] * 0.1f; f4 = 0.f;
    } else {
      f0 = sc[14]; f1 = sc[17] * (1.f / 300.f);
      f2 = sc[16] * 0.1f; f3 = sc[18] * 0.1f; f4 = 1.f;
    }
    const int r = tid;
    float sum = 0.f;
    for (int d2 = 0; d2 < 64; ++d2) {
      const float *w0 = p.heroW + (2 * d2) * 5;
      const float *w1 = w0 + 5;
      float va = p.heroB[2 * d2] + f0 * w0[0] + f1 * w0[1] + f2 * w0[2] + f3 * w0[3] + f4 * w0[4];
      float vb = p.heroB[2 * d2 + 1] + f0 * w1[0] + f1 * w1[1] + f2 * w1[2] + f3 * w1[3] + f4 * w1[4];
      tokp[r * ST + d2] = pack2(va, vb);
      sum += va + vb;
    }
    float m = sum * (1.f / 128.f);
    float var = 0.f;
    for (int d2 = 0; d2 < 64; ++d2) {
      unsigned w = tokp[r * ST + d2];
      float t0 = lo2f(w) - m, t1 = hi2f(w) - m;
      var = fmaf(t0, t0, var); var = fmaf(t1, t1, var);
    }
    float rs = rsqrtf(var * (1.f / 128.f) + 1e-5f);
    for (int d2 = 0; d2 < 64; ++d2) {
      unsigned w = tokp[r * ST + d2];
      int d = 2 * d2;
      float v0 = (lo2f(w) - m) * rs * p.heroG[d] + p.heroBe[d] +
                 p.tte[(1 + which) * D_ + d] + gvec[d];
      float v1 = (hi2f(w) - m) * rs * p.heroG[d + 1] + p.heroBe[d + 1] +
                 p.tte[(1 + which) * D_ + d + 1] + gvec[d + 1];
      tokp[r * ST + d2] = pack2(v0, v1);
    }
  }

  // ---- transformer layers ----
  for (int l = 0; l < NL_; ++l) {
    const float *ln1g = p.ln1g + l * D_, *ln1b = p.ln1b + l * D_;
    const float *qkvW = p.qkvW + l * 3 * D_ * D_, *qkvB = p.qkvB + l * 3 * D_;
    const float *oW = p.oW + l * D_ * D_, *oB = p.oB + l * D_;
    const float *ln2g = p.ln2g + l * D_, *ln2b = p.ln2b + l * D_;
    const float *f1W = p.f1W + l * 4 * D_ * D_, *f1B = p.f1B + l * 4 * D_;
    const float *f2W = p.f2W + l * 4 * D_ * D_, *f2B = p.f2B + l * D_;

    __syncthreads();  // aux/xln reuse fence (embed scratch / prev layer)

    // LN1: tokp -> xln (bf16), pads zeroed
    if (hasrow) {
      float s0 = 0.f, s1 = 0.f;
#pragma unroll 8
      for (int d2 = 0; d2 < 64; ++d2) {
        unsigned w = tokp[tid * ST + d2];
        s0 += lo2f(w); s1 += hi2f(w);
      }
      float m = (s0 + s1) * (1.f / 128.f);
      float v0 = 0.f, v1 = 0.f;
#pragma unroll 8
      for (int d2 = 0; d2 < 64; ++d2) {
        unsigned w = tokp[tid * ST + d2];
        float t0 = lo2f(w) - m, t1 = hi2f(w) - m;
        v0 = fmaf(t0, t0, v0); v1 = fmaf(t1, t1, v1);
      }
      float rs = rsqrtf((v0 + v1) * (1.f / 128.f) + 1e-5f);
#pragma unroll 2
      for (int d2 = 0; d2 < 64; ++d2) {
        unsigned w = tokp[tid * ST + d2];
        int d = 2 * d2;
        xln[tid * ST + d2] = pack2((lo2f(w) - m) * rs * ln1g[d] + ln1b[d],
                                   (hi2f(w) - m) * rs * ln1g[d + 1] + ln1b[d + 1]);
      }
    } else {
      for (int d2 = 0; d2 < 64; ++d2) xln[tid * ST + d2] = 0u;
    }
    __syncthreads();

    unsigned oall2[64];

#pragma unroll
    for (int h = 0; h < NH_; ++h) {
      // Q-projection MFMA -> aux f32 cols 0..31
      for (int nt = wave; nt < 2; nt += 3)
        mfma_ntile(xln, qkvW, 128, h * 32 + nt * 16,
                   qkvB + h * 32 + nt * 16, aux, 0, nt * 16, lane);
      __syncthreads();
      float q[32];
      if (hasrow) {
#pragma unroll
        for (int c = 0; c < 32; ++c) q[c] = __uint_as_float(aux[tid * ST + c]);
      }
      __syncthreads();
      // K,V-projection MFMA -> aux f32 (K cols 0..31, V cols 32..63)
      for (int job = wave; job < 4; job += 3) {
        int nt = job & 1;
        int isV = job >> 1;
        int base = (isV ? 256 : 128) + h * 32 + nt * 16;
        mfma_ntile(xln, qkvW, 128, base, qkvB + base, aux, 0,
                   isV * 32 + nt * 16, lane);
      }
      __syncthreads();
      // attention (per-row scalar, f32 K/V)
      if (hasrow) {
        float mx = -1e30f, lsum = 0.f;
        float oa[32];
#pragma unroll
        for (int c = 0; c < 32; ++c) oa[c] = 0.f;
        for (int j = 0; j < S_; ++j) {
          const unsigned *kr = aux + j * ST;
          float s0 = 0.f, s1 = 0.f, s2 = 0.f, s3 = 0.f;
#pragma unroll
          for (int c = 0; c < 32; c += 4) {
            s0 = fmaf(q[c], __uint_as_float(kr[c]), s0);
            s1 = fmaf(q[c + 1], __uint_as_float(kr[c + 1]), s1);
            s2 = fmaf(q[c + 2], __uint_as_float(kr[c + 2]), s2);
            s3 = fmaf(q[c + 3], __uint_as_float(kr[c + 3]), s3);
          }
          float s = ((s0 + s1) + (s2 + s3)) * 0.17677669529663687f;
          if (s > mx) {
            float corr = __expf(mx - s);
            lsum *= corr;
#pragma unroll
            for (int c = 0; c < 32; ++c) oa[c] *= corr;
            mx = s;
          }
          float pw = __expf(s - mx);
          lsum += pw;
#pragma unroll
          for (int c = 0; c < 32; ++c)
            oa[c] = fmaf(pw, __uint_as_float(kr[32 + c]), oa[c]);
        }
        float inv = 1.f / lsum;
#pragma unroll
        for (int c2 = 0; c2 < 16; ++c2)
          oall2[h * 16 + c2] = pack2(oa[2 * c2] * inv, oa[2 * c2 + 1] * inv);
      }
      __syncthreads();  // aux free for next head
    }

    // attn-out -> xln (overwrites LN1)
    if (hasrow) {
#pragma unroll
      for (int c = 0; c < 64; ++c) xln[tid * ST + c] = oall2[c];
    } else {
      for (int c = 0; c < 64; ++c) xln[tid * ST + c] = 0u;
    }
    __syncthreads();

    // O-projection MFMA -> aux bf16
    for (int nt = wave; nt < 8; nt += 3)
      mfma_ntile(xln, oW, 128, nt * 16, oB + nt * 16, aux, 1, nt * 16, lane);
    __syncthreads();

    // residual + LN2 (tokp += aux; tokp -> xln)
    if (hasrow) {
#pragma unroll 2
      for (int d2 = 0; d2 < 64; ++d2) {
        unsigned tw = tokp[tid * ST + d2], aw = aux[tid * ST + d2];
        tokp[tid * ST + d2] = pack2(lo2f(tw) + lo2f(aw), hi2f(tw) + hi2f(aw));
      }
      float s0 = 0.f, s1 = 0.f;
#pragma unroll 8
      for (int d2 = 0; d2 < 64; ++d2) {
        unsigned w = tokp[tid * ST + d2];
        s0 += lo2f(w); s1 += hi2f(w);
      }
      float m = (s0 + s1) * (1.f / 128.f);
      float v0 = 0.f, v1 = 0.f;
#pragma unroll 8
      for (int d2 = 0; d2 < 64; ++d2) {
        unsigned w = tokp[tid * ST + d2];
        float t0 = lo2f(w) - m, t1 = hi2f(w) - m;
        v0 = fmaf(t0, t0, v0); v1 = fmaf(t1, t1, v1);
      }
      float rs = rsqrtf((v0 + v1) * (1.f / 128.f) + 1e-5f);
#pragma unroll 2
      for (int d2 = 0; d2 < 64; ++d2) {
        unsigned w = tokp[tid * ST + d2];
        int d = 2 * d2;
        xln[tid * ST + d2] = pack2((lo2f(w) - m) * rs * ln2g[d] + ln2b[d],
                                   (hi2f(w) - m) * rs * ln2g[d + 1] + ln2b[d + 1]);
      }
    } else {
      for (int d2 = 0; d2 < 64; ++d2) xln[tid * ST + d2] = 0u;
    }
    __syncthreads();

    // FFN: 4 hidden chunks of 128; FFN2 accumulates in registers
    f32x4 acc2[36];
#pragma unroll
    for (int o = 0; o < 3; ++o) {
      int nt = wave + 3 * o;
      float bv = (nt < 8) ? f2B[nt * 16 + (lane & 15)] : 0.f;
#pragma unroll
      for (int mt = 0; mt < 12; ++mt) acc2[o * 12 + mt] = {bv, bv, bv, bv};
    }
    for (int chunk = 0; chunk < 4; ++chunk) {
      // FFN1 chunk -> relu -> aux bf16 (hidden cols 0..127)
      for (int nt = wave; nt < 8; nt += 3)
        mfma_ntile(xln, f1W, 128, chunk * 128 + nt * 16,
                   f1B + chunk * 128 + nt * 16, aux, 2, nt * 16, lane);
      __syncthreads();
      // FFN2 partial: acc2 += hidden @ W2chunk^T
#pragma unroll
      for (int o = 0; o < 3; ++o) {
        int nt = wave + 3 * o;
        if (nt < 8) {
          const float *wrow = f2W + (nt * 16 + (lane & 15)) * 512 + chunk * 128;
          int koff = (lane >> 4) << 3;
          bf16x8 b0 = ldBw(wrow, koff);
          bf16x8 b1 = ldBw(wrow, 32 + koff);
          bf16x8 b2 = ldBw(wrow, 64 + koff);
          bf16x8 b3 = ldBw(wrow, 96 + koff);
#pragma unroll
          for (int mt = 0; mt < 12; ++mt) {
            f32x4 a = acc2[o * 12 + mt];
            a = MFMA16(ldA(aux, mt * 16, 0, lane), b0, a, 0, 0, 0);
            a = MFMA16(ldA(aux, mt * 16, 1, lane), b1, a, 0, 0, 0);
            a = MFMA16(ldA(aux, mt * 16, 2, lane), b2, a, 0, 0, 0);
            a = MFMA16(ldA(aux, mt * 16, 3, lane), b3, a, 0, 0, 0);
            acc2[o * 12 + mt] = a;
          }
        }
      }
      __syncthreads();  // before next chunk overwrites hidden
    }
    // FFN2 writeback -> aux bf16
    {
      unsigned short *o16 = (unsigned short *)aux;
#pragma unroll
      for (int o = 0; o < 3; ++o) {
        int nt = wave + 3 * o;
        if (nt < 8) {
          int col = nt * 16 + (lane & 15);
#pragma unroll
          for (int mt = 0; mt < 12; ++mt) {
            int rb = mt * 16 + ((lane >> 4) << 2);
            f32x4 a = acc2[o * 12 + mt];
#pragma unroll
            for (int g = 0; g < 4; ++g)
              o16[(rb + g) * (ST * 2) + col] = f2bf_rn(a[g]);
          }
        }
      }
    }
    __syncthreads();
    // residual 2
    if (hasrow) {
#pragma unroll 2
      for (int d2 = 0; d2 < 64; ++d2) {
        unsigned tw = tokp[tid * ST + d2], aw = aux[tid * ST + d2];
        tokp[tid * ST + d2] = pack2(lo2f(tw) + lo2f(aw), hi2f(tw) + hi2f(aw));
      }
    }
  }

  // ---- post-LN ----
  if (hasrow) {
    float s0 = 0.f, s1 = 0.f;
#pragma unroll 8
    for (int d2 = 0; d2 < 64; ++d2) {
      unsigned w = tokp[tid * ST + d2];
      s0 += lo2f(w); s1 += hi2f(w);
    }
    float m = (s0 + s1) * (1.f / 128.f);
    float v0 = 0.f, v1 = 0.f;
#pragma unroll 8
    for (int d2 = 0; d2 < 64; ++d2) {
      unsigned w = tokp[tid * ST + d2];
      float t0 = lo2f(w) - m, t1 = hi2f(w) - m;
      v0 = fmaf(t0, t0, v0); v1 = fmaf(t1, t1, v1);
    }
    float rs = rsqrtf((v0 + v1) * (1.f / 128.f) + 1e-5f);
#pragma unroll 2
    for (int d2 = 0; d2 < 64; ++d2) {
      unsigned w = tokp[tid * ST + d2];
      int d = 2 * d2;
      tokp[tid * ST + d2] = pack2((lo2f(w) - m) * rs * p.plng[d] + p.plnb[d],
                                  (hi2f(w) - m) * rs * p.plng[d + 1] + p.plnb[d + 1]);
    }
  }
  __syncthreads();

  // ---- pooled mean ----
  if (tid < D_) {
    const int d2 = tid >> 1;
    const bool hi = tid & 1;
    float s0 = 0.f, s1 = 0.f;
    int r = 0;
    for (; r + 2 <= S_; r += 2) {
      unsigned w0 = tokp[r * ST + d2], w1 = tokp[(r + 1) * ST + d2];
      s0 += hi ? hi2f(w0) : lo2f(w0);
      s1 += hi ? hi2f(w1) : lo2f(w1);
    }
    unsigned wl = tokp[(S_ - 1) * ST + d2];
    s0 += hi ? hi2f(wl) : lo2f(wl);
    pooled[tid] = (s0 + s1) * (1.f / (float)S_);
  }
  __syncthreads();
  if (tid < D_) {
    const float *wa = p.atW1 + tid * D_;
    const float *wv = p.vlW1 + tid * D_;
    float a0 = p.atB1[tid], a1 = 0.f, vv0 = p.vlB1[tid], vv1 = 0.f;
#pragma unroll 4
    for (int k = 0; k < D_; k += 2) {
      float pk0 = pooled[k], pk1 = pooled[k + 1];
      a0 = fmaf(pk0, wa[k], a0);   a1 = fmaf(pk1, wa[k + 1], a1);
      vv0 = fmaf(pk0, wv[k], vv0); vv1 = fmaf(pk1, wv[k + 1], vv1);
    }
    hid1[tid] = fmaxf(a0 + a1, 0.f);
    hid2[tid] = fmaxf(vv0 + vv1, 0.f);
  }
  __syncthreads();

  // ---- hex head ----
  if (tid < H_) {
    float hh[64];
#pragma unroll
    for (int j = 0; j < 64; ++j) hh[j] = p.hxB1[j];
    for (int kb = 0; kb < 8; ++kb) {
      float xr[16];
#pragma unroll
      for (int i2 = 0; i2 < 8; ++i2) {
        unsigned w = tokp[tid * ST + kb * 8 + i2];
        xr[2 * i2] = lo2f(w); xr[2 * i2 + 1] = hi2f(w);
      }
      const float *w = p.hxW1 + kb * 16;
#pragma unroll
      for (int j = 0; j < 64; ++j) {
#pragma unroll
        for (int i = 0; i < 16; ++i)
          hh[j] = fmaf(xr[i], w[j * D_ + i], hh[j]);
      }
    }
    float o = p.hxB2[0];
#pragma unroll
    for (int j = 0; j < 64; ++j) o = fmaf(fmaxf(hh[j], 0.f), p.hxW2[j], o);
    p.out[OFF_HEX + b * H_ + tid] = o;
  }
  if (tid < NAT_) {
    const float *w = p.atW2 + tid * D_;
    float o0 = p.atB2[tid], o1 = 0.f, o2 = 0.f, o3 = 0.f;
#pragma unroll 4
    for (int k = 0; k < D_; k += 4) {
      o0 = fmaf(hid1[k], w[k], o0);     o1 = fmaf(hid1[k + 1], w[k + 1], o1);
      o2 = fmaf(hid1[k + 2], w[k + 2], o2); o3 = fmaf(hid1[k + 3], w[k + 3], o3);
    }
    p.out[b * NAT_ + tid] = (o0 + o1) + (o2 + o3);
  }
  if (tid == 190) {
    float o0 = p.vlB2[0], o1 = 0.f, o2 = 0.f, o3 = 0.f;
#pragma unroll 4
    for (int k = 0; k < D_; k += 4) {
      o0 = fmaf(hid2[k], p.vlW2[k], o0);     o1 = fmaf(hid2[k + 1], p.vlW2[k + 1], o1);
      o2 = fmaf(hid2[k + 2], p.vlW2[k + 2], o2); o3 = fmaf(hid2[k + 3], p.vlW2[k + 3], o3);
    }
    p.out[OFF_VAL + b] = (o0 + o1) + (o2 + o3);
  }
  if (tid >= 32 && tid < 32 + MS_) {
    int si = tid - 32;
    float o;
    if (svalid[si]) {
      int r = sposc[si];
      float hh[64];
#pragma unroll
      for (int j = 0; j < 64; ++j) hh[j] = p.tgB1[j];
      for (int kb = 0; kb < 8; ++kb) {
        float xr[16];
#pragma unroll
        for (int i2 = 0; i2 < 8; ++i2) {
          unsigned w = tokp[r * ST + kb * 8 + i2];
          xr[2 * i2] = lo2f(w); xr[2 * i2 + 1] = hi2f(w);
        }
        const float *w = p.tgW1 + kb * 16;
#pragma unroll
        for (int j = 0; j < 64; ++j) {
#pragma unroll
          for (int i = 0; i < 16; ++i)
            hh[j] = fmaf(xr[i], w[j * D_ + i], hh[j]);
        }
      }
      o = p.tgB2[0];
#pragma unroll
      for (int j = 0; j < 64; ++j) o = fmaf(fmaxf(hh[j], 0.f), p.tgW2[j], o);
    } else {
      o = -1e9f;
    }
    p.out[OFF_TGT + b * MS_ + si] = o;
  }
}

extern "C" void kernel_launch(void* const* d_in, const int* in_sizes, int n_in,
                              void* d_out, int out_size, void* d_ws, size_t ws_size,
                              hipStream_t stream) {
  (void)in_sizes; (void)n_in; (void)out_size; (void)d_ws; (void)ws_size;
  Params p;
  p.scalars = (const float *)d_in[0];
  p.stacks = (const float *)d_in[1];
  p.obstacles = (const float *)d_in[2];
  p.reach = (const float *)d_in[3];
  p.n_stacks = (const int *)d_in[4];
  p.cemb = (const float *)d_in[5];
  p.pos_emb = (const float *)d_in[6];
  p.tte = (const float *)d_in[7];
  p.hexW = (const float *)d_in[8];  p.hexB = (const float *)d_in[9];
  p.hexG = (const float *)d_in[10]; p.hexBe = (const float *)d_in[11];
  p.heroW = (const float *)d_in[12]; p.heroB = (const float *)d_in[13];
  p.heroG = (const float *)d_in[14]; p.heroBe = (const float *)d_in[15];
  p.gW = (const float *)d_in[16]; p.gB = (const float *)d_in[17];
  p.ln1g = (const float *)d_in[18]; p.ln1b = (const float *)d_in[19];
  p.qkvW = (const float *)d_in[20]; p.qkvB = (const float *)d_in[21];
  p.oW = (const float *)d_in[22]; p.oB = (const float *)d_in[23];
  p.ln2g = (const float *)d_in[24]; p.ln2b = (const float *)d_in[25];
  p.f1W = (const float *)d_in[26]; p.f1B = (const float *)d_in[27];
  p.f2W = (const float *)d_in[28]; p.f2B = (const float *)d_in[29];
  p.plng = (const float *)d_in[30]; p.plnb = (const float *)d_in[31];
  p.atW1 = (const float *)d_in[32]; p.atB1 = (const float *)d_in[33];
  p.atW2 = (const float *)d_in[34]; p.atB2 = (const float *)d_in[35];
  p.hxW1 = (const float *)d_in[36]; p.hxB1 = (const float *)d_in[37];
  p.hxW2 = (const float *)d_in[38]; p.hxB2 = (const float *)d_in[39];
  p.tgW1 = (const float *)d_in[40]; p.tgB1 = (const float *)d_in[41];
  p.tgW2 = (const float *)d_in[42]; p.tgB2 = (const float *)d_in[43];
  p.vlW1 = (const float *)d_in[44]; p.vlB1 = (const float *)d_in[45];
  p.vlW2 = (const float *)d_in[46]; p.vlB2 = (const float *)d_in[47];
  p.out = (float *)d_out;
  battle_kernel<<<dim3(B_), dim3(192), 0, stream>>>(p);
}

// Round 14
// 2691.669 us; speedup vs baseline: 26.5917x; 2.8431x over previous
//
#include <hip/hip_runtime.h>
#include <hip/hip_bf16.h>

#define DEV static __device__ __forceinline__

typedef __attribute__((ext_vector_type(8))) short bf16x8;
typedef __attribute__((ext_vector_type(4))) float f32x4;
#define MFMA16 __builtin_amdgcn_mfma_f32_16x16x32_bf16

DEV unsigned short f2bf_rn(float x) {
  unsigned u = __float_as_uint(x);
  u = u + 0x7fffu + ((u >> 16) & 1u);
  return (unsigned short)(u >> 16);
}
DEV unsigned pack2(float a, float b) {
  return (unsigned)f2bf_rn(a) | ((unsigned)f2bf_rn(b) << 16);
}
DEV float lo2f(unsigned w) { return __uint_as_float(w << 16); }
DEV float hi2f(unsigned w) { return __uint_as_float(w & 0xffff0000u); }

constexpr int H_ = 187, MS_ = 20, MOB_ = 10, D_ = 128, NH_ = 4, NL_ = 4,
              CE_ = 16, NAT_ = 5, NCT_ = 256, HEXC_ = 29, B_ = 1024;
constexpr int S_ = H_ + 2;   // 189 tokens
constexpr int ST = 68;       // tokp/xln/area row stride (u32)
constexpr int PST = 36;      // P (scores/QK staging) row stride (u32)
constexpr int VTS = 100;     // V^T row stride (u32)

constexpr int VT_OFF   = 192 * PST;        // 6912
constexpr int CORR_OFF = VT_OFF + 32 * VTS; // 10112
constexpr int LSUM_OFF = CORR_OFF + 192;    // 10304
constexpr int GV_OFF   = LSUM_OFF + 192;    // 10496
constexpr int PO_OFF   = GV_OFF + 128;
constexpr int H1_OFF   = PO_OFF + 128;
constexpr int H2_OFF   = H1_OFF + 128;      // ends 11008 < 13056

constexpr int OFF_HEX = B_ * NAT_;
constexpr int OFF_TGT = OFF_HEX + B_ * H_;
constexpr int OFF_VAL = OFF_TGT + B_ * MS_;

constexpr float SCALE = 0.17677669529663687f;  // 1/sqrt(32)

struct Params {
  const float *scalars, *stacks, *obstacles, *reach;
  const int  *n_stacks;
  const float *cemb, *pos_emb, *tte;
  const float *hexW, *hexB, *hexG, *hexBe;
  const float *heroW, *heroB, *heroG, *heroBe;
  const float *gW, *gB;
  const float *ln1g, *ln1b, *qkvW, *qkvB, *oW, *oB;
  const float *ln2g, *ln2b, *f1W, *f1B, *f2W, *f2B;
  const float *plng, *plnb;
  const float *atW1, *atB1, *atW2, *atB2;
  const float *hxW1, *hxB1, *hxW2, *hxB2;
  const float *tgW1, *tgB1, *tgW2, *tgB2;
  const float *vlW1, *vlB1, *vlW2, *vlB2;
  float *out;
};

// A/B fragment load: lane l&15 = free-index row; k = (l>>4)*8 + j contiguous.
DEV bf16x8 ldAx(const unsigned* buf, int stride, int mbase, int cbase, int lane) {
  return *(const bf16x8*)(buf + (mbase + (lane & 15)) * stride + cbase +
                          ((lane >> 4) << 2));
}
DEV bf16x8 ldBw(const float* wrow, int koff) {
  const float* q = wrow + koff;
  bf16x8 r;
#pragma unroll
  for (int j = 0; j < 8; ++j) r[j] = (short)f2bf_rn(q[j]);
  return r;
}

__global__ __launch_bounds__(384, 1) void battle_kernel(Params p) {
  __shared__ __align__(16) unsigned tokp[192 * ST];
  __shared__ __align__(16) unsigned xln[192 * ST];
  __shared__ __align__(16) unsigned area[192 * ST];
  __shared__ int svalid[MS_], sposc[MS_];

  const int b = blockIdx.x;
  const int tid = threadIdx.x;
  const int lane = tid & 63;
  const int wave = tid >> 6;  // 0..5
  const bool hasrow = tid < S_;
  const float *sc = p.scalars + b * 19;

  float *areaF = (float *)area;
  unsigned short *tok16 = (unsigned short *)tokp;
  unsigned short *xln16 = (unsigned short *)xln;
  unsigned short *P16 = (unsigned short *)area;
  unsigned short *vt16 = (unsigned short *)(area + VT_OFF);

  float *hexcont = (float *)area;          // u32 0..5422
  int   *cids    = (int *)area + 5440;
  float *obsch   = (float *)area + 5632;   // ends 5819 < VT_OFF

  // ---- E0 ----
  if (tid < D_) {
    float g0 = sc[1] * 0.02f, g1 = sc[4] * 0.1f, g2 = sc[5] * 0.1f;
    float g3 = sc[6], g4 = sc[3];
    const float *w = p.gW + tid * 5;
    areaF[GV_OFF + tid] = p.gB[tid] + g0 * w[0] + g1 * w[1] + g2 * w[2] +
                          g3 * w[3] + g4 * w[4];
  }
  for (int i = tid; i < H_ * HEXC_; i += 384) hexcont[i] = 0.f;
  for (int i = tid; i < H_; i += 384) { cids[i] = 0; obsch[i] = 0.f; }
  if (tid >= 189 && tid < 192) {  // zero pad rows of tokp (avoid NaN in RMW)
    for (int c = 0; c < 64; ++c) tokp[tid * ST + c] = 0u;
  }
  __syncthreads();

  // ---- E2: stack scatter ----
  if (tid < MS_) {
    const float *st = p.stacks + (b * MS_ + tid) * 35;
    int pos = (int)st[18];
    float alive = st[23];
    int ns = p.n_stacks[b];
    bool valid = (pos >= 0) && (pos < H_) && (alive >= 0.5f) && (tid < ns);
    svalid[tid] = valid ? 1 : 0;
    sposc[tid] = min(max(pos, 0), H_ - 1);
    if (valid) {
      float maxhp = fmaxf(st[4], 1.0f);
      float *hc = hexcont + pos * HEXC_;
      hc[0] = 1.0f;
      hc[1] = st[2] * 1e-3f;
      hc[2] = st[3] / maxhp;
      hc[3] = st[8] * 0.01f;  hc[4] = st[9] * 0.01f;
      hc[5] = st[10] * 0.01f; hc[6] = st[11] * 0.01f;
      hc[7] = st[12] * 0.01f; hc[8] = st[13] * 0.01f;
      hc[9] = st[14] * 0.01f; hc[10] = st[15] * 0.01f;
      hc[11] = st[16] * 0.05f; hc[12] = st[17] * 0.05f;
      float s20 = st[20];
      hc[13] = s20;
      hc[14] = (s20 == sc[3]) ? 1.f : 0.f;
      hc[15] = alive;
      hc[16] = st[24]; hc[17] = st[25]; hc[18] = st[26];
      hc[19] = st[27]; hc[20] = st[28]; hc[21] = st[29];
      hc[22] = st[30];
      hc[23] = st[31] * (1.f / 30.f);
      hc[24] = st[33] * 0.2f;
      hc[25] = st[34] * 0.1f;
      hc[26] = (st[0] == sc[2]) ? 1.f : 0.f;
      hc[27] = 0.f; hc[28] = 0.f;
      cids[pos] = min((int)st[1], NCT_ - 1);
    }
  }
  if (tid >= 64 && tid < 64 + MOB_) {
    const float *ob = p.obstacles + (b * MOB_ + (tid - 64)) * 3;
    int opos = (int)ob[2];
    if (ob[0] > 0.f && opos >= 0 && opos < H_) obsch[opos] = 1.0f;
  }
  __syncthreads();

  // ---- E4/E5: tokens -> tokp (bf16 pairs) ----
  if (tid < H_) {
    const int r = tid;
    float f[HEXC_ + CE_];
#pragma unroll
    for (int c = 0; c < HEXC_; ++c) f[c] = hexcont[r * HEXC_ + c];
    f[27] = p.reach[b * H_ + r];
    f[28] = obsch[r];
    int cid = cids[r];
#pragma unroll
    for (int e = 0; e < CE_; ++e) f[HEXC_ + e] = p.cemb[cid * CE_ + e];
    float sum = 0.f;
    for (int d2 = 0; d2 < 64; ++d2) {
      const float *w0 = p.hexW + (2 * d2) * 45;
      const float *w1 = w0 + 45;
      float a0 = p.hexB[2 * d2], a1 = 0.f, a2 = 0.f, a3 = 0.f;
      float b0 = p.hexB[2 * d2 + 1], b1 = 0.f, b2 = 0.f, b3 = 0.f;
#pragma unroll
      for (int k = 0; k < 44; k += 4) {
        a0 = fmaf(f[k], w0[k], a0);       a1 = fmaf(f[k + 1], w0[k + 1], a1);
        a2 = fmaf(f[k + 2], w0[k + 2], a2); a3 = fmaf(f[k + 3], w0[k + 3], a3);
        b0 = fmaf(f[k], w1[k], b0);       b1 = fmaf(f[k + 1], w1[k + 1], b1);
        b2 = fmaf(f[k + 2], w1[k + 2], b2); b3 = fmaf(f[k + 3], w1[k + 3], b3);
      }
      a0 = fmaf(f[44], w0[44], a0);
      b0 = fmaf(f[44], w1[44], b0);
      float va = (a0 + a1) + (a2 + a3), vb = (b0 + b1) + (b2 + b3);
      tokp[r * ST + d2] = pack2(va, vb);
      sum += va + vb;
    }
    float m = sum * (1.f / 128.f);
    float var = 0.f;
#pragma unroll 4
    for (int d2 = 0; d2 < 64; ++d2) {
      unsigned w = tokp[r * ST + d2];
      float t0 = lo2f(w) - m, t1 = hi2f(w) - m;
      var = fmaf(t0, t0, var); var = fmaf(t1, t1, var);
    }
    float rs = rsqrtf(var * (1.f / 128.f) + 1e-5f);
#pragma unroll 2
    for (int d2 = 0; d2 < 64; ++d2) {
      unsigned w = tokp[r * ST + d2];
      int d = 2 * d2;
      float v0 = (lo2f(w) - m) * rs * p.hexG[d] + p.hexBe[d] +
                 p.pos_emb[r * D_ + d] + p.tte[d] + areaF[GV_OFF + d];
      float v1 = (hi2f(w) - m) * rs * p.hexG[d + 1] + p.hexBe[d + 1] +
                 p.pos_emb[r * D_ + d + 1] + p.tte[d + 1] + areaF[GV_OFF + d + 1];
      tokp[r * ST + d2] = pack2(v0, v1);
    }
  } else if (tid < S_) {
    const int which = tid - H_;
    float f0, f1, f2, f3, f4;
    if (which == 0) {
      f0 = sc[8];  f1 = sc[11] * (1.f / 300.f);
      f2 = sc[10] * 0.1f; f3 = sc[12] * 0.1f; f4 = 0.f;
    } else {
      f0 = sc[14]; f1 = sc[17] * (1.f / 300.f);
      f2 = sc[16] * 0.1f; f3 = sc[18] * 0.1f; f4 = 1.f;
    }
    const int r = tid;
    float sum = 0.f;
    for (int d2 = 0; d2 < 64; ++d2) {
      const float *w0 = p.heroW + (2 * d2) * 5;
      const float *w1 = w0 + 5;
      float va = p.heroB[2 * d2] + f0 * w0[0] + f1 * w0[1] + f2 * w0[2] + f3 * w0[3] + f4 * w0[4];
      float vb = p.heroB[2 * d2 + 1] + f0 * w1[0] + f1 * w1[1] + f2 * w1[2] + f3 * w1[3] + f4 * w1[4];
      tokp[r * ST + d2] = pack2(va, vb);
      sum += va + vb;
    }
    float m = sum * (1.f / 128.f);
    float var = 0.f;
    for (int d2 = 0; d2 < 64; ++d2) {
      unsigned w = tokp[r * ST + d2];
      float t0 = lo2f(w) - m, t1 = hi2f(w) - m;
      var = fmaf(t0, t0, var); var = fmaf(t1, t1, var);
    }
    float rs = rsqrtf(var * (1.f / 128.f) + 1e-5f);
    for (int d2 = 0; d2 < 64; ++d2) {
      unsigned w = tokp[r * ST + d2];
      int d = 2 * d2;
      float v0 = (lo2f(w) - m) * rs * p.heroG[d] + p.heroBe[d] +
                 p.tte[(1 + which) * D_ + d] + areaF[GV_OFF + d];
      float v1 = (hi2f(w) - m) * rs * p.heroG[d + 1] + p.heroBe[d + 1] +
                 p.tte[(1 + which) * D_ + d + 1] + areaF[GV_OFF + d + 1];
      tokp[r * ST + d2] = pack2(v0, v1);
    }
  }

  // ---- transformer layers ----
  for (int l = 0; l < NL_; ++l) {
    const float *ln1g = p.ln1g + l * D_, *ln1b = p.ln1b + l * D_;
    const float *qkvW = p.qkvW + l * 3 * D_ * D_, *qkvB = p.qkvB + l * 3 * D_;
    const float *oW = p.oW + l * D_ * D_, *oB = p.oB + l * D_;
    const float *ln2g = p.ln2g + l * D_, *ln2b = p.ln2b + l * D_;
    const float *f1W = p.f1W + l * 4 * D_ * D_, *f1B = p.f1B + l * 4 * D_;
    const float *f2W = p.f2W + l * 4 * D_ * D_, *f2B = p.f2B + l * D_;

    __syncthreads();

    // LN1 -> xln
    if (hasrow) {
      float s0 = 0.f, s1 = 0.f;
#pragma unroll 8
      for (int d2 = 0; d2 < 64; ++d2) {
        unsigned w = tokp[tid * ST + d2];
        s0 += lo2f(w); s1 += hi2f(w);
      }
      float m = (s0 + s1) * (1.f / 128.f);
      float v0 = 0.f, v1 = 0.f;
#pragma unroll 8
      for (int d2 = 0; d2 < 64; ++d2) {
        unsigned w = tokp[tid * ST + d2];
        float t0 = lo2f(w) - m, t1 = hi2f(w) - m;
        v0 = fmaf(t0, t0, v0); v1 = fmaf(t1, t1, v1);
      }
      float rs = rsqrtf((v0 + v1) * (1.f / 128.f) + 1e-5f);
#pragma unroll 2
      for (int d2 = 0; d2 < 64; ++d2) {
        unsigned w = tokp[tid * ST + d2];
        int d = 2 * d2;
        xln[tid * ST + d2] = pack2((lo2f(w) - m) * rs * ln1g[d] + ln1b[d],
                                   (hi2f(w) - m) * rs * ln1g[d + 1] + ln1b[d + 1]);
      }
    } else if (tid < 192) {
      for (int d2 = 0; d2 < 64; ++d2) xln[tid * ST + d2] = 0u;
    }
    __syncthreads();

    f32x4 oacc[4][2][2];

#pragma unroll
    for (int h = 0; h < NH_; ++h) {
      // init O
#pragma unroll
      for (int mi = 0; mi < 2; ++mi)
#pragma unroll
        for (int nd = 0; nd < 2; ++nd) oacc[h][mi][nd] = {0.f, 0.f, 0.f, 0.f};

      // Phase A: QKV projection. 6 jobs = 6 waves.
      {
        int job = wave;
        int nrow0, c16 = 0, isV = 0, ntd = 0;
        if (job < 2)      { nrow0 = h * 32 + job * 16;            c16 = job * 16; }
        else if (job < 4) { nrow0 = 128 + h * 32 + (job - 2) * 16; c16 = 32 + (job - 2) * 16; }
        else              { nrow0 = 256 + h * 32 + (job - 4) * 16; isV = 1; ntd = job - 4; }
        const float *wrow = qkvW + (nrow0 + (lane & 15)) * 128;
        int koff = (lane >> 4) << 3;
        bf16x8 b0 = ldBw(wrow, koff), b1 = ldBw(wrow, 32 + koff);
        bf16x8 b2 = ldBw(wrow, 64 + koff), b3 = ldBw(wrow, 96 + koff);
        float bv = qkvB[nrow0 + (lane & 15)];
        int col16 = c16 + (lane & 15);
#pragma unroll 1
        for (int mt = 0; mt < 12; ++mt) {
          f32x4 acc = {bv, bv, bv, bv};
          acc = MFMA16(ldAx(xln, ST, mt * 16, 0, lane), b0, acc, 0, 0, 0);
          acc = MFMA16(ldAx(xln, ST, mt * 16, 16, lane), b1, acc, 0, 0, 0);
          acc = MFMA16(ldAx(xln, ST, mt * 16, 32, lane), b2, acc, 0, 0, 0);
          acc = MFMA16(ldAx(xln, ST, mt * 16, 48, lane), b3, acc, 0, 0, 0);
          int rb = mt * 16 + ((lane >> 4) << 2);
          if (!isV) {
#pragma unroll
            for (int g = 0; g < 4; ++g)
              P16[(rb + g) * (PST * 2) + col16] = f2bf_rn(acc[g]);
          } else {
#pragma unroll
            for (int g = 0; g < 4; ++g)
              vt16[(ntd * 16 + (lane & 15)) * (VTS * 2) + rb + g] = f2bf_rn(acc[g]);
          }
        }
      }
      __syncthreads();

      // Phase B: load Q (own 2 mt) and all K fragments to registers
      bf16x8 qf0 = ldAx(area, PST, (2 * wave) * 16, 0, lane);
      bf16x8 qf1 = ldAx(area, PST, (2 * wave + 1) * 16, 0, lane);
      bf16x8 kf[12];
#pragma unroll
      for (int nt = 0; nt < 12; ++nt)
        kf[nt] = ldAx(area, PST, nt * 16, 16, lane);
      float mrun = -1e30f, lrun = 0.f;
      __syncthreads();  // P free for scores

      // j-tiles
#pragma unroll
      for (int t = 0; t < 3; ++t) {
        // QK^T: own 2 mt x 4 local nt
#pragma unroll
        for (int mi = 0; mi < 2; ++mi) {
          int rb = (2 * wave + mi) * 16 + ((lane >> 4) << 2);
#pragma unroll
          for (int ntl = 0; ntl < 4; ++ntl) {
            f32x4 s = {0.f, 0.f, 0.f, 0.f};
            s = MFMA16(mi ? qf1 : qf0, kf[t * 4 + ntl], s, 0, 0, 0);
            int col16 = ntl * 16 + (lane & 15);
#pragma unroll
            for (int g = 0; g < 4; ++g)
              P16[(rb + g) * (PST * 2) + col16] = f2bf_rn(s[g]);
          }
        }
        __syncthreads();
        // softmax partial (row per thread), two-pass
        if (tid < 192) {
          float tm = -1e30f;
#pragma unroll
          for (int c2 = 0; c2 < 32; ++c2) {
            unsigned w = area[tid * PST + c2];
            float v0 = lo2f(w) * SCALE, v1 = hi2f(w) * SCALE;
            if (t == 2 && c2 == 30) v1 = -1e30f;
            if (t == 2 && c2 == 31) { v0 = -1e30f; v1 = -1e30f; }
            tm = fmaxf(tm, fmaxf(v0, v1));
          }
          float mnew = fmaxf(mrun, tm);
          float corrv = __expf(mrun - mnew);
          float ts = 0.f;
#pragma unroll
          for (int c2 = 0; c2 < 32; ++c2) {
            unsigned w = area[tid * PST + c2];
            float e0 = __expf(lo2f(w) * SCALE - mnew);
            float e1 = __expf(hi2f(w) * SCALE - mnew);
            if (t == 2 && c2 == 30) e1 = 0.f;
            if (t == 2 && c2 == 31) { e0 = 0.f; e1 = 0.f; }
            ts += e0 + e1;
            area[tid * PST + c2] = pack2(e0, e1);
          }
          lrun = lrun * corrv + ts;
          mrun = mnew;
          areaF[CORR_OFF + tid] = corrv;
          if (t == 2) areaF[LSUM_OFF + tid] = lrun;
        }
        __syncthreads();
        // PV: rescale + accumulate
#pragma unroll
        for (int mi = 0; mi < 2; ++mi) {
          int rb = (2 * wave + mi) * 16 + ((lane >> 4) << 2);
          float c0 = areaF[CORR_OFF + rb], c1 = areaF[CORR_OFF + rb + 1];
          float c2v = areaF[CORR_OFF + rb + 2], c3 = areaF[CORR_OFF + rb + 3];
#pragma unroll
          for (int nd = 0; nd < 2; ++nd) {
            f32x4 a = oacc[h][mi][nd];
            a[0] *= c0; a[1] *= c1; a[2] *= c2v; a[3] *= c3;
#pragma unroll
            for (int kt = 0; kt < 2; ++kt) {
              bf16x8 af = ldAx(area, PST, (2 * wave + mi) * 16, kt * 16, lane);
              bf16x8 bv = *(const bf16x8*)(area + VT_OFF +
                            (nd * 16 + (lane & 15)) * VTS + t * 32 + kt * 16 +
                            ((lane >> 4) << 2));
              a = MFMA16(af, bv, a, 0, 0, 0);
            }
            oacc[h][mi][nd] = a;
          }
          if (t == 2) {
            float i0 = 1.f / areaF[LSUM_OFF + rb];
            float i1 = 1.f / areaF[LSUM_OFF + rb + 1];
            float i2 = 1.f / areaF[LSUM_OFF + rb + 2];
            float i3 = 1.f / areaF[LSUM_OFF + rb + 3];
#pragma unroll
            for (int nd = 0; nd < 2; ++nd) {
              f32x4 a = oacc[h][mi][nd];
              a[0] *= i0; a[1] *= i1; a[2] *= i2; a[3] *= i3;
              oacc[h][mi][nd] = a;
            }
          }
        }
        __syncthreads();
      }
    }  // heads

    // write O (all heads) -> xln
#pragma unroll
    for (int h = 0; h < NH_; ++h)
#pragma unroll
      for (int mi = 0; mi < 2; ++mi) {
        int rb = (2 * wave + mi) * 16 + ((lane >> 4) << 2);
#pragma unroll
        for (int nd = 0; nd < 2; ++nd) {
          int col16 = h * 32 + nd * 16 + (lane & 15);
          f32x4 a = oacc[h][mi][nd];
#pragma unroll
          for (int g = 0; g < 4; ++g)
            xln16[(rb + g) * (ST * 2) + col16] = f2bf_rn(a[g]);
        }
      }
    __syncthreads();

    // O-projection, fused residual RMW into tokp
#pragma unroll 1
    for (int job = wave; job < 16; job += 6) {
      int nt = job >> 1, mh = job & 1;
      const float *wrow = oW + (nt * 16 + (lane & 15)) * 128;
      int koff = (lane >> 4) << 3;
      bf16x8 b0 = ldBw(wrow, koff), b1 = ldBw(wrow, 32 + koff);
      bf16x8 b2 = ldBw(wrow, 64 + koff), b3 = ldBw(wrow, 96 + koff);
      float bv = oB[nt * 16 + (lane & 15)];
      int col16 = nt * 16 + (lane & 15);
#pragma unroll 1
      for (int mt = mh * 6; mt < mh * 6 + 6; ++mt) {
        f32x4 acc = {bv, bv, bv, bv};
        acc = MFMA16(ldAx(xln, ST, mt * 16, 0, lane), b0, acc, 0, 0, 0);
        acc = MFMA16(ldAx(xln, ST, mt * 16, 16, lane), b1, acc, 0, 0, 0);
        acc = MFMA16(ldAx(xln, ST, mt * 16, 32, lane), b2, acc, 0, 0, 0);
        acc = MFMA16(ldAx(xln, ST, mt * 16, 48, lane), b3, acc, 0, 0, 0);
        int rb = mt * 16 + ((lane >> 4) << 2);
#pragma unroll
        for (int g = 0; g < 4; ++g) {
          int a16 = (rb + g) * (ST * 2) + col16;
          float old = __uint_as_float((unsigned)tok16[a16] << 16);
          tok16[a16] = f2bf_rn(old + acc[g]);
        }
      }
    }
    __syncthreads();

    // LN2 -> xln
    if (hasrow) {
      float s0 = 0.f, s1 = 0.f;
#pragma unroll 8
      for (int d2 = 0; d2 < 64; ++d2) {
        unsigned w = tokp[tid * ST + d2];
        s0 += lo2f(w); s1 += hi2f(w);
      }
      float m = (s0 + s1) * (1.f / 128.f);
      float v0 = 0.f, v1 = 0.f;
#pragma unroll 8
      for (int d2 = 0; d2 < 64; ++d2) {
        unsigned w = tokp[tid * ST + d2];
        float t0 = lo2f(w) - m, t1 = hi2f(w) - m;
        v0 = fmaf(t0, t0, v0); v1 = fmaf(t1, t1, v1);
      }
      float rs = rsqrtf((v0 + v1) * (1.f / 128.f) + 1e-5f);
#pragma unroll 2
      for (int d2 = 0; d2 < 64; ++d2) {
        unsigned w = tokp[tid * ST + d2];
        int d = 2 * d2;
        xln[tid * ST + d2] = pack2((lo2f(w) - m) * rs * ln2g[d] + ln2b[d],
                                   (hi2f(w) - m) * rs * ln2g[d + 1] + ln2b[d + 1]);
      }
    } else if (tid < 192) {
      for (int d2 = 0; d2 < 64; ++d2) xln[tid * ST + d2] = 0u;
    }
    __syncthreads();

    // FFN: 4 chunks of 128 hidden; FFN2 accumulates in registers
    f32x4 acc2[2][12];
#pragma unroll
    for (int o = 0; o < 2; ++o) {
      int nt = wave + 6 * o;
      float bv = (nt < 8) ? f2B[nt * 16 + (lane & 15)] : 0.f;
#pragma unroll
      for (int mt = 0; mt < 12; ++mt) acc2[o][mt] = {bv, bv, bv, bv};
    }
    for (int chunk = 0; chunk < 4; ++chunk) {
      // FFN1 -> relu bf16 into area
#pragma unroll 1
      for (int job = wave; job < 16; job += 6) {
        int nt = job >> 1, mh = job & 1;
        const float *wrow = f1W + (chunk * 128 + nt * 16 + (lane & 15)) * 128;
        int koff = (lane >> 4) << 3;
        bf16x8 b0 = ldBw(wrow, koff), b1 = ldBw(wrow, 32 + koff);
        bf16x8 b2 = ldBw(wrow, 64 + koff), b3 = ldBw(wrow, 96 + koff);
        float bv = f1B[chunk * 128 + nt * 16 + (lane & 15)];
        int col16 = nt * 16 + (lane & 15);
#pragma unroll 1
        for (int mt = mh * 6; mt < mh * 6 + 6; ++mt) {
          f32x4 acc = {bv, bv, bv, bv};
          acc = MFMA16(ldAx(xln, ST, mt * 16, 0, lane), b0, acc, 0, 0, 0);
          acc = MFMA16(ldAx(xln, ST, mt * 16, 16, lane), b1, acc, 0, 0, 0);
          acc = MFMA16(ldAx(xln, ST, mt * 16, 32, lane), b2, acc, 0, 0, 0);
          acc = MFMA16(ldAx(xln, ST, mt * 16, 48, lane), b3, acc, 0, 0, 0);
          int rb = mt * 16 + ((lane >> 4) << 2);
#pragma unroll
          for (int g = 0; g < 4; ++g)
            P16[(rb + g) * (ST * 2) + col16] = f2bf_rn(fmaxf(acc[g], 0.f));
        }
      }
      __syncthreads();
      // FFN2 partial
#pragma unroll
      for (int o = 0; o < 2; ++o) {
        int nt = wave + 6 * o;
        if (nt < 8) {
          const float *wrow = f2W + (nt * 16 + (lane & 15)) * 512 + chunk * 128;
          int koff = (lane >> 4) << 3;
          bf16x8 b0 = ldBw(wrow, koff), b1 = ldBw(wrow, 32 + koff);
          bf16x8 b2 = ldBw(wrow, 64 + koff), b3 = ldBw(wrow, 96 + koff);
#pragma unroll
          for (int mt = 0; mt < 12; ++mt) {
            f32x4 a = acc2[o][mt];
            a = MFMA16(ldAx(area, ST, mt * 16, 0, lane), b0, a, 0, 0, 0);
            a = MFMA16(ldAx(area, ST, mt * 16, 16, lane), b1, a, 0, 0, 0);
            a = MFMA16(ldAx(area, ST, mt * 16, 32, lane), b2, a, 0, 0, 0);
            a = MFMA16(ldAx(area, ST, mt * 16, 48, lane), b3, a, 0, 0, 0);
            acc2[o][mt] = a;
          }
        }
      }
      __syncthreads();
    }
    // FFN2 residual RMW into tokp
#pragma unroll
    for (int o = 0; o < 2; ++o) {
      int nt = wave + 6 * o;
      if (nt < 8) {
        int col16 = nt * 16 + (lane & 15);
#pragma unroll
        for (int mt = 0; mt < 12; ++mt) {
          int rb = mt * 16 + ((lane >> 4) << 2);
          f32x4 a = acc2[o][mt];
#pragma unroll
          for (int g = 0; g < 4; ++g) {
            int a16 = (rb + g) * (ST * 2) + col16;
            float old = __uint_as_float((unsigned)tok16[a16] << 16);
            tok16[a16] = f2bf_rn(old + a[g]);
          }
        }
      }
    }
  }  // layers
  __syncthreads();

  // ---- post-LN ----
  if (hasrow) {
    float s0 = 0.f, s1 = 0.f;
#pragma unroll 8
    for (int d2 = 0; d2 < 64; ++d2) {
      unsigned w = tokp[tid * ST + d2];
      s0 += lo2f(w); s1 += hi2f(w);
    }
    float m = (s0 + s1) * (1.f / 128.f);
    float v0 = 0.f, v1 = 0.f;
#pragma unroll 8
    for (int d2 = 0; d2 < 64; ++d2) {
      unsigned w = tokp[tid * ST + d2];
      float t0 = lo2f(w) - m, t1 = hi2f(w) - m;
      v0 = fmaf(t0, t0, v0); v1 = fmaf(t1, t1, v1);
    }
    float rs = rsqrtf((v0 + v1) * (1.f / 128.f) + 1e-5f);
#pragma unroll 2
    for (int d2 = 0; d2 < 64; ++d2) {
      unsigned w = tokp[tid * ST + d2];
      int d = 2 * d2;
      tokp[tid * ST + d2] = pack2((lo2f(w) - m) * rs * p.plng[d] + p.plnb[d],
                                  (hi2f(w) - m) * rs * p.plng[d + 1] + p.plnb[d + 1]);
    }
  }
  __syncthreads();

  // ---- pooled mean ----
  if (tid < D_) {
    const int d2 = tid >> 1;
    const bool hi = tid & 1;
    float s0 = 0.f, s1 = 0.f;
    int r = 0;
    for (; r + 2 <= S_; r += 2) {
      unsigned w0 = tokp[r * ST + d2], w1 = tokp[(r + 1) * ST + d2];
      s0 += hi ? hi2f(w0) : lo2f(w0);
      s1 += hi ? hi2f(w1) : lo2f(w1);
    }
    unsigned wl = tokp[(S_ - 1) * ST + d2];
    s0 += hi ? hi2f(wl) : lo2f(wl);
    areaF[PO_OFF + tid] = (s0 + s1) * (1.f / (float)S_);
  }
  __syncthreads();
  if (tid < D_) {
    const float *wa = p.atW1 + tid * D_;
    const float *wv = p.vlW1 + tid * D_;
    float a0 = p.atB1[tid], a1 = 0.f, vv0 = p.vlB1[tid], vv1 = 0.f;
#pragma unroll 4
    for (int k = 0; k < D_; k += 2) {
      float pk0 = areaF[PO_OFF + k], pk1 = areaF[PO_OFF + k + 1];
      a0 = fmaf(pk0, wa[k], a0);   a1 = fmaf(pk1, wa[k + 1], a1);
      vv0 = fmaf(pk0, wv[k], vv0); vv1 = fmaf(pk1, wv[k + 1], vv1);
    }
    areaF[H1_OFF + tid] = fmaxf(a0 + a1, 0.f);
    areaF[H2_OFF + tid] = fmaxf(vv0 + vv1, 0.f);
  }
  __syncthreads();

  // ---- hex head ----
  if (tid < H_) {
    float hh[64];
#pragma unroll
    for (int j = 0; j < 64; ++j) hh[j] = p.hxB1[j];
    for (int kb = 0; kb < 8; ++kb) {
      float xr[16];
#pragma unroll
      for (int i2 = 0; i2 < 8; ++i2) {
        unsigned w = tokp[tid * ST + kb * 8 + i2];
        xr[2 * i2] = lo2f(w); xr[2 * i2 + 1] = hi2f(w);
      }
      const float *w = p.hxW1 + kb * 16;
#pragma unroll
      for (int j = 0; j < 64; ++j) {
#pragma unroll
        for (int i = 0; i < 16; ++i)
          hh[j] = fmaf(xr[i], w[j * D_ + i], hh[j]);
      }
    }
    float o = p.hxB2[0];
#pragma unroll
    for (int j = 0; j < 64; ++j) o = fmaf(fmaxf(hh[j], 0.f), p.hxW2[j], o);
    p.out[OFF_HEX + b * H_ + tid] = o;
  }
  if (tid < NAT_) {
    const float *w = p.atW2 + tid * D_;
    float o0 = p.atB2[tid], o1 = 0.f, o2 = 0.f, o3 = 0.f;
#pragma unroll 4
    for (int k = 0; k < D_; k += 4) {
      o0 = fmaf(areaF[H1_OFF + k], w[k], o0);
      o1 = fmaf(areaF[H1_OFF + k + 1], w[k + 1], o1);
      o2 = fmaf(areaF[H1_OFF + k + 2], w[k + 2], o2);
      o3 = fmaf(areaF[H1_OFF + k + 3], w[k + 3], o3);
    }
    p.out[b * NAT_ + tid] = (o0 + o1) + (o2 + o3);
  }
  if (tid == 190) {
    float o0 = p.vlB2[0], o1 = 0.f, o2 = 0.f, o3 = 0.f;
#pragma unroll 4
    for (int k = 0; k < D_; k += 4) {
      o0 = fmaf(areaF[H2_OFF + k], p.vlW2[k], o0);
      o1 = fmaf(areaF[H2_OFF + k + 1], p.vlW2[k + 1], o1);
      o2 = fmaf(areaF[H2_OFF + k + 2], p.vlW2[k + 2], o2);
      o3 = fmaf(areaF[H2_OFF + k + 3], p.vlW2[k + 3], o3);
    }
    p.out[OFF_VAL + b] = (o0 + o1) + (o2 + o3);
  }
  if (tid >= 32 && tid < 32 + MS_) {
    int si = tid - 32;
    float o;
    if (svalid[si]) {
      int r = sposc[si];
      float hh[64];
#pragma unroll
      for (int j = 0; j < 64; ++j) hh[j] = p.tgB1[j];
      for (int kb = 0; kb < 8; ++kb) {
        float xr[16];
#pragma unroll
        for (int i2 = 0; i2 < 8; ++i2) {
          unsigned w = tokp[r * ST + kb * 8 + i2];
          xr[2 * i2] = lo2f(w); xr[2 * i2 + 1] = hi2f(w);
        }
        const float *w = p.tgW1 + kb * 16;
#pragma unroll
        for (int j = 0; j < 64; ++j) {
#pragma unroll
          for (int i = 0; i < 16; ++i)
            hh[j] = fmaf(xr[i], w[j * D_ + i], hh[j]);
        }
      }
      o = p.tgB2[0];
#pragma unroll
      for (int j = 0; j < 64; ++j) o = fmaf(fmaxf(hh[j], 0.f), p.tgW2[j], o);
    } else {
      o = -1e9f;
    }
    p.out[OFF_TGT + b * MS_ + si] = o;
  }
}

extern "C" void kernel_launch(void* const* d_in, const int* in_sizes, int n_in,
                              void* d_out, int out_size, void* d_ws, size_t ws_size,
                              hipStream_t stream) {
  (void)in_sizes; (void)n_in; (void)out_size; (void)d_ws; (void)ws_size;
  Params p;
  p.scalars = (const float *)d_in[0];
  p.stacks = (const float *)d_in[1];
  p.obstacles = (const float *)d_in[2];
  p.reach = (const float *)d_in[3];
  p.n_stacks = (const int *)d_in[4];
  p.cemb = (const float *)d_in[5];
  p.pos_emb = (const float *)d_in[6];
  p.tte = (const float *)d_in[7];
  p.hexW = (const float *)d_in[8];  p.hexB = (const float *)d_in[9];
  p.hexG = (const float *)d_in[10]; p.hexBe = (const float *)d_in[11];
  p.heroW = (const float *)d_in[12]; p.heroB = (const float *)d_in[13];
  p.heroG = (const float *)d_in[14]; p.heroBe = (const float *)d_in[15];
  p.gW = (const float *)d_in[16]; p.gB = (const float *)d_in[17];
  p.ln1g = (const float *)d_in[18]; p.ln1b = (const float *)d_in[19];
  p.qkvW = (const float *)d_in[20]; p.qkvB = (const float *)d_in[21];
  p.oW = (const float *)d_in[22]; p.oB = (const float *)d_in[23];
  p.ln2g = (const float *)d_in[24]; p.ln2b = (const float *)d_in[25];
  p.f1W = (const float *)d_in[26]; p.f1B = (const float *)d_in[27];
  p.f2W = (const float *)d_in[28]; p.f2B = (const float *)d_in[29];
  p.plng = (const float *)d_in[30]; p.plnb = (const float *)d_in[31];
  p.atW1 = (const float *)d_in[32]; p.atB1 = (const float *)d_in[33];
  p.atW2 = (const float *)d_in[34]; p.atB2 = (const float *)d_in[35];
  p.hxW1 = (const float *)d_in[36]; p.hxB1 = (const float *)d_in[37];
  p.hxW2 = (const float *)d_in[38]; p.hxB2 = (const float *)d_in[39];
  p.tgW1 = (const float *)d_in[40]; p.tgB1 = (const float *)d_in[41];
  p.tgW2 = (const float *)d_in[42]; p.tgB2 = (const float *)d_in[43];
  p.vlW1 = (const float *)d_in[44]; p.vlB1 = (const float *)d_in[45];
  p.vlW2 = (const float *)d_in[46]; p.vlB2 = (const float *)d_in[47];
  p.out = (float *)d_out;
  battle_kernel<<<dim3(B_), dim3(384), 0, stream>>>(p);
}

// Round 15
// 2114.721 us; speedup vs baseline: 33.8466x; 1.2728x over previous
//
#include <hip/hip_runtime.h>
#include <hip/hip_bf16.h>

#define DEV static __device__ __forceinline__

typedef __attribute__((ext_vector_type(8))) short bf16x8;
typedef __attribute__((ext_vector_type(4))) float f32x4;
#define MFMA16 __builtin_amdgcn_mfma_f32_16x16x32_bf16

DEV unsigned short f2bf_rn(float x) {
  unsigned u = __float_as_uint(x);
  u = u + 0x7fffu + ((u >> 16) & 1u);
  return (unsigned short)(u >> 16);
}
DEV unsigned pack2(float a, float b) {
  return (unsigned)f2bf_rn(a) | ((unsigned)f2bf_rn(b) << 16);
}
DEV float lo2f(unsigned w) { return __uint_as_float(w << 16); }
DEV float hi2f(unsigned w) { return __uint_as_float(w & 0xffff0000u); }

constexpr int H_ = 187, MS_ = 20, MOB_ = 10, D_ = 128, NH_ = 4, NL_ = 4,
              CE_ = 16, NAT_ = 5, NCT_ = 256, HEXC_ = 29, B_ = 1024;
constexpr int S_ = H_ + 2;
constexpr int ST = 68;
constexpr int PST = 36;
constexpr int VTS = 100;

constexpr int VT_OFF   = 192 * PST;
constexpr int CORR_OFF = VT_OFF + 32 * VTS;
constexpr int LSUM_OFF = CORR_OFF + 192;
constexpr int GV_OFF   = LSUM_OFF + 192;
constexpr int PO_OFF   = GV_OFF + 128;
constexpr int H1_OFF   = PO_OFF + 128;
constexpr int H2_OFF   = H1_OFF + 128;

constexpr int OFF_HEX = B_ * NAT_;
constexpr int OFF_TGT = OFF_HEX + B_ * H_;
constexpr int OFF_VAL = OFF_TGT + B_ * MS_;

constexpr float SCALE = 0.17677669529663687f;

// bf16 weight workspace layout (elements)
constexpr int WS_Q = 0;                       // 4 x 384 x 128
constexpr int WS_O = WS_Q + 4 * 384 * 128;    // 4 x 128 x 128
constexpr int WS_F1 = WS_O + 4 * 128 * 128;   // 4 x 512 x 128
constexpr int WS_F2 = WS_F1 + 4 * 512 * 128;  // 4 x 128 x 512
constexpr int WS_TOT = WS_F2 + 4 * 128 * 512; // 786432 elems

struct Params {
  const float *scalars, *stacks, *obstacles, *reach;
  const int  *n_stacks;
  const float *cemb, *pos_emb, *tte;
  const float *hexW, *hexB, *hexG, *hexBe;
  const float *heroW, *heroB, *heroG, *heroBe;
  const float *gW, *gB;
  const float *ln1g, *ln1b, *qkvW, *qkvB, *oW, *oB;
  const float *ln2g, *ln2b, *f1W, *f1B, *f2W, *f2B;
  const float *plng, *plnb;
  const float *atW1, *atB1, *atW2, *atB2;
  const float *hxW1, *hxB1, *hxW2, *hxB2;
  const float *tgW1, *tgB1, *tgW2, *tgB2;
  const float *vlW1, *vlB1, *vlW2, *vlB2;
  const unsigned short *wsb;
  float *out;
};

DEV bf16x8 ldAx(const unsigned* buf, int stride, int mbase, int cbase, int lane) {
  return *(const bf16x8*)(buf + (mbase + (lane & 15)) * stride + cbase +
                          ((lane >> 4) << 2));
}
DEV bf16x8 ldBw(const float* q) {
  bf16x8 r;
#pragma unroll
  for (int j = 0; j < 8; ++j) r[j] = (short)f2bf_rn(q[j]);
  return r;
}
template <bool WSB>
DEV bf16x8 ldB(const unsigned short* wb, const float* wf, int off) {
  if constexpr (WSB) return *(const bf16x8*)(wb + off);
  else return ldBw(wf + off);
}

__global__ __launch_bounds__(256) void convw_kernel(const float *qkv,
                                                    const float *o,
                                                    const float *f1,
                                                    const float *f2,
                                                    unsigned short *ws) {
  int i = blockIdx.x * 256 + threadIdx.x;
  if (i < WS_O) ws[i] = f2bf_rn(qkv[i - WS_Q]);
  else if (i < WS_F1) ws[i] = f2bf_rn(o[i - WS_O]);
  else if (i < WS_F2) ws[i] = f2bf_rn(f1[i - WS_F1]);
  else if (i < WS_TOT) ws[i] = f2bf_rn(f2[i - WS_F2]);
}

template <bool WSB>
__global__ __launch_bounds__(384, 1) void battle_kernel(Params p) {
  __shared__ __align__(16) unsigned tokp[192 * ST];
  __shared__ __align__(16) unsigned xln[192 * ST];
  __shared__ __align__(16) unsigned area[192 * ST];
  __shared__ int svalid[MS_], sposc[MS_];

  const int b = blockIdx.x;
  const int tid = threadIdx.x;
  const int lane = tid & 63;
  const int wave = tid >> 6;
  const bool hasrow = tid < S_;
  const float *sc = p.scalars + b * 19;

  float *areaF = (float *)area;
  unsigned short *tok16 = (unsigned short *)tokp;
  unsigned short *xln16 = (unsigned short *)xln;
  unsigned short *P16 = (unsigned short *)area;
  unsigned short *vt16 = (unsigned short *)(area + VT_OFF);

  float *hexcont = (float *)area;
  int   *cids    = (int *)area + 5440;
  float *obsch   = (float *)area + 5632;

  if (tid < D_) {
    float g0 = sc[1] * 0.02f, g1 = sc[4] * 0.1f, g2 = sc[5] * 0.1f;
    float g3 = sc[6], g4 = sc[3];
    const float *w = p.gW + tid * 5;
    areaF[GV_OFF + tid] = p.gB[tid] + g0 * w[0] + g1 * w[1] + g2 * w[2] +
                          g3 * w[3] + g4 * w[4];
  }
  for (int i = tid; i < H_ * HEXC_; i += 384) hexcont[i] = 0.f;
  for (int i = tid; i < H_; i += 384) { cids[i] = 0; obsch[i] = 0.f; }
  if (tid >= 189 && tid < 192) {
    for (int c = 0; c < 64; ++c) tokp[tid * ST + c] = 0u;
  }
  __syncthreads();

  if (tid < MS_) {
    const float *st = p.stacks + (b * MS_ + tid) * 35;
    int pos = (int)st[18];
    float alive = st[23];
    int ns = p.n_stacks[b];
    bool valid = (pos >= 0) && (pos < H_) && (alive >= 0.5f) && (tid < ns);
    svalid[tid] = valid ? 1 : 0;
    sposc[tid] = min(max(pos, 0), H_ - 1);
    if (valid) {
      float maxhp = fmaxf(st[4], 1.0f);
      float *hc = hexcont + pos * HEXC_;
      hc[0] = 1.0f;
      hc[1] = st[2] * 1e-3f;
      hc[2] = st[3] / maxhp;
      hc[3] = st[8] * 0.01f;  hc[4] = st[9] * 0.01f;
      hc[5] = st[10] * 0.01f; hc[6] = st[11] * 0.01f;
      hc[7] = st[12] * 0.01f; hc[8] = st[13] * 0.01f;
      hc[9] = st[14] * 0.01f; hc[10] = st[15] * 0.01f;
      hc[11] = st[16] * 0.05f; hc[12] = st[17] * 0.05f;
      float s20 = st[20];
      hc[13] = s20;
      hc[14] = (s20 == sc[3]) ? 1.f : 0.f;
      hc[15] = alive;
      hc[16] = st[24]; hc[17] = st[25]; hc[18] = st[26];
      hc[19] = st[27]; hc[20] = st[28]; hc[21] = st[29];
      hc[22] = st[30];
      hc[23] = st[31] * (1.f / 30.f);
      hc[24] = st[33] * 0.2f;
      hc[25] = st[34] * 0.1f;
      hc[26] = (st[0] == sc[2]) ? 1.f : 0.f;
      hc[27] = 0.f; hc[28] = 0.f;
      cids[pos] = min((int)st[1], NCT_ - 1);
    }
  }
  if (tid >= 64 && tid < 64 + MOB_) {
    const float *ob = p.obstacles + (b * MOB_ + (tid - 64)) * 3;
    int opos = (int)ob[2];
    if (ob[0] > 0.f && opos >= 0 && opos < H_) obsch[opos] = 1.0f;
  }
  __syncthreads();

  if (tid < H_) {
    const int r = tid;
    float f[HEXC_ + CE_];
#pragma unroll
    for (int c = 0; c < HEXC_; ++c) f[c] = hexcont[r * HEXC_ + c];
    f[27] = p.reach[b * H_ + r];
    f[28] = obsch[r];
    int cid = cids[r];
#pragma unroll
    for (int e = 0; e < CE_; ++e) f[HEXC_ + e] = p.cemb[cid * CE_ + e];
    float sum = 0.f;
    for (int d2 = 0; d2 < 64; ++d2) {
      const float *w0 = p.hexW + (2 * d2) * 45;
      const float *w1 = w0 + 45;
      float a0 = p.hexB[2 * d2], a1 = 0.f, a2 = 0.f, a3 = 0.f;
      float b0 = p.hexB[2 * d2 + 1], b1 = 0.f, b2 = 0.f, b3 = 0.f;
#pragma unroll
      for (int k = 0; k < 44; k += 4) {
        a0 = fmaf(f[k], w0[k], a0);       a1 = fmaf(f[k + 1], w0[k + 1], a1);
        a2 = fmaf(f[k + 2], w0[k + 2], a2); a3 = fmaf(f[k + 3], w0[k + 3], a3);
        b0 = fmaf(f[k], w1[k], b0);       b1 = fmaf(f[k + 1], w1[k + 1], b1);
        b2 = fmaf(f[k + 2], w1[k + 2], b2); b3 = fmaf(f[k + 3], w1[k + 3], b3);
      }
      a0 = fmaf(f[44], w0[44], a0);
      b0 = fmaf(f[44], w1[44], b0);
      float va = (a0 + a1) + (a2 + a3), vb = (b0 + b1) + (b2 + b3);
      tokp[r * ST + d2] = pack2(va, vb);
      sum += va + vb;
    }
    float m = sum * (1.f / 128.f);
    float var = 0.f;
#pragma unroll 4
    for (int d2 = 0; d2 < 64; ++d2) {
      unsigned w = tokp[r * ST + d2];
      float t0 = lo2f(w) - m, t1 = hi2f(w) - m;
      var = fmaf(t0, t0, var); var = fmaf(t1, t1, var);
    }
    float rs = rsqrtf(var * (1.f / 128.f) + 1e-5f);
#pragma unroll 2
    for (int d2 = 0; d2 < 64; ++d2) {
      unsigned w = tokp[r * ST + d2];
      int d = 2 * d2;
      float v0 = (lo2f(w) - m) * rs * p.hexG[d] + p.hexBe[d] +
                 p.pos_emb[r * D_ + d] + p.tte[d] + areaF[GV_OFF + d];
      float v1 = (hi2f(w) - m) * rs * p.hexG[d + 1] + p.hexBe[d + 1] +
                 p.pos_emb[r * D_ + d + 1] + p.tte[d + 1] + areaF[GV_OFF + d + 1];
      tokp[r * ST + d2] = pack2(v0, v1);
    }
  } else if (tid < S_) {
    const int which = tid - H_;
    float f0, f1, f2, f3, f4;
    if (which == 0) {
      f0 = sc[8];  f1 = sc[11] * (1.f / 300.f);
      f2 = sc[10] * 0.1f; f3 = sc[12] * 0.1f; f4 = 0.f;
    } else {
      f0 = sc[14]; f1 = sc[17] * (1.f / 300.f);
      f2 = sc[16] * 0.1f; f3 = sc[18] * 0.1f; f4 = 1.f;
    }
    const int r = tid;
    float sum = 0.f;
    for (int d2 = 0; d2 < 64; ++d2) {
      const float *w0 = p.heroW + (2 * d2) * 5;
      const float *w1 = w0 + 5;
      float va = p.heroB[2 * d2] + f0 * w0[0] + f1 * w0[1] + f2 * w0[2] + f3 * w0[3] + f4 * w0[4];
      float vb = p.heroB[2 * d2 + 1] + f0 * w1[0] + f1 * w1[1] + f2 * w1[2] + f3 * w1[3] + f4 * w1[4];
      tokp[r * ST + d2] = pack2(va, vb);
      sum += va + vb;
    }
    float m = sum * (1.f / 128.f);
    float var = 0.f;
    for (int d2 = 0; d2 < 64; ++d2) {
      unsigned w = tokp[r * ST + d2];
      float t0 = lo2f(w) - m, t1 = hi2f(w) - m;
      var = fmaf(t0, t0, var); var = fmaf(t1, t1, var);
    }
    float rs = rsqrtf(var * (1.f / 128.f) + 1e-5f);
    for (int d2 = 0; d2 < 64; ++d2) {
      unsigned w = tokp[r * ST + d2];
      int d = 2 * d2;
      float v0 = (lo2f(w) - m) * rs * p.heroG[d] + p.heroBe[d] +
                 p.tte[(1 + which) * D_ + d] + areaF[GV_OFF + d];
      float v1 = (hi2f(w) - m) * rs * p.heroG[d + 1] + p.heroBe[d + 1] +
                 p.tte[(1 + which) * D_ + d + 1] + areaF[GV_OFF + d + 1];
      tokp[r * ST + d2] = pack2(v0, v1);
    }
  }

  for (int l = 0; l < NL_; ++l) {
    const float *ln1g = p.ln1g + l * D_, *ln1b = p.ln1b + l * D_;
    const float *qkvW = p.qkvW + l * 3 * D_ * D_, *qkvB = p.qkvB + l * 3 * D_;
    const float *oW = p.oW + l * D_ * D_, *oB = p.oB + l * D_;
    const float *ln2g = p.ln2g + l * D_, *ln2b = p.ln2b + l * D_;
    const float *f1W = p.f1W + l * 4 * D_ * D_, *f1B = p.f1B + l * 4 * D_;
    const float *f2W = p.f2W + l * 4 * D_ * D_, *f2B = p.f2B + l * D_;
    const unsigned short *qkvWb = p.wsb + WS_Q + l * 384 * 128;
    const unsigned short *oWb = p.wsb + WS_O + l * 128 * 128;
    const unsigned short *f1Wb = p.wsb + WS_F1 + l * 512 * 128;
    const unsigned short *f2Wb = p.wsb + WS_F2 + l * 128 * 512;

    __syncthreads();

    // LN1 -> xln
    if (hasrow) {
      float s0 = 0.f, s1 = 0.f;
#pragma unroll 8
      for (int d2 = 0; d2 < 64; ++d2) {
        unsigned w = tokp[tid * ST + d2];
        s0 += lo2f(w); s1 += hi2f(w);
      }
      float m = (s0 + s1) * (1.f / 128.f);
      float v0 = 0.f, v1 = 0.f;
#pragma unroll 8
      for (int d2 = 0; d2 < 64; ++d2) {
        unsigned w = tokp[tid * ST + d2];
        float t0 = lo2f(w) - m, t1 = hi2f(w) - m;
        v0 = fmaf(t0, t0, v0); v1 = fmaf(t1, t1, v1);
      }
      float rs = rsqrtf((v0 + v1) * (1.f / 128.f) + 1e-5f);
#pragma unroll 2
      for (int d2 = 0; d2 < 64; ++d2) {
        unsigned w = tokp[tid * ST + d2];
        int d = 2 * d2;
        xln[tid * ST + d2] = pack2((lo2f(w) - m) * rs * ln1g[d] + ln1b[d],
                                   (hi2f(w) - m) * rs * ln1g[d + 1] + ln1b[d + 1]);
      }
    } else if (tid < 192) {
      for (int d2 = 0; d2 < 64; ++d2) xln[tid * ST + d2] = 0u;
    }
    __syncthreads();

    f32x4 oacc[4][2][2];

#pragma unroll
    for (int h = 0; h < NH_; ++h) {
#pragma unroll
      for (int mi = 0; mi < 2; ++mi)
#pragma unroll
        for (int nd = 0; nd < 2; ++nd) oacc[h][mi][nd] = {0.f, 0.f, 0.f, 0.f};

      // Phase A: QKV projection (6 jobs = 6 waves)
      {
        int job = wave;
        int nrow0, c16 = 0, isV = 0, ntd = 0;
        if (job < 2)      { nrow0 = h * 32 + job * 16;            c16 = job * 16; }
        else if (job < 4) { nrow0 = 128 + h * 32 + (job - 2) * 16; c16 = 32 + (job - 2) * 16; }
        else              { nrow0 = 256 + h * 32 + (job - 4) * 16; isV = 1; ntd = job - 4; }
        int roff = (nrow0 + (lane & 15)) * 128;
        int koff = (lane >> 4) << 3;
        bf16x8 b0 = ldB<WSB>(qkvWb, qkvW, roff + koff);
        bf16x8 b1 = ldB<WSB>(qkvWb, qkvW, roff + 32 + koff);
        bf16x8 b2 = ldB<WSB>(qkvWb, qkvW, roff + 64 + koff);
        bf16x8 b3 = ldB<WSB>(qkvWb, qkvW, roff + 96 + koff);
        float bv = qkvB[nrow0 + (lane & 15)];
        int col16 = c16 + (lane & 15);
#pragma unroll 1
        for (int mt = 0; mt < 12; ++mt) {
          f32x4 acc = {bv, bv, bv, bv};
          acc = MFMA16(ldAx(xln, ST, mt * 16, 0, lane), b0, acc, 0, 0, 0);
          acc = MFMA16(ldAx(xln, ST, mt * 16, 16, lane), b1, acc, 0, 0, 0);
          acc = MFMA16(ldAx(xln, ST, mt * 16, 32, lane), b2, acc, 0, 0, 0);
          acc = MFMA16(ldAx(xln, ST, mt * 16, 48, lane), b3, acc, 0, 0, 0);
          int rb = mt * 16 + ((lane >> 4) << 2);
          if (!isV) {
#pragma unroll
            for (int g = 0; g < 4; ++g)
              P16[(rb + g) * (PST * 2) + col16] = f2bf_rn(acc[g]);
          } else {
#pragma unroll
            for (int g = 0; g < 4; ++g)
              vt16[(ntd * 16 + (lane & 15)) * (VTS * 2) + rb + g] = f2bf_rn(acc[g]);
          }
        }
      }
      __syncthreads();

      bf16x8 qf0 = ldAx(area, PST, (2 * wave) * 16, 0, lane);
      bf16x8 qf1 = ldAx(area, PST, (2 * wave + 1) * 16, 0, lane);
      bf16x8 kf[12];
#pragma unroll
      for (int nt = 0; nt < 12; ++nt)
        kf[nt] = ldAx(area, PST, nt * 16, 16, lane);
      float mrun = -1e30f, lrun = 0.f;
      const int srow = 32 * wave + (lane & 31);  // softmax row (own wave block)
      const int shalf = lane >> 5;               // 0: cols 0..31, 1: 32..63
      __syncthreads();  // all waves done reading Q/K from P

      // barrier-free tile loop (each wave touches only its own P rows)
#pragma unroll
      for (int t = 0; t < 3; ++t) {
        // QK^T for own 32 rows x 64 cols
#pragma unroll
        for (int mi = 0; mi < 2; ++mi) {
          int rb = (2 * wave + mi) * 16 + ((lane >> 4) << 2);
#pragma unroll
          for (int ntl = 0; ntl < 4; ++ntl) {
            f32x4 s = {0.f, 0.f, 0.f, 0.f};
            s = MFMA16(mi ? qf1 : qf0, kf[t * 4 + ntl], s, 0, 0, 0);
            int col16 = ntl * 16 + (lane & 15);
#pragma unroll
            for (int g = 0; g < 4; ++g)
              P16[(rb + g) * (PST * 2) + col16] = f2bf_rn(s[g]);
          }
        }
        // in-wave softmax: lane pair (l, l^32) shares row srow
        {
          float tm = -1e30f;
          int cb = shalf * 16;
#pragma unroll
          for (int c2i = 0; c2i < 16; ++c2i) {
            int c2 = cb + c2i;
            unsigned w = area[srow * PST + c2];
            float v0 = lo2f(w) * SCALE, v1 = hi2f(w) * SCALE;
            if (t == 2 && c2 == 30) v1 = -1e30f;
            if (t == 2 && c2 == 31) { v0 = -1e30f; v1 = -1e30f; }
            tm = fmaxf(tm, fmaxf(v0, v1));
          }
          tm = fmaxf(tm, __shfl_xor(tm, 32));
          float mnew = fmaxf(mrun, tm);
          float corrv = __expf(mrun - mnew);
          float ts = 0.f;
#pragma unroll
          for (int c2i = 0; c2i < 16; ++c2i) {
            int c2 = cb + c2i;
            unsigned w = area[srow * PST + c2];
            float e0 = __expf(lo2f(w) * SCALE - mnew);
            float e1 = __expf(hi2f(w) * SCALE - mnew);
            if (t == 2 && c2 == 30) e1 = 0.f;
            if (t == 2 && c2 == 31) { e0 = 0.f; e1 = 0.f; }
            ts += e0 + e1;
            area[srow * PST + c2] = pack2(e0, e1);
          }
          ts += __shfl_xor(ts, 32);
          lrun = lrun * corrv + ts;
          mrun = mnew;
          if (shalf == 0) {
            areaF[CORR_OFF + srow] = corrv;
            if (t == 2) areaF[LSUM_OFF + srow] = lrun;
          }
        }
        // PV for own rows (reads own P + stable VT + own corr)
#pragma unroll
        for (int mi = 0; mi < 2; ++mi) {
          int rb = (2 * wave + mi) * 16 + ((lane >> 4) << 2);
          float c0 = areaF[CORR_OFF + rb], c1 = areaF[CORR_OFF + rb + 1];
          float c2v = areaF[CORR_OFF + rb + 2], c3 = areaF[CORR_OFF + rb + 3];
#pragma unroll
          for (int nd = 0; nd < 2; ++nd) {
            f32x4 a = oacc[h][mi][nd];
            a[0] *= c0; a[1] *= c1; a[2] *= c2v; a[3] *= c3;
#pragma unroll
            for (int kt = 0; kt < 2; ++kt) {
              bf16x8 af = ldAx(area, PST, (2 * wave + mi) * 16, kt * 16, lane);
              bf16x8 bv = *(const bf16x8*)(area + VT_OFF +
                            (nd * 16 + (lane & 15)) * VTS + t * 32 + kt * 16 +
                            ((lane >> 4) << 2));
              a = MFMA16(af, bv, a, 0, 0, 0);
            }
            oacc[h][mi][nd] = a;
          }
          if (t == 2) {
            float i0 = 1.f / areaF[LSUM_OFF + rb];
            float i1 = 1.f / areaF[LSUM_OFF + rb + 1];
            float i2 = 1.f / areaF[LSUM_OFF + rb + 2];
            float i3 = 1.f / areaF[LSUM_OFF + rb + 3];
#pragma unroll
            for (int nd = 0; nd < 2; ++nd) {
              f32x4 a = oacc[h][mi][nd];
              a[0] *= i0; a[1] *= i1; a[2] *= i2; a[3] *= i3;
              oacc[h][mi][nd] = a;
            }
          }
        }
      }
      __syncthreads();  // before next head's phase A overwrites P/VT
    }  // heads

    // O write -> xln
#pragma unroll
    for (int h = 0; h < NH_; ++h)
#pragma unroll
      for (int mi = 0; mi < 2; ++mi) {
        int rb = (2 * wave + mi) * 16 + ((lane >> 4) << 2);
#pragma unroll
        for (int nd = 0; nd < 2; ++nd) {
          int col16 = h * 32 + nd * 16 + (lane & 15);
          f32x4 a = oacc[h][mi][nd];
#pragma unroll
          for (int g = 0; g < 4; ++g)
            xln16[(rb + g) * (ST * 2) + col16] = f2bf_rn(a[g]);
        }
      }
    __syncthreads();

    // O-projection + residual RMW
#pragma unroll 1
    for (int job = wave; job < 16; job += 6) {
      int nt = job >> 1, mh = job & 1;
      int roff = (nt * 16 + (lane & 15)) * 128;
      int koff = (lane >> 4) << 3;
      bf16x8 b0 = ldB<WSB>(oWb, oW, roff + koff);
      bf16x8 b1 = ldB<WSB>(oWb, oW, roff + 32 + koff);
      bf16x8 b2 = ldB<WSB>(oWb, oW, roff + 64 + koff);
      bf16x8 b3 = ldB<WSB>(oWb, oW, roff + 96 + koff);
      float bv = oB[nt * 16 + (lane & 15)];
      int col16 = nt * 16 + (lane & 15);
#pragma unroll 1
      for (int mt = mh * 6; mt < mh * 6 + 6; ++mt) {
        f32x4 acc = {bv, bv, bv, bv};
        acc = MFMA16(ldAx(xln, ST, mt * 16, 0, lane), b0, acc, 0, 0, 0);
        acc = MFMA16(ldAx(xln, ST, mt * 16, 16, lane), b1, acc, 0, 0, 0);
        acc = MFMA16(ldAx(xln, ST, mt * 16, 32, lane), b2, acc, 0, 0, 0);
        acc = MFMA16(ldAx(xln, ST, mt * 16, 48, lane), b3, acc, 0, 0, 0);
        int rb = mt * 16 + ((lane >> 4) << 2);
#pragma unroll
        for (int g = 0; g < 4; ++g) {
          int a16 = (rb + g) * (ST * 2) + col16;
          float old = __uint_as_float((unsigned)tok16[a16] << 16);
          tok16[a16] = f2bf_rn(old + acc[g]);
        }
      }
    }
    __syncthreads();

    // LN2 -> xln
    if (hasrow) {
      float s0 = 0.f, s1 = 0.f;
#pragma unroll 8
      for (int d2 = 0; d2 < 64; ++d2) {
        unsigned w = tokp[tid * ST + d2];
        s0 += lo2f(w); s1 += hi2f(w);
      }
      float m = (s0 + s1) * (1.f / 128.f);
      float v0 = 0.f, v1 = 0.f;
#pragma unroll 8
      for (int d2 = 0; d2 < 64; ++d2) {
        unsigned w = tokp[tid * ST + d2];
        float t0 = lo2f(w) - m, t1 = hi2f(w) - m;
        v0 = fmaf(t0, t0, v0); v1 = fmaf(t1, t1, v1);
      }
      float rs = rsqrtf((v0 + v1) * (1.f / 128.f) + 1e-5f);
#pragma unroll 2
      for (int d2 = 0; d2 < 64; ++d2) {
        unsigned w = tokp[tid * ST + d2];
        int d = 2 * d2;
        xln[tid * ST + d2] = pack2((lo2f(w) - m) * rs * ln2g[d] + ln2b[d],
                                   (hi2f(w) - m) * rs * ln2g[d + 1] + ln2b[d + 1]);
      }
    } else if (tid < 192) {
      for (int d2 = 0; d2 < 64; ++d2) xln[tid * ST + d2] = 0u;
    }
    __syncthreads();

    // FFN
    f32x4 acc2[2][12];
#pragma unroll
    for (int o = 0; o < 2; ++o) {
      int nt = wave + 6 * o;
      float bv = (nt < 8) ? f2B[nt * 16 + (lane & 15)] : 0.f;
#pragma unroll
      for (int mt = 0; mt < 12; ++mt) acc2[o][mt] = {bv, bv, bv, bv};
    }
    for (int chunk = 0; chunk < 4; ++chunk) {
#pragma unroll 1
      for (int job = wave; job < 16; job += 6) {
        int nt = job >> 1, mh = job & 1;
        int roff = (chunk * 128 + nt * 16 + (lane & 15)) * 128;
        int koff = (lane >> 4) << 3;
        bf16x8 b0 = ldB<WSB>(f1Wb, f1W, roff + koff);
        bf16x8 b1 = ldB<WSB>(f1Wb, f1W, roff + 32 + koff);
        bf16x8 b2 = ldB<WSB>(f1Wb, f1W, roff + 64 + koff);
        bf16x8 b3 = ldB<WSB>(f1Wb, f1W, roff + 96 + koff);
        float bv = f1B[chunk * 128 + nt * 16 + (lane & 15)];
        int col16 = nt * 16 + (lane & 15);
#pragma unroll 1
        for (int mt = mh * 6; mt < mh * 6 + 6; ++mt) {
          f32x4 acc = {bv, bv, bv, bv};
          acc = MFMA16(ldAx(xln, ST, mt * 16, 0, lane), b0, acc, 0, 0, 0);
          acc = MFMA16(ldAx(xln, ST, mt * 16, 16, lane), b1, acc, 0, 0, 0);
          acc = MFMA16(ldAx(xln, ST, mt * 16, 32, lane), b2, acc, 0, 0, 0);
          acc = MFMA16(ldAx(xln, ST, mt * 16, 48, lane), b3, acc, 0, 0, 0);
          int rb = mt * 16 + ((lane >> 4) << 2);
#pragma unroll
          for (int g = 0; g < 4; ++g)
            P16[(rb + g) * (ST * 2) + col16] = f2bf_rn(fmaxf(acc[g], 0.f));
        }
      }
      __syncthreads();
#pragma unroll
      for (int o = 0; o < 2; ++o) {
        int nt = wave + 6 * o;
        if (nt < 8) {
          int roff = (nt * 16 + (lane & 15)) * 512 + chunk * 128;
          int koff = (lane >> 4) << 3;
          bf16x8 b0 = ldB<WSB>(f2Wb, f2W, roff + koff);
          bf16x8 b1 = ldB<WSB>(f2Wb, f2W, roff + 32 + koff);
          bf16x8 b2 = ldB<WSB>(f2Wb, f2W, roff + 64 + koff);
          bf16x8 b3 = ldB<WSB>(f2Wb, f2W, roff + 96 + koff);
#pragma unroll
          for (int mt = 0; mt < 12; ++mt) {
            f32x4 a = acc2[o][mt];
            a = MFMA16(ldAx(area, ST, mt * 16, 0, lane), b0, a, 0, 0, 0);
            a = MFMA16(ldAx(area, ST, mt * 16, 16, lane), b1, a, 0, 0, 0);
            a = MFMA16(ldAx(area, ST, mt * 16, 32, lane), b2, a, 0, 0, 0);
            a = MFMA16(ldAx(area, ST, mt * 16, 48, lane), b3, a, 0, 0, 0);
            acc2[o][mt] = a;
          }
        }
      }
      __syncthreads();
    }
#pragma unroll
    for (int o = 0; o < 2; ++o) {
      int nt = wave + 6 * o;
      if (nt < 8) {
        int col16 = nt * 16 + (lane & 15);
#pragma unroll
        for (int mt = 0; mt < 12; ++mt) {
          int rb = mt * 16 + ((lane >> 4) << 2);
          f32x4 a = acc2[o][mt];
#pragma unroll
          for (int g = 0; g < 4; ++g) {
            int a16 = (rb + g) * (ST * 2) + col16;
            float old = __uint_as_float((unsigned)tok16[a16] << 16);
            tok16[a16] = f2bf_rn(old + a[g]);
          }
        }
      }
    }
  }  // layers
  __syncthreads();

  // post-LN
  if (hasrow) {
    float s0 = 0.f, s1 = 0.f;
#pragma unroll 8
    for (int d2 = 0; d2 < 64; ++d2) {
      unsigned w = tokp[tid * ST + d2];
      s0 += lo2f(w); s1 += hi2f(w);
    }
    float m = (s0 + s1) * (1.f / 128.f);
    float v0 = 0.f, v1 = 0.f;
#pragma unroll 8
    for (int d2 = 0; d2 < 64; ++d2) {
      unsigned w = tokp[tid * ST + d2];
      float t0 = lo2f(w) - m, t1 = hi2f(w) - m;
      v0 = fmaf(t0, t0, v0); v1 = fmaf(t1, t1, v1);
    }
    float rs = rsqrtf((v0 + v1) * (1.f / 128.f) + 1e-5f);
#pragma unroll 2
    for (int d2 = 0; d2 < 64; ++d2) {
      unsigned w = tokp[tid * ST + d2];
      int d = 2 * d2;
      tokp[tid * ST + d2] = pack2((lo2f(w) - m) * rs * p.plng[d] + p.plnb[d],
                                  (hi2f(w) - m) * rs * p.plng[d + 1] + p.plnb[d + 1]);
    }
  }
  __syncthreads();

  if (tid < D_) {
    const int d2 = tid >> 1;
    const bool hi = tid & 1;
    float s0 = 0.f, s1 = 0.f;
    int r = 0;
    for (; r + 2 <= S_; r += 2) {
      unsigned w0 = tokp[r * ST + d2], w1 = tokp[(r + 1) * ST + d2];
      s0 += hi ? hi2f(w0) : lo2f(w0);
      s1 += hi ? hi2f(w1) : lo2f(w1);
    }
    unsigned wl = tokp[(S_ - 1) * ST + d2];
    s0 += hi ? hi2f(wl) : lo2f(wl);
    areaF[PO_OFF + tid] = (s0 + s1) * (1.f / (float)S_);
  }
  __syncthreads();
  if (tid < D_) {
    const float *wa = p.atW1 + tid * D_;
    const float *wv = p.vlW1 + tid * D_;
    float a0 = p.atB1[tid], a1 = 0.f, vv0 = p.vlB1[tid], vv1 = 0.f;
#pragma unroll 4
    for (int k = 0; k < D_; k += 2) {
      float pk0 = areaF[PO_OFF + k], pk1 = areaF[PO_OFF + k + 1];
      a0 = fmaf(pk0, wa[k], a0);   a1 = fmaf(pk1, wa[k + 1], a1);
      vv0 = fmaf(pk0, wv[k], vv0); vv1 = fmaf(pk1, wv[k + 1], vv1);
    }
    areaF[H1_OFF + tid] = fmaxf(a0 + a1, 0.f);
    areaF[H2_OFF + tid] = fmaxf(vv0 + vv1, 0.f);
  }
  __syncthreads();

  if (tid < H_) {
    float hh[64];
#pragma unroll
    for (int j = 0; j < 64; ++j) hh[j] = p.hxB1[j];
    for (int kb = 0; kb < 8; ++kb) {
      float xr[16];
#pragma unroll
      for (int i2 = 0; i2 < 8; ++i2) {
        unsigned w = tokp[tid * ST + kb * 8 + i2];
        xr[2 * i2] = lo2f(w); xr[2 * i2 + 1] = hi2f(w);
      }
      const float *w = p.hxW1 + kb * 16;
#pragma unroll
      for (int j = 0; j < 64; ++j) {
#pragma unroll
        for (int i = 0; i < 16; ++i)
          hh[j] = fmaf(xr[i], w[j * D_ + i], hh[j]);
      }
    }
    float o = p.hxB2[0];
#pragma unroll
    for (int j = 0; j < 64; ++j) o = fmaf(fmaxf(hh[j], 0.f), p.hxW2[j], o);
    p.out[OFF_HEX + b * H_ + tid] = o;
  }
  if (tid < NAT_) {
    const float *w = p.atW2 + tid * D_;
    float o0 = p.atB2[tid], o1 = 0.f, o2 = 0.f, o3 = 0.f;
#pragma unroll 4
    for (int k = 0; k < D_; k += 4) {
      o0 = fmaf(areaF[H1_OFF + k], w[k], o0);
      o1 = fmaf(areaF[H1_OFF + k + 1], w[k + 1], o1);
      o2 = fmaf(areaF[H1_OFF + k + 2], w[k + 2], o2);
      o3 = fmaf(areaF[H1_OFF + k + 3], w[k + 3], o3);
    }
    p.out[b * NAT_ + tid] = (o0 + o1) + (o2 + o3);
  }
  if (tid == 190) {
    float o0 = p.vlB2[0], o1 = 0.f, o2 = 0.f, o3 = 0.f;
#pragma unroll 4
    for (int k = 0; k < D_; k += 4) {
      o0 = fmaf(areaF[H2_OFF + k], p.vlW2[k], o0);
      o1 = fmaf(areaF[H2_OFF + k + 1], p.vlW2[k + 1], o1);
      o2 = fmaf(areaF[H2_OFF + k + 2], p.vlW2[k + 2], o2);
      o3 = fmaf(areaF[H2_OFF + k + 3], p.vlW2[k + 3], o3);
    }
    p.out[OFF_VAL + b] = (o0 + o1) + (o2 + o3);
  }
  if (tid >= 32 && tid < 32 + MS_) {
    int si = tid - 32;
    float o;
    if (svalid[si]) {
      int r = sposc[si];
      float hh[64];
#pragma unroll
      for (int j = 0; j < 64; ++j) hh[j] = p.tgB1[j];
      for (int kb = 0; kb < 8; ++kb) {
        float xr[16];
#pragma unroll
        for (int i2 = 0; i2 < 8; ++i2) {
          unsigned w = tokp[r * ST + kb * 8 + i2];
          xr[2 * i2] = lo2f(w); xr[2 * i2 + 1] = hi2f(w);
        }
        const float *w = p.tgW1 + kb * 16;
#pragma unroll
        for (int j = 0; j < 64; ++j) {
#pragma unroll
          for (int i = 0; i < 16; ++i)
            hh[j] = fmaf(xr[i], w[j * D_ + i], hh[j]);
        }
      }
      o = p.tgB2[0];
#pragma unroll
      for (int j = 0; j < 64; ++j) o = fmaf(fmaxf(hh[j], 0.f), p.tgW2[j], o);
    } else {
      o = -1e9f;
    }
    p.out[OFF_TGT + b * MS_ + si] = o;
  }
}

extern "C" void kernel_launch(void* const* d_in, const int* in_sizes, int n_in,
                              void* d_out, int out_size, void* d_ws, size_t ws_size,
                              hipStream_t stream) {
  (void)in_sizes; (void)n_in; (void)out_size;
  Params p;
  p.scalars = (const float *)d_in[0];
  p.stacks = (const float *)d_in[1];
  p.obstacles = (const float *)d_in[2];
  p.reach = (const float *)d_in[3];
  p.n_stacks = (const int *)d_in[4];
  p.cemb = (const float *)d_in[5];
  p.pos_emb = (const float *)d_in[6];
  p.tte = (const float *)d_in[7];
  p.hexW = (const float *)d_in[8];  p.hexB = (const float *)d_in[9];
  p.hexG = (const float *)d_in[10]; p.hexBe = (const float *)d_in[11];
  p.heroW = (const float *)d_in[12]; p.heroB = (const float *)d_in[13];
  p.heroG = (const float *)d_in[14]; p.heroBe = (const float *)d_in[15];
  p.gW = (const float *)d_in[16]; p.gB = (const float *)d_in[17];
  p.ln1g = (const float *)d_in[18]; p.ln1b = (const float *)d_in[19];
  p.qkvW = (const float *)d_in[20]; p.qkvB = (const float *)d_in[21];
  p.oW = (const float *)d_in[22]; p.oB = (const float *)d_in[23];
  p.ln2g = (const float *)d_in[24]; p.ln2b = (const float *)d_in[25];
  p.f1W = (const float *)d_in[26]; p.f1B = (const float *)d_in[27];
  p.f2W = (const float *)d_in[28]; p.f2B = (const float *)d_in[29];
  p.plng = (const float *)d_in[30]; p.plnb = (const float *)d_in[31];
  p.atW1 = (const float *)d_in[32]; p.atB1 = (const float *)d_in[33];
  p.atW2 = (const float *)d_in[34]; p.atB2 = (const float *)d_in[35];
  p.hxW1 = (const float *)d_in[36]; p.hxB1 = (const float *)d_in[37];
  p.hxW2 = (const float *)d_in[38]; p.hxB2 = (const float *)d_in[39];
  p.tgW1 = (const float *)d_in[40]; p.tgB1 = (const float *)d_in[41];
  p.tgW2 = (const float *)d_in[42]; p.tgB2 = (const float *)d_in[43];
  p.vlW1 = (const float *)d_in[44]; p.vlB1 = (const float *)d_in[45];
  p.vlW2 = (const float *)d_in[46]; p.vlB2 = (const float *)d_in[47];
  p.out = (float *)d_out;
  bool usews = ws_size >= (size_t)WS_TOT * 2;
  if (usews) {
    p.wsb = (const unsigned short *)d_ws;
    convw_kernel<<<dim3((WS_TOT + 255) / 256), dim3(256), 0, stream>>>(
        p.qkvW, p.oW, p.f1W, p.f2W, (unsigned short *)d_ws);
    battle_kernel<true><<<dim3(B_), dim3(384), 0, stream>>>(p);
  } else {
    p.wsb = nullptr;
    battle_kernel<false><<<dim3(B_), dim3(384), 0, stream>>>(p);
  }
}

// Round 16
// 2085.972 us; speedup vs baseline: 34.3131x; 1.0138x over previous
//
#include <hip/hip_runtime.h>
#include <hip/hip_bf16.h>

#define DEV static __device__ __forceinline__

typedef __attribute__((ext_vector_type(8))) short bf16x8;
typedef __attribute__((ext_vector_type(4))) float f32x4;
#define MFMA16 __builtin_amdgcn_mfma_f32_16x16x32_bf16

DEV unsigned short f2bf_rn(float x) {
  unsigned u = __float_as_uint(x);
  u = u + 0x7fffu + ((u >> 16) & 1u);
  return (unsigned short)(u >> 16);
}
DEV unsigned pack2(float a, float b) {
  return (unsigned)f2bf_rn(a) | ((unsigned)f2bf_rn(b) << 16);
}
DEV float lo2f(unsigned w) { return __uint_as_float(w << 16); }
DEV float hi2f(unsigned w) { return __uint_as_float(w & 0xffff0000u); }

constexpr int H_ = 187, MS_ = 20, MOB_ = 10, D_ = 128, NH_ = 4, NL_ = 4,
              CE_ = 16, NAT_ = 5, NCT_ = 256, HEXC_ = 29, B_ = 1024;
constexpr int S_ = H_ + 2;
constexpr int ST = 68;
constexpr int PST = 36;
constexpr int VTS = 100;

constexpr int VT_OFF   = 192 * PST;
constexpr int CORR_OFF = VT_OFF + 32 * VTS;
constexpr int LSUM_OFF = CORR_OFF + 192;
constexpr int GV_OFF   = LSUM_OFF + 192;
constexpr int PO_OFF   = GV_OFF + 128;
constexpr int H1_OFF   = PO_OFF + 128;
constexpr int H2_OFF   = H1_OFF + 128;

constexpr int OFF_HEX = B_ * NAT_;
constexpr int OFF_TGT = OFF_HEX + B_ * H_;
constexpr int OFF_VAL = OFF_TGT + B_ * MS_;

constexpr float SCALE = 0.17677669529663687f;

constexpr int WS_Q = 0;
constexpr int WS_O = WS_Q + 4 * 384 * 128;
constexpr int WS_F1 = WS_O + 4 * 128 * 128;
constexpr int WS_F2 = WS_F1 + 4 * 512 * 128;
constexpr int WS_TOT = WS_F2 + 4 * 128 * 512;

struct Params {
  const float *scalars, *stacks, *obstacles, *reach;
  const int  *n_stacks;
  const float *cemb, *pos_emb, *tte;
  const float *hexW, *hexB, *hexG, *hexBe;
  const float *heroW, *heroB, *heroG, *heroBe;
  const float *gW, *gB;
  const float *ln1g, *ln1b, *qkvW, *qkvB, *oW, *oB;
  const float *ln2g, *ln2b, *f1W, *f1B, *f2W, *f2B;
  const float *plng, *plnb;
  const float *atW1, *atB1, *atW2, *atB2;
  const float *hxW1, *hxB1, *hxW2, *hxB2;
  const float *tgW1, *tgB1, *tgW2, *tgB2;
  const float *vlW1, *vlB1, *vlW2, *vlB2;
  const unsigned short *wsb;
  float *out;
};

DEV bf16x8 ldAx(const unsigned* buf, int stride, int mbase, int cbase, int lane) {
  return *(const bf16x8*)(buf + (mbase + (lane & 15)) * stride + cbase +
                          ((lane >> 4) << 2));
}
DEV bf16x8 ldBw(const float* q) {
  bf16x8 r;
#pragma unroll
  for (int j = 0; j < 8; ++j) r[j] = (short)f2bf_rn(q[j]);
  return r;
}
template <bool WSB>
DEV bf16x8 ldB(const unsigned short* wb, const float* wf, int off) {
  if constexpr (WSB) return *(const bf16x8*)(wb + off);
  else return ldBw(wf + off);
}

__global__ __launch_bounds__(256) void convw_kernel(const float *qkv,
                                                    const float *o,
                                                    const float *f1,
                                                    const float *f2,
                                                    unsigned short *ws) {
  int i = blockIdx.x * 256 + threadIdx.x;
  if (i < WS_O) ws[i] = f2bf_rn(qkv[i - WS_Q]);
  else if (i < WS_F1) ws[i] = f2bf_rn(o[i - WS_O]);
  else if (i < WS_F2) ws[i] = f2bf_rn(f1[i - WS_F1]);
  else if (i < WS_TOT) ws[i] = f2bf_rn(f2[i - WS_F2]);
}

template <bool WSB>
__global__ __launch_bounds__(768, 1) void battle_kernel(Params p) {
  __shared__ __align__(16) unsigned tokp[192 * ST];
  __shared__ __align__(16) unsigned xln[192 * ST];
  __shared__ __align__(16) unsigned area[192 * ST];
  __shared__ int svalid[MS_], sposc[MS_];

  const int b = blockIdx.x;
  const int tid = threadIdx.x;
  const int lane = tid & 63;
  const int wave = tid >> 6;           // 0..11
  const bool hasrow = tid < S_;
  const float *sc = p.scalars + b * 19;

  float *areaF = (float *)area;
  unsigned short *tok16 = (unsigned short *)tokp;
  unsigned short *xln16 = (unsigned short *)xln;
  unsigned short *P16 = (unsigned short *)area;
  unsigned short *vt16 = (unsigned short *)(area + VT_OFF);

  float *hexcont = (float *)area;
  int   *cids    = (int *)area + 5440;
  float *obsch   = (float *)area + 5632;

  if (tid < D_) {
    float g0 = sc[1] * 0.02f, g1 = sc[4] * 0.1f, g2 = sc[5] * 0.1f;
    float g3 = sc[6], g4 = sc[3];
    const float *w = p.gW + tid * 5;
    areaF[GV_OFF + tid] = p.gB[tid] + g0 * w[0] + g1 * w[1] + g2 * w[2] +
                          g3 * w[3] + g4 * w[4];
  }
  for (int i = tid; i < H_ * HEXC_; i += 768) hexcont[i] = 0.f;
  for (int i = tid; i < H_; i += 768) { cids[i] = 0; obsch[i] = 0.f; }
  if (tid >= 189 && tid < 192) {
    for (int c = 0; c < 64; ++c) tokp[tid * ST + c] = 0u;
  }
  __syncthreads();

  if (tid < MS_) {
    const float *st = p.stacks + (b * MS_ + tid) * 35;
    int pos = (int)st[18];
    float alive = st[23];
    int ns = p.n_stacks[b];
    bool valid = (pos >= 0) && (pos < H_) && (alive >= 0.5f) && (tid < ns);
    svalid[tid] = valid ? 1 : 0;
    sposc[tid] = min(max(pos, 0), H_ - 1);
    if (valid) {
      float maxhp = fmaxf(st[4], 1.0f);
      float *hc = hexcont + pos * HEXC_;
      hc[0] = 1.0f;
      hc[1] = st[2] * 1e-3f;
      hc[2] = st[3] / maxhp;
      hc[3] = st[8] * 0.01f;  hc[4] = st[9] * 0.01f;
      hc[5] = st[10] * 0.01f; hc[6] = st[11] * 0.01f;
      hc[7] = st[12] * 0.01f; hc[8] = st[13] * 0.01f;
      hc[9] = st[14] * 0.01f; hc[10] = st[15] * 0.01f;
      hc[11] = st[16] * 0.05f; hc[12] = st[17] * 0.05f;
      float s20 = st[20];
      hc[13] = s20;
      hc[14] = (s20 == sc[3]) ? 1.f : 0.f;
      hc[15] = alive;
      hc[16] = st[24]; hc[17] = st[25]; hc[18] = st[26];
      hc[19] = st[27]; hc[20] = st[28]; hc[21] = st[29];
      hc[22] = st[30];
      hc[23] = st[31] * (1.f / 30.f);
      hc[24] = st[33] * 0.2f;
      hc[25] = st[34] * 0.1f;
      hc[26] = (st[0] == sc[2]) ? 1.f : 0.f;
      hc[27] = 0.f; hc[28] = 0.f;
      cids[pos] = min((int)st[1], NCT_ - 1);
    }
  }
  if (tid >= 64 && tid < 64 + MOB_) {
    const float *ob = p.obstacles + (b * MOB_ + (tid - 64)) * 3;
    int opos = (int)ob[2];
    if (ob[0] > 0.f && opos >= 0 && opos < H_) obsch[opos] = 1.0f;
  }
  __syncthreads();

  if (tid < H_) {
    const int r = tid;
    float f[HEXC_ + CE_];
#pragma unroll
    for (int c = 0; c < HEXC_; ++c) f[c] = hexcont[r * HEXC_ + c];
    f[27] = p.reach[b * H_ + r];
    f[28] = obsch[r];
    int cid = cids[r];
#pragma unroll
    for (int e = 0; e < CE_; ++e) f[HEXC_ + e] = p.cemb[cid * CE_ + e];
    float sum = 0.f;
    for (int d2 = 0; d2 < 64; ++d2) {
      const float *w0 = p.hexW + (2 * d2) * 45;
      const float *w1 = w0 + 45;
      float a0 = p.hexB[2 * d2], a1 = 0.f, a2 = 0.f, a3 = 0.f;
      float b0 = p.hexB[2 * d2 + 1], b1 = 0.f, b2 = 0.f, b3 = 0.f;
#pragma unroll
      for (int k = 0; k < 44; k += 4) {
        a0 = fmaf(f[k], w0[k], a0);       a1 = fmaf(f[k + 1], w0[k + 1], a1);
        a2 = fmaf(f[k + 2], w0[k + 2], a2); a3 = fmaf(f[k + 3], w0[k + 3], a3);
        b0 = fmaf(f[k], w1[k], b0);       b1 = fmaf(f[k + 1], w1[k + 1], b1);
        b2 = fmaf(f[k + 2], w1[k + 2], b2); b3 = fmaf(f[k + 3], w1[k + 3], b3);
      }
      a0 = fmaf(f[44], w0[44], a0);
      b0 = fmaf(f[44], w1[44], b0);
      float va = (a0 + a1) + (a2 + a3), vb = (b0 + b1) + (b2 + b3);
      tokp[r * ST + d2] = pack2(va, vb);
      sum += va + vb;
    }
    float m = sum * (1.f / 128.f);
    float var = 0.f;
#pragma unroll 4
    for (int d2 = 0; d2 < 64; ++d2) {
      unsigned w = tokp[r * ST + d2];
      float t0 = lo2f(w) - m, t1 = hi2f(w) - m;
      var = fmaf(t0, t0, var); var = fmaf(t1, t1, var);
    }
    float rs = rsqrtf(var * (1.f / 128.f) + 1e-5f);
#pragma unroll 2
    for (int d2 = 0; d2 < 64; ++d2) {
      unsigned w = tokp[r * ST + d2];
      int d = 2 * d2;
      float v0 = (lo2f(w) - m) * rs * p.hexG[d] + p.hexBe[d] +
                 p.pos_emb[r * D_ + d] + p.tte[d] + areaF[GV_OFF + d];
      float v1 = (hi2f(w) - m) * rs * p.hexG[d + 1] + p.hexBe[d + 1] +
                 p.pos_emb[r * D_ + d + 1] + p.tte[d + 1] + areaF[GV_OFF + d + 1];
      tokp[r * ST + d2] = pack2(v0, v1);
    }
  } else if (tid < S_) {
    const int which = tid - H_;
    float f0, f1, f2, f3, f4;
    if (which == 0) {
      f0 = sc[8];  f1 = sc[11] * (1.f / 300.f);
      f2 = sc[10] * 0.1f; f3 = sc[12] * 0.1f; f4 = 0.f;
    } else {
      f0 = sc[14]; f1 = sc[17] * (1.f / 300.f);
      f2 = sc[16] * 0.1f; f3 = sc[18] * 0.1f; f4 = 1.f;
    }
    const int r = tid;
    float sum = 0.f;
    for (int d2 = 0; d2 < 64; ++d2) {
      const float *w0 = p.heroW + (2 * d2) * 5;
      const float *w1 = w0 + 5;
      float va = p.heroB[2 * d2] + f0 * w0[0] + f1 * w0[1] + f2 * w0[2] + f3 * w0[3] + f4 * w0[4];
      float vb = p.heroB[2 * d2 + 1] + f0 * w1[0] + f1 * w1[1] + f2 * w1[2] + f3 * w1[3] + f4 * w1[4];
      tokp[r * ST + d2] = pack2(va, vb);
      sum += va + vb;
    }
    float m = sum * (1.f / 128.f);
    float var = 0.f;
    for (int d2 = 0; d2 < 64; ++d2) {
      unsigned w = tokp[r * ST + d2];
      float t0 = lo2f(w) - m, t1 = hi2f(w) - m;
      var = fmaf(t0, t0, var); var = fmaf(t1, t1, var);
    }
    float rs = rsqrtf(var * (1.f / 128.f) + 1e-5f);
    for (int d2 = 0; d2 < 64; ++d2) {
      unsigned w = tokp[r * ST + d2];
      int d = 2 * d2;
      float v0 = (lo2f(w) - m) * rs * p.heroG[d] + p.heroBe[d] +
                 p.tte[(1 + which) * D_ + d] + areaF[GV_OFF + d];
      float v1 = (hi2f(w) - m) * rs * p.heroG[d + 1] + p.heroBe[d + 1] +
                 p.tte[(1 + which) * D_ + d + 1] + areaF[GV_OFF + d + 1];
      tokp[r * ST + d2] = pack2(v0, v1);
    }
  }

  const int lrow = tid >> 2;     // LN row (0..191)
  const int lsub = tid & 3;      // LN sub-slice (16 u32 each)

  for (int l = 0; l < NL_; ++l) {
    const float *ln1g = p.ln1g + l * D_, *ln1b = p.ln1b + l * D_;
    const float *qkvW = p.qkvW + l * 3 * D_ * D_, *qkvB = p.qkvB + l * 3 * D_;
    const float *oW = p.oW + l * D_ * D_, *oB = p.oB + l * D_;
    const float *ln2g = p.ln2g + l * D_, *ln2b = p.ln2b + l * D_;
    const float *f1W = p.f1W + l * 4 * D_ * D_, *f1B = p.f1B + l * 4 * D_;
    const float *f2W = p.f2W + l * 4 * D_ * D_, *f2B = p.f2B + l * D_;
    const unsigned short *qkvWb = p.wsb + WS_Q + l * 384 * 128;
    const unsigned short *oWb = p.wsb + WS_O + l * 128 * 128;
    const unsigned short *f1Wb = p.wsb + WS_F1 + l * 512 * 128;
    const unsigned short *f2Wb = p.wsb + WS_F2 + l * 128 * 512;

    __syncthreads();

    // LN1 -> xln (4 lanes per row)
    if (lrow < S_) {
      float s = 0.f;
#pragma unroll
      for (int i = 0; i < 16; ++i) {
        unsigned w = tokp[lrow * ST + lsub * 16 + i];
        s += lo2f(w) + hi2f(w);
      }
      s += __shfl_xor(s, 1); s += __shfl_xor(s, 2);
      float m = s * (1.f / 128.f);
      float v = 0.f;
#pragma unroll
      for (int i = 0; i < 16; ++i) {
        unsigned w = tokp[lrow * ST + lsub * 16 + i];
        float t0 = lo2f(w) - m, t1 = hi2f(w) - m;
        v = fmaf(t0, t0, v); v = fmaf(t1, t1, v);
      }
      v += __shfl_xor(v, 1); v += __shfl_xor(v, 2);
      float rs = rsqrtf(v * (1.f / 128.f) + 1e-5f);
#pragma unroll
      for (int i = 0; i < 16; ++i) {
        int d2 = lsub * 16 + i, d = 2 * d2;
        unsigned w = tokp[lrow * ST + d2];
        xln[lrow * ST + d2] = pack2((lo2f(w) - m) * rs * ln1g[d] + ln1b[d],
                                    (hi2f(w) - m) * rs * ln1g[d + 1] + ln1b[d + 1]);
      }
    } else {
#pragma unroll
      for (int i = 0; i < 16; ++i) xln[lrow * ST + lsub * 16 + i] = 0u;
    }
    __syncthreads();

    f32x4 oacc[4][2];

#pragma unroll
    for (int h = 0; h < NH_; ++h) {
#pragma unroll
      for (int nd = 0; nd < 2; ++nd) oacc[h][nd] = {0.f, 0.f, 0.f, 0.f};

      // Phase A: QKV projection, 12 jobs = 12 waves (nt of 6 x mhalf)
      {
        int ntg = wave >> 1, mh = wave & 1;
        int nrow0, c16 = 0, isV = 0, ntd = 0;
        if (ntg < 2)      { nrow0 = h * 32 + ntg * 16;            c16 = ntg * 16; }
        else if (ntg < 4) { nrow0 = 128 + h * 32 + (ntg - 2) * 16; c16 = 32 + (ntg - 2) * 16; }
        else              { nrow0 = 256 + h * 32 + (ntg - 4) * 16; isV = 1; ntd = ntg - 4; }
        int roff = (nrow0 + (lane & 15)) * 128;
        int koff = (lane >> 4) << 3;
        bf16x8 b0 = ldB<WSB>(qkvWb, qkvW, roff + koff);
        bf16x8 b1 = ldB<WSB>(qkvWb, qkvW, roff + 32 + koff);
        bf16x8 b2 = ldB<WSB>(qkvWb, qkvW, roff + 64 + koff);
        bf16x8 b3 = ldB<WSB>(qkvWb, qkvW, roff + 96 + koff);
        float bv = qkvB[nrow0 + (lane & 15)];
        int col16 = c16 + (lane & 15);
#pragma unroll 1
        for (int mt = mh * 6; mt < mh * 6 + 6; ++mt) {
          f32x4 acc = {bv, bv, bv, bv};
          acc = MFMA16(ldAx(xln, ST, mt * 16, 0, lane), b0, acc, 0, 0, 0);
          acc = MFMA16(ldAx(xln, ST, mt * 16, 16, lane), b1, acc, 0, 0, 0);
          acc = MFMA16(ldAx(xln, ST, mt * 16, 32, lane), b2, acc, 0, 0, 0);
          acc = MFMA16(ldAx(xln, ST, mt * 16, 48, lane), b3, acc, 0, 0, 0);
          int rb = mt * 16 + ((lane >> 4) << 2);
          if (!isV) {
#pragma unroll
            for (int g = 0; g < 4; ++g)
              P16[(rb + g) * (PST * 2) + col16] = f2bf_rn(acc[g]);
          } else {
#pragma unroll
            for (int g = 0; g < 4; ++g)
              vt16[(ntd * 16 + (lane & 15)) * (VTS * 2) + rb + g] = f2bf_rn(acc[g]);
          }
        }
      }
      __syncthreads();

      // Phase B: Q for own m-tile + all K fragments
      bf16x8 qf = ldAx(area, PST, wave * 16, 0, lane);
      bf16x8 kf[12];
#pragma unroll
      for (int nt = 0; nt < 12; ++nt)
        kf[nt] = ldAx(area, PST, nt * 16, 16, lane);
      float mrun = -1e30f, lrun = 0.f;
      const int srow = wave * 16 + (lane & 15);
      const int ssub = lane >> 4;  // 0..3, u32 cols ssub*8..+8
      __syncthreads();

#pragma unroll
      for (int t = 0; t < 3; ++t) {
        // QK^T for own 16 rows x 64 cols
        {
          int rb = wave * 16 + ((lane >> 4) << 2);
#pragma unroll
          for (int ntl = 0; ntl < 4; ++ntl) {
            f32x4 s = {0.f, 0.f, 0.f, 0.f};
            s = MFMA16(qf, kf[t * 4 + ntl], s, 0, 0, 0);
            int col16 = ntl * 16 + (lane & 15);
#pragma unroll
            for (int g = 0; g < 4; ++g)
              P16[(rb + g) * (PST * 2) + col16] = f2bf_rn(s[g]);
          }
        }
        // in-wave softmax: 4 lanes per row
        {
          float tm = -1e30f;
          int cb = ssub * 8;
#pragma unroll
          for (int i = 0; i < 8; ++i) {
            int c2 = cb + i;
            unsigned w = area[srow * PST + c2];
            float v0 = lo2f(w) * SCALE, v1 = hi2f(w) * SCALE;
            if (t == 2 && c2 == 30) v1 = -1e30f;
            if (t == 2 && c2 == 31) { v0 = -1e30f; v1 = -1e30f; }
            tm = fmaxf(tm, fmaxf(v0, v1));
          }
          tm = fmaxf(tm, __shfl_xor(tm, 16));
          tm = fmaxf(tm, __shfl_xor(tm, 32));
          float mnew = fmaxf(mrun, tm);
          float corrv = __expf(mrun - mnew);
          float ts = 0.f;
#pragma unroll
          for (int i = 0; i < 8; ++i) {
            int c2 = cb + i;
            unsigned w = area[srow * PST + c2];
            float e0 = __expf(lo2f(w) * SCALE - mnew);
            float e1 = __expf(hi2f(w) * SCALE - mnew);
            if (t == 2 && c2 == 30) e1 = 0.f;
            if (t == 2 && c2 == 31) { e0 = 0.f; e1 = 0.f; }
            ts += e0 + e1;
            area[srow * PST + c2] = pack2(e0, e1);
          }
          ts += __shfl_xor(ts, 16);
          ts += __shfl_xor(ts, 32);
          lrun = lrun * corrv + ts;
          mrun = mnew;
          if (ssub == 0) {
            areaF[CORR_OFF + srow] = corrv;
            if (t == 2) areaF[LSUM_OFF + srow] = lrun;
          }
        }
        // PV for own rows
        {
          int rb = wave * 16 + ((lane >> 4) << 2);
          float c0 = areaF[CORR_OFF + rb], c1 = areaF[CORR_OFF + rb + 1];
          float c2v = areaF[CORR_OFF + rb + 2], c3 = areaF[CORR_OFF + rb + 3];
#pragma unroll
          for (int nd = 0; nd < 2; ++nd) {
            f32x4 a = oacc[h][nd];
            a[0] *= c0; a[1] *= c1; a[2] *= c2v; a[3] *= c3;
#pragma unroll
            for (int kt = 0; kt < 2; ++kt) {
              bf16x8 af = ldAx(area, PST, wave * 16, kt * 16, lane);
              bf16x8 bv = *(const bf16x8*)(area + VT_OFF +
                            (nd * 16 + (lane & 15)) * VTS + t * 32 + kt * 16 +
                            ((lane >> 4) << 2));
              a = MFMA16(af, bv, a, 0, 0, 0);
            }
            oacc[h][nd] = a;
          }
          if (t == 2) {
            float i0 = 1.f / areaF[LSUM_OFF + rb];
            float i1 = 1.f / areaF[LSUM_OFF + rb + 1];
            float i2 = 1.f / areaF[LSUM_OFF + rb + 2];
            float i3 = 1.f / areaF[LSUM_OFF + rb + 3];
#pragma unroll
            for (int nd = 0; nd < 2; ++nd) {
              f32x4 a = oacc[h][nd];
              a[0] *= i0; a[1] *= i1; a[2] *= i2; a[3] *= i3;
              oacc[h][nd] = a;
            }
          }
        }
      }
      __syncthreads();
    }  // heads

    // O write -> xln (own m-tile, all heads)
#pragma unroll
    for (int h = 0; h < NH_; ++h) {
      int rb = wave * 16 + ((lane >> 4) << 2);
#pragma unroll
      for (int nd = 0; nd < 2; ++nd) {
        int col16 = h * 32 + nd * 16 + (lane & 15);
        f32x4 a = oacc[h][nd];
#pragma unroll
        for (int g = 0; g < 4; ++g)
          xln16[(rb + g) * (ST * 2) + col16] = f2bf_rn(a[g]);
      }
    }
    __syncthreads();

    // O-projection + residual RMW (16 jobs stride 12)
#pragma unroll 1
    for (int job = wave; job < 16; job += 12) {
      int nt = job >> 1, mh = job & 1;
      int roff = (nt * 16 + (lane & 15)) * 128;
      int koff = (lane >> 4) << 3;
      bf16x8 b0 = ldB<WSB>(oWb, oW, roff + koff);
      bf16x8 b1 = ldB<WSB>(oWb, oW, roff + 32 + koff);
      bf16x8 b2 = ldB<WSB>(oWb, oW, roff + 64 + koff);
      bf16x8 b3 = ldB<WSB>(oWb, oW, roff + 96 + koff);
      float bv = oB[nt * 16 + (lane & 15)];
      int col16 = nt * 16 + (lane & 15);
#pragma unroll 1
      for (int mt = mh * 6; mt < mh * 6 + 6; ++mt) {
        f32x4 acc = {bv, bv, bv, bv};
        acc = MFMA16(ldAx(xln, ST, mt * 16, 0, lane), b0, acc, 0, 0, 0);
        acc = MFMA16(ldAx(xln, ST, mt * 16, 16, lane), b1, acc, 0, 0, 0);
        acc = MFMA16(ldAx(xln, ST, mt * 16, 32, lane), b2, acc, 0, 0, 0);
        acc = MFMA16(ldAx(xln, ST, mt * 16, 48, lane), b3, acc, 0, 0, 0);
        int rb = mt * 16 + ((lane >> 4) << 2);
#pragma unroll
        for (int g = 0; g < 4; ++g) {
          int a16 = (rb + g) * (ST * 2) + col16;
          float old = __uint_as_float((unsigned)tok16[a16] << 16);
          tok16[a16] = f2bf_rn(old + acc[g]);
        }
      }
    }
    __syncthreads();

    // LN2 -> xln (4 lanes per row)
    if (lrow < S_) {
      float s = 0.f;
#pragma unroll
      for (int i = 0; i < 16; ++i) {
        unsigned w = tokp[lrow * ST + lsub * 16 + i];
        s += lo2f(w) + hi2f(w);
      }
      s += __shfl_xor(s, 1); s += __shfl_xor(s, 2);
      float m = s * (1.f / 128.f);
      float v = 0.f;
#pragma unroll
      for (int i = 0; i < 16; ++i) {
        unsigned w = tokp[lrow * ST + lsub * 16 + i];
        float t0 = lo2f(w) - m, t1 = hi2f(w) - m;
        v = fmaf(t0, t0, v); v = fmaf(t1, t1, v);
      }
      v += __shfl_xor(v, 1); v += __shfl_xor(v, 2);
      float rs = rsqrtf(v * (1.f / 128.f) + 1e-5f);
#pragma unroll
      for (int i = 0; i < 16; ++i) {
        int d2 = lsub * 16 + i, d = 2 * d2;
        unsigned w = tokp[lrow * ST + d2];
        xln[lrow * ST + d2] = pack2((lo2f(w) - m) * rs * ln2g[d] + ln2b[d],
                                    (hi2f(w) - m) * rs * ln2g[d + 1] + ln2b[d + 1]);
      }
    } else {
#pragma unroll
      for (int i = 0; i < 16; ++i) xln[lrow * ST + lsub * 16 + i] = 0u;
    }
    __syncthreads();

    // FFN: jobs {wave, wave+12}; 6-mt accumulators
    const int ja = wave;                       // job a: nt=ja>>1, mh=ja&1
    const bool hasb = wave < 4;
    const int jb = wave + 12;                  // job b (nt 6..7)
    const int nta = ja >> 1, mha = ja & 1;
    const int ntb = jb >> 1, mhb = jb & 1;
    f32x4 acca[6], accb[6];
    {
      float bva = f2B[nta * 16 + (lane & 15)];
#pragma unroll
      for (int i = 0; i < 6; ++i) acca[i] = {bva, bva, bva, bva};
      float bvb = hasb ? f2B[ntb * 16 + (lane & 15)] : 0.f;
#pragma unroll
      for (int i = 0; i < 6; ++i) accb[i] = {bvb, bvb, bvb, bvb};
    }
    for (int chunk = 0; chunk < 4; ++chunk) {
      // FFN1 (16 jobs stride 12) -> relu bf16 into area
#pragma unroll 1
      for (int job = wave; job < 16; job += 12) {
        int nt = job >> 1, mh = job & 1;
        int roff = (chunk * 128 + nt * 16 + (lane & 15)) * 128;
        int koff = (lane >> 4) << 3;
        bf16x8 b0 = ldB<WSB>(f1Wb, f1W, roff + koff);
        bf16x8 b1 = ldB<WSB>(f1Wb, f1W, roff + 32 + koff);
        bf16x8 b2 = ldB<WSB>(f1Wb, f1W, roff + 64 + koff);
        bf16x8 b3 = ldB<WSB>(f1Wb, f1W, roff + 96 + koff);
        float bv = f1B[chunk * 128 + nt * 16 + (lane & 15)];
        int col16 = nt * 16 + (lane & 15);
#pragma unroll 1
        for (int mt = mh * 6; mt < mh * 6 + 6; ++mt) {
          f32x4 acc = {bv, bv, bv, bv};
          acc = MFMA16(ldAx(xln, ST, mt * 16, 0, lane), b0, acc, 0, 0, 0);
          acc = MFMA16(ldAx(xln, ST, mt * 16, 16, lane), b1, acc, 0, 0, 0);
          acc = MFMA16(ldAx(xln, ST, mt * 16, 32, lane), b2, acc, 0, 0, 0);
          acc = MFMA16(ldAx(xln, ST, mt * 16, 48, lane), b3, acc, 0, 0, 0);
          int rb = mt * 16 + ((lane >> 4) << 2);
#pragma unroll
          for (int g = 0; g < 4; ++g)
            P16[(rb + g) * (ST * 2) + col16] = f2bf_rn(fmaxf(acc[g], 0.f));
        }
      }
      __syncthreads();
      // FFN2 partials: job a (all waves), job b (waves 0-3)
      {
        int roff = (nta * 16 + (lane & 15)) * 512 + chunk * 128;
        int koff = (lane >> 4) << 3;
        bf16x8 b0 = ldB<WSB>(f2Wb, f2W, roff + koff);
        bf16x8 b1 = ldB<WSB>(f2Wb, f2W, roff + 32 + koff);
        bf16x8 b2 = ldB<WSB>(f2Wb, f2W, roff + 64 + koff);
        bf16x8 b3 = ldB<WSB>(f2Wb, f2W, roff + 96 + koff);
#pragma unroll
        for (int i = 0; i < 6; ++i) {
          int mt = mha * 6 + i;
          f32x4 a = acca[i];
          a = MFMA16(ldAx(area, ST, mt * 16, 0, lane), b0, a, 0, 0, 0);
          a = MFMA16(ldAx(area, ST, mt * 16, 16, lane), b1, a, 0, 0, 0);
          a = MFMA16(ldAx(area, ST, mt * 16, 32, lane), b2, a, 0, 0, 0);
          a = MFMA16(ldAx(area, ST, mt * 16, 48, lane), b3, a, 0, 0, 0);
          acca[i] = a;
        }
      }
      if (hasb) {
        int roff = (ntb * 16 + (lane & 15)) * 512 + chunk * 128;
        int koff = (lane >> 4) << 3;
        bf16x8 b0 = ldB<WSB>(f2Wb, f2W, roff + koff);
        bf16x8 b1 = ldB<WSB>(f2Wb, f2W, roff + 32 + koff);
        bf16x8 b2 = ldB<WSB>(f2Wb, f2W, roff + 64 + koff);
        bf16x8 b3 = ldB<WSB>(f2Wb, f2W, roff + 96 + koff);
#pragma unroll
        for (int i = 0; i < 6; ++i) {
          int mt = mhb * 6 + i;
          f32x4 a = accb[i];
          a = MFMA16(ldAx(area, ST, mt * 16, 0, lane), b0, a, 0, 0, 0);
          a = MFMA16(ldAx(area, ST, mt * 16, 16, lane), b1, a, 0, 0, 0);
          a = MFMA16(ldAx(area, ST, mt * 16, 32, lane), b2, a, 0, 0, 0);
          a = MFMA16(ldAx(area, ST, mt * 16, 48, lane), b3, a, 0, 0, 0);
          accb[i] = a;
        }
      }
      __syncthreads();
    }
    // FFN2 residual RMW
    {
      int col16 = nta * 16 + (lane & 15);
#pragma unroll
      for (int i = 0; i < 6; ++i) {
        int rb = (mha * 6 + i) * 16 + ((lane >> 4) << 2);
        f32x4 a = acca[i];
#pragma unroll
        for (int g = 0; g < 4; ++g) {
          int a16 = (rb + g) * (ST * 2) + col16;
          float old = __uint_as_float((unsigned)tok16[a16] << 16);
          tok16[a16] = f2bf_rn(old + a[g]);
        }
      }
    }
    if (hasb) {
      int col16 = ntb * 16 + (lane & 15);
#pragma unroll
      for (int i = 0; i < 6; ++i) {
        int rb = (mhb * 6 + i) * 16 + ((lane >> 4) << 2);
        f32x4 a = accb[i];
#pragma unroll
        for (int g = 0; g < 4; ++g) {
          int a16 = (rb + g) * (ST * 2) + col16;
          float old = __uint_as_float((unsigned)tok16[a16] << 16);
          tok16[a16] = f2bf_rn(old + a[g]);
        }
      }
    }
  }  // layers
  __syncthreads();

  // post-LN (4 lanes per row, in place)
  if (lrow < S_) {
    float s = 0.f;
#pragma unroll
    for (int i = 0; i < 16; ++i) {
      unsigned w = tokp[lrow * ST + lsub * 16 + i];
      s += lo2f(w) + hi2f(w);
    }
    s += __shfl_xor(s, 1); s += __shfl_xor(s, 2);
    float m = s * (1.f / 128.f);
    float v = 0.f;
#pragma unroll
    for (int i = 0; i < 16; ++i) {
      unsigned w = tokp[lrow * ST + lsub * 16 + i];
      float t0 = lo2f(w) - m, t1 = hi2f(w) - m;
      v = fmaf(t0, t0, v); v = fmaf(t1, t1, v);
    }
    v += __shfl_xor(v, 1); v += __shfl_xor(v, 2);
    float rs = rsqrtf(v * (1.f / 128.f) + 1e-5f);
#pragma unroll
    for (int i = 0; i < 16; ++i) {
      int d2 = lsub * 16 + i, d = 2 * d2;
      unsigned w = tokp[lrow * ST + d2];
      tokp[lrow * ST + d2] = pack2((lo2f(w) - m) * rs * p.plng[d] + p.plnb[d],
                                   (hi2f(w) - m) * rs * p.plng[d + 1] + p.plnb[d + 1]);
    }
  }
  __syncthreads();

  if (tid < D_) {
    const int d2 = tid >> 1;
    const bool hi = tid & 1;
    float s0 = 0.f, s1 = 0.f;
    int r = 0;
    for (; r + 2 <= S_; r += 2) {
      unsigned w0 = tokp[r * ST + d2], w1 = tokp[(r + 1) * ST + d2];
      s0 += hi ? hi2f(w0) : lo2f(w0);
      s1 += hi ? hi2f(w1) : lo2f(w1);
    }
    unsigned wl = tokp[(S_ - 1) * ST + d2];
    s0 += hi ? hi2f(wl) : lo2f(wl);
    areaF[PO_OFF + tid] = (s0 + s1) * (1.f / (float)S_);
  }
  __syncthreads();
  if (tid < D_) {
    const float *wa = p.atW1 + tid * D_;
    const float *wv = p.vlW1 + tid * D_;
    float a0 = p.atB1[tid], a1 = 0.f, vv0 = p.vlB1[tid], vv1 = 0.f;
#pragma unroll 4
    for (int k = 0; k < D_; k += 2) {
      float pk0 = areaF[PO_OFF + k], pk1 = areaF[PO_OFF + k + 1];
      a0 = fmaf(pk0, wa[k], a0);   a1 = fmaf(pk1, wa[k + 1], a1);
      vv0 = fmaf(pk0, wv[k], vv0); vv1 = fmaf(pk1, wv[k + 1], vv1);
    }
    areaF[H1_OFF + tid] = fmaxf(a0 + a1, 0.f);
    areaF[H2_OFF + tid] = fmaxf(vv0 + vv1, 0.f);
  }
  __syncthreads();

  if (tid < H_) {
    float hh[64];
#pragma unroll
    for (int j = 0; j < 64; ++j) hh[j] = p.hxB1[j];
    for (int kb = 0; kb < 8; ++kb) {
      float xr[16];
#pragma unroll
      for (int i2 = 0; i2 < 8; ++i2) {
        unsigned w = tokp[tid * ST + kb * 8 + i2];
        xr[2 * i2] = lo2f(w); xr[2 * i2 + 1] = hi2f(w);
      }
      const float *w = p.hxW1 + kb * 16;
#pragma unroll
      for (int j = 0; j < 64; ++j) {
#pragma unroll
        for (int i = 0; i < 16; ++i)
          hh[j] = fmaf(xr[i], w[j * D_ + i], hh[j]);
      }
    }
    float o = p.hxB2[0];
#pragma unroll
    for (int j = 0; j < 64; ++j) o = fmaf(fmaxf(hh[j], 0.f), p.hxW2[j], o);
    p.out[OFF_HEX + b * H_ + tid] = o;
  }
  if (tid < NAT_) {
    const float *w = p.atW2 + tid * D_;
    float o0 = p.atB2[tid], o1 = 0.f, o2 = 0.f, o3 = 0.f;
#pragma unroll 4
    for (int k = 0; k < D_; k += 4) {
      o0 = fmaf(areaF[H1_OFF + k], w[k], o0);
      o1 = fmaf(areaF[H1_OFF + k + 1], w[k + 1], o1);
      o2 = fmaf(areaF[H1_OFF + k + 2], w[k + 2], o2);
      o3 = fmaf(areaF[H1_OFF + k + 3], w[k + 3], o3);
    }
    p.out[b * NAT_ + tid] = (o0 + o1) + (o2 + o3);
  }
  if (tid == 190) {
    float o0 = p.vlB2[0], o1 = 0.f, o2 = 0.f, o3 = 0.f;
#pragma unroll 4
    for (int k = 0; k < D_; k += 4) {
      o0 = fmaf(areaF[H2_OFF + k], p.vlW2[k], o0);
      o1 = fmaf(areaF[H2_OFF + k + 1], p.vlW2[k + 1], o1);
      o2 = fmaf(areaF[H2_OFF + k + 2], p.vlW2[k + 2], o2);
      o3 = fmaf(areaF[H2_OFF + k + 3], p.vlW2[k + 3], o3);
    }
    p.out[OFF_VAL + b] = (o0 + o1) + (o2 + o3);
  }
  if (tid >= 32 && tid < 32 + MS_) {
    int si = tid - 32;
    float o;
    if (svalid[si]) {
      int r = sposc[si];
      float hh[64];
#pragma unroll
      for (int j = 0; j < 64; ++j) hh[j] = p.tgB1[j];
      for (int kb = 0; kb < 8; ++kb) {
        float xr[16];
#pragma unroll
        for (int i2 = 0; i2 < 8; ++i2) {
          unsigned w = tokp[r * ST + kb * 8 + i2];
          xr[2 * i2] = lo2f(w); xr[2 * i2 + 1] = hi2f(w);
        }
        const float *w = p.tgW1 + kb * 16;
#pragma unroll
        for (int j = 0; j < 64; ++j) {
#pragma unroll
          for (int i = 0; i < 16; ++i)
            hh[j] = fmaf(xr[i], w[j * D_ + i], hh[j]);
        }
      }
      o = p.tgB2[0];
#pragma unroll
      for (int j = 0; j < 64; ++j) o = fmaf(fmaxf(hh[j], 0.f), p.tgW2[j], o);
    } else {
      o = -1e9f;
    }
    p.out[OFF_TGT + b * MS_ + si] = o;
  }
}

extern "C" void kernel_launch(void* const* d_in, const int* in_sizes, int n_in,
                              void* d_out, int out_size, void* d_ws, size_t ws_size,
                              hipStream_t stream) {
  (void)in_sizes; (void)n_in; (void)out_size;
  Params p;
  p.scalars = (const float *)d_in[0];
  p.stacks = (const float *)d_in[1];
  p.obstacles = (const float *)d_in[2];
  p.reach = (const float *)d_in[3];
  p.n_stacks = (const int *)d_in[4];
  p.cemb = (const float *)d_in[5];
  p.pos_emb = (const float *)d_in[6];
  p.tte = (const float *)d_in[7];
  p.hexW = (const float *)d_in[8];  p.hexB = (const float *)d_in[9];
  p.hexG = (const float *)d_in[10]; p.hexBe = (const float *)d_in[11];
  p.heroW = (const float *)d_in[12]; p.heroB = (const float *)d_in[13];
  p.heroG = (const float *)d_in[14]; p.heroBe = (const float *)d_in[15];
  p.gW = (const float *)d_in[16]; p.gB = (const float *)d_in[17];
  p.ln1g = (const float *)d_in[18]; p.ln1b = (const float *)d_in[19];
  p.qkvW = (const float *)d_in[20]; p.qkvB = (const float *)d_in[21];
  p.oW = (const float *)d_in[22]; p.oB = (const float *)d_in[23];
  p.ln2g = (const float *)d_in[24]; p.ln2b = (const float *)d_in[25];
  p.f1W = (const float *)d_in[26]; p.f1B = (const float *)d_in[27];
  p.f2W = (const float *)d_in[28]; p.f2B = (const float *)d_in[29];
  p.plng = (const float *)d_in[30]; p.plnb = (const float *)d_in[31];
  p.atW1 = (const float *)d_in[32]; p.atB1 = (const float *)d_in[33];
  p.atW2 = (const float *)d_in[34]; p.atB2 = (const float *)d_in[35];
  p.hxW1 = (const float *)d_in[36]; p.hxB1 = (const float *)d_in[37];
  p.hxW2 = (const float *)d_in[38]; p.hxB2 = (const float *)d_in[39];
  p.tgW1 = (const float *)d_in[40]; p.tgB1 = (const float *)d_in[41];
  p.tgW2 = (const float *)d_in[42]; p.tgB2 = (const float *)d_in[43];
  p.vlW1 = (const float *)d_in[44]; p.vlB1 = (const float *)d_in[45];
  p.vlW2 = (const float *)d_in[46]; p.vlB2 = (const float *)d_in[47];
  p.out = (float *)d_out;
  bool usews = ws_size >= (size_t)WS_TOT * 2;
  if (usews) {
    p.wsb = (const unsigned short *)d_ws;
    convw_kernel<<<dim3((WS_TOT + 255) / 256), dim3(256), 0, stream>>>(
        p.qkvW, p.oW, p.f1W, p.f2W, (unsigned short *)d_ws);
    battle_kernel<true><<<dim3(B_), dim3(768), 0, stream>>>(p);
  } else {
    p.wsb = nullptr;
    battle_kernel<false><<<dim3(B_), dim3(768), 0, stream>>>(p);
  }
}